// Round 7
// baseline (1462.330 us; speedup 1.0000x reference)
//
#include <hip/hip_runtime.h>
#include <hip/hip_bf16.h>
#include <hip/hip_fp16.h>
#include <hip/hip_cooperative_groups.h>

namespace cg = cooperative_groups;

#define NN 100000
#define EE 1600000
#define NBIN 64
#define BSH 9
#define BSZ 512
#define NBK 196   // ceil(NN/512)

typedef _Float16 h8v __attribute__((ext_vector_type(8)));
typedef float f4v __attribute__((ext_vector_type(4)));

__device__ __forceinline__ float sigm(float v) { return 1.0f / (1.0f + expf(-v)); }
__device__ __forceinline__ float4 f4add(float4 a, float4 b) {
  a.x += b.x; a.y += b.y; a.z += b.z; a.w += b.w; return a;
}
__device__ __forceinline__ float4 h4f(uint2 v) {
  __half2 a = *reinterpret_cast<__half2*>(&v.x);
  __half2 b = *reinterpret_cast<__half2*>(&v.y);
  float2 fa = __half22float2(a), fb = __half22float2(b);
  return make_float4(fa.x, fa.y, fb.x, fb.y);
}
__device__ __forceinline__ void h8acc(uint4 v, float* a) {
  float4 lo = h4f(make_uint2(v.x, v.y));
  float4 hi = h4f(make_uint2(v.z, v.w));
  a[0] += lo.x; a[1] += lo.y; a[2] += lo.z; a[3] += lo.w;
  a[4] += hi.x; a[5] += hi.y; a[6] += hi.z; a[7] += hi.w;
}
__device__ __forceinline__ uint2 pack4h(float4 r) {
  __half2 q0 = __floats2half2_rn(r.x, r.y), q1 = __floats2half2_rn(r.z, r.w);
  uint2 o; o.x = *(unsigned*)&q0; o.y = *(unsigned*)&q1; return o;
}

// ================= CSR build (bucketed, XCD-local writes) =================
__global__ __launch_bounds__(256) void k_bhist(const int* __restrict__ ei, int* __restrict__ ghist) {
  __shared__ int lh[NBK];
  for (int j = threadIdx.x; j < NBK; j += 256) lh[j] = 0;
  __syncthreads();
  for (int i = blockIdx.x * 256 + threadIdx.x; i < EE; i += gridDim.x * 256)
    atomicAdd(&lh[ei[EE + i] >> BSH], 1);
  __syncthreads();
  for (int j = threadIdx.x; j < NBK; j += 256) {
    int v = lh[j];
    if (v) atomicAdd(&ghist[j], v);
  }
}

__global__ void k_b196scan(const int* __restrict__ ghist, int* __restrict__ gcur,
                           int* __restrict__ bexclB, int* __restrict__ csr_off) {
  __shared__ int sh[256];
  int tid = threadIdx.x;
  int v = (tid < NBK) ? ghist[tid] : 0;
  sh[tid] = v;
  __syncthreads();
  for (int d = 1; d < 256; d <<= 1) {
    int t = (tid >= d) ? sh[tid - d] : 0;
    __syncthreads();
    sh[tid] += t;
    __syncthreads();
  }
  int excl = sh[tid] - v;
  if (tid < NBK) { gcur[tid] = excl; bexclB[tid] = excl; }
  if (tid == 0) { bexclB[NBK] = EE; csr_off[NN] = EE; }
}

// WG-local 196-way multi-split; packed u32 = src | (dst_lo << 17)
__global__ __launch_bounds__(256) void k_split(const int* __restrict__ ei,
                                               int* __restrict__ gcur,
                                               unsigned* __restrict__ pairs) {
  __shared__ int cntL[256];
  __shared__ int segO[256];
  __shared__ int curL[256];
  __shared__ int baseL[256];
  __shared__ unsigned stag[4096];
  __shared__ unsigned char bktL[4096];
  int tid = threadIdx.x;
  int tile0 = blockIdx.x * 4096;
  int tcnt = min(4096, EE - tile0);
  cntL[tid] = 0; curL[tid] = 0;
  __syncthreads();
  for (int i = tid; i < tcnt; i += 256)
    atomicAdd(&cntL[ei[EE + tile0 + i] >> BSH], 1);
  __syncthreads();
  int v = cntL[tid];
  segO[tid] = v;
  __syncthreads();
  for (int d = 1; d < 256; d <<= 1) {
    int t = (tid >= d) ? segO[tid - d] : 0;
    __syncthreads();
    segO[tid] += t;
    __syncthreads();
  }
  int excl = segO[tid] - v;
  __syncthreads();
  segO[tid] = excl;
  __syncthreads();
  for (int i = tid; i < tcnt; i += 256) {
    int s = ei[tile0 + i], dd = ei[EE + tile0 + i];
    int b = dd >> BSH;
    int slot = segO[b] + atomicAdd(&curL[b], 1);
    stag[slot] = (unsigned)s | ((unsigned)(dd & (BSZ - 1)) << 17);
    bktL[slot] = (unsigned char)b;
  }
  baseL[tid] = v ? atomicAdd(&gcur[tid], v) : 0;
  __syncthreads();
  for (int i = tid; i < tcnt; i += 256) {
    int b = bktL[i];
    pairs[baseL[b] + (i - segO[b])] = stag[i];
  }
}

// fused per-bucket count + scan + fill (pairs slice stays L2-hot between passes)
__global__ __launch_bounds__(256) void k_bbuild(const unsigned* __restrict__ pairs,
                                                const int* __restrict__ bexclB,
                                                int* __restrict__ cnt, int* __restrict__ csr_off,
                                                float* __restrict__ dis, int* __restrict__ csr_src) {
  __shared__ int c[BSZ];
  __shared__ int ps[256];
  __shared__ int curB[BSZ];
  int tid = threadIdx.x;
  int b = blockIdx.x;
  int lo = b << BSH;
  for (int j = tid; j < BSZ; j += 256) c[j] = 0;
  __syncthreads();
  int s0e = bexclB[b], s1e = bexclB[b + 1];
  for (int i = s0e + tid; i < s1e; i += 256)
    atomicAdd(&c[pairs[i] >> 17], 1);
  __syncthreads();
  int a0 = c[2 * tid], a1 = c[2 * tid + 1];
  int pv = a0 + a1;
  ps[tid] = pv;
  __syncthreads();
  for (int d = 1; d < 256; d <<= 1) {
    int t = (tid >= d) ? ps[tid - d] : 0;
    __syncthreads();
    ps[tid] += t;
    __syncthreads();
  }
  int pex = ps[tid] - pv;
  int base = s0e + pex;
  int n0 = lo + 2 * tid, n1 = n0 + 1;
  if (n0 < NN) {
    csr_off[n0] = base; cnt[n0] = a0;
    dis[n0] = (a0 > 0) ? rsqrtf((float)a0) : 0.0f;
  }
  if (n1 < NN) {
    csr_off[n1] = base + a0; cnt[n1] = a1;
    dis[n1] = (a1 > 0) ? rsqrtf((float)a1) : 0.0f;
  }
  curB[2 * tid] = base;
  curB[2 * tid + 1] = base + a0;
  __syncthreads();
  for (int i = s0e + tid; i < s1e; i += 256) {
    unsigned pk = pairs[i];
    int p = atomicAdd(&curB[pk >> 17], 1);
    csr_src[p] = (int)(pk & 0x1FFFFu);
  }
}

// ================= degree sort (perm) =================
__global__ __launch_bounds__(256) void k_hist(const int* __restrict__ cnt, int* __restrict__ hist) {
  __shared__ int lh[NBIN];
  if (threadIdx.x < NBIN) lh[threadIdx.x] = 0;
  __syncthreads();
  int i = blockIdx.x * 256 + threadIdx.x;
  if (i < NN) atomicAdd(&lh[min(cnt[i], NBIN - 1)], 1);
  __syncthreads();
  if (threadIdx.x < NBIN) {
    int v = lh[threadIdx.x];
    if (v) atomicAdd(&hist[threadIdx.x], v);
  }
}
__global__ void k_binscan(const int* __restrict__ hist, int* __restrict__ bincur) {
  int tid = threadIdx.x;
  int v = hist[tid];
  int incl = v;
  for (int d = 1; d < 64; d <<= 1) {
    int t = __shfl_up(incl, d, 64);
    if (tid >= d) incl += t;
  }
  bincur[tid] = incl - v;
}
__global__ __launch_bounds__(256) void k_scatter(const int* __restrict__ cnt,
                                                 int* __restrict__ bincur,
                                                 int* __restrict__ perm) {
  __shared__ int lh[NBIN];
  __shared__ int lbase[NBIN];
  if (threadIdx.x < NBIN) lh[threadIdx.x] = 0;
  __syncthreads();
  int i = blockIdx.x * 256 + threadIdx.x;
  int b = 0, r = 0;
  bool valid = i < NN;
  if (valid) {
    b = min(cnt[i], NBIN - 1);
    r = atomicAdd(&lh[b], 1);
  }
  __syncthreads();
  if (threadIdx.x < NBIN) {
    int v = lh[threadIdx.x];
    lbase[threadIdx.x] = v ? atomicAdd(&bincur[threadIdx.x], v) : 0;
  }
  __syncthreads();
  if (valid) perm[lbase[b] + r] = i;
}

// ================= fused prep: pad12h | prep_a32 | wcast1 | wcast =================
#define PREP_B0 ((NN * 12 + 255) / 256)
#define PREP_B1 ((NN + 255) / 256)
__global__ __launch_bounds__(256) void k_prep(
    const float* __restrict__ x, const float* __restrict__ s1wl, const float* __restrict__ s1wr,
    const float* __restrict__ s2wl, const float* __restrict__ s2wr,
    __half* __restrict__ x12h, __half* __restrict__ A32,
    __half* __restrict__ w1h, __half* __restrict__ w2h) {
  int bid = blockIdx.x;
  if (bid < PREP_B0) {
    int i = bid * 256 + threadIdx.x;
    if (i < NN * 12) {
      int n = i / 12, j = i - n * 12;
      x12h[i] = __float2half((j < 11) ? x[n * 11 + j] : 0.0f);
    }
  } else if (bid < PREP_B0 + PREP_B1) {
    int i = (bid - PREP_B0) * 256 + threadIdx.x;
    if (i < NN) {
      float a[11];
      #pragma unroll
      for (int j = 0; j < 11; ++j) a[j] = x[(long)i * 11 + j];
      uint2* row = (uint2*)(A32 + (long)i * 32);
      row[3] = make_uint2(0u, 0u);
      row[4] = pack4h(make_float4(a[0], a[1], a[2], a[3]));
      row[5] = pack4h(make_float4(a[4], a[5], a[6], a[7]));
      row[6] = pack4h(make_float4(a[8], a[9], a[10], 0.0f));
      row[7] = make_uint2(0u, 0u);
    }
  } else if (bid < PREP_B0 + PREP_B1 + 16) {
    int i = (bid - PREP_B0 - PREP_B1) * 256 + threadIdx.x;  // 0..4095
    int o = i >> 5, k = i & 31;
    float v = 0.0f;
    if (k < 11) v = s1wl[o * 11 + k];
    else if (k >= 16 && k < 27) v = s1wr[o * 11 + (k - 16)];
    w1h[i] = __float2half(v);
  } else {
    int i = (bid - PREP_B0 - PREP_B1 - 16) * 256 + threadIdx.x;  // 0..32767
    int o = i >> 8, k = i & 255;
    float v = (k < 128) ? s2wl[o * 128 + k] : s2wr[o * 128 + (k - 128)];
    w2h[i] = __float2half(v);
  }
}

// ================= SAGE gathers =================
__global__ void k_gmean12h(const __half* __restrict__ x12h, const int* __restrict__ perm,
                           const int* __restrict__ off, const int* __restrict__ srcarr,
                           __half* __restrict__ A32) {
  int g = blockIdx.x * 64 + (threadIdx.x >> 2);
  int t = threadIdx.x & 3;
  if (g >= NN || t >= 3) return;
  int node = perm[g];
  int s = off[node], e = off[node + 1];
  const uint2* h2 = (const uint2*)x12h;
  float4 acc = {0, 0, 0, 0};
  int p = s;
  for (; p + 4 <= e; p += 4) {
    int s0 = srcarr[p], s1 = srcarr[p + 1], s2 = srcarr[p + 2], s3 = srcarr[p + 3];
    acc = f4add(acc, f4add(f4add(h4f(h2[(long)s0 * 3 + t]), h4f(h2[(long)s1 * 3 + t])),
                           f4add(h4f(h2[(long)s2 * 3 + t]), h4f(h2[(long)s3 * 3 + t]))));
  }
  for (; p < e; ++p) acc = f4add(acc, h4f(h2[(long)srcarr[p] * 3 + t]));
  int c = e - s;
  float inv = 1.0f / (float)(c > 0 ? c : 1);
  acc.x *= inv; acc.y *= inv; acc.z *= inv; acc.w *= inv;
  ((uint2*)A32)[(long)node * 8 + t] = pack4h(acc);
}

__global__ void k_gather128(const __half* __restrict__ h, const int* __restrict__ perm,
                            const int* __restrict__ off, const int* __restrict__ srcarr,
                            __half* __restrict__ outh) {
  int g = blockIdx.x * 16 + (threadIdx.x >> 4);
  int t = threadIdx.x & 15;
  if (g >= NN) return;
  int node = perm[g];
  int s = off[node], e = off[node + 1];
  const uint4* h4 = (const uint4*)h;
  float acc[8] = {};
  int p = s;
  for (; p + 4 <= e; p += 4) {
    int s0 = srcarr[p], s1 = srcarr[p + 1], s2 = srcarr[p + 2], s3 = srcarr[p + 3];
    uint4 r0 = h4[(long)s0 * 16 + t], r1 = h4[(long)s1 * 16 + t];
    uint4 r2 = h4[(long)s2 * 16 + t], r3 = h4[(long)s3 * 16 + t];
    h8acc(r0, acc); h8acc(r1, acc); h8acc(r2, acc); h8acc(r3, acc);
  }
  for (; p < e; ++p) h8acc(h4[(long)srcarr[p] * 16 + t], acc);
  int c = e - s;
  float inv = 1.0f / (float)(c > 0 ? c : 1);
  uint2 lo = pack4h(make_float4(acc[0] * inv, acc[1] * inv, acc[2] * inv, acc[3] * inv));
  uint2 hi = pack4h(make_float4(acc[4] * inv, acc[5] * inv, acc[6] * inv, acc[7] * inv));
  uint4 o; o.x = lo.x; o.y = lo.y; o.z = hi.x; o.w = hi.y;
  ((uint4*)outh)[(long)node * 16 + t] = o;
}

// ================= SAGE MFMA layers =================
__global__ __launch_bounds__(256) void k_mm1_mfma(
    const __half* __restrict__ A32, const __half* __restrict__ W32,
    const float* __restrict__ bias, __half* __restrict__ out) {
  __shared__ __half lt[4][32][136];
  int tid = threadIdx.x;
  int wave = tid >> 6, l = tid & 63;
  int lr = l & 15, lk = l >> 4;
  int m0 = blockIdx.x * 128 + wave * 32;
  f4v acc[2][8] = {};
  h8v afrag[2];
  #pragma unroll
  for (int rt = 0; rt < 2; ++rt) {
    int row = m0 + rt * 16 + lr;
    h8v z = {};
    afrag[rt] = (row < NN) ? *(const h8v*)&A32[(long)row * 32 + lk * 8] : z;
  }
  #pragma unroll
  for (int c = 0; c < 8; ++c) {
    h8v bfrag = *(const h8v*)&W32[(c * 16 + lr) * 32 + lk * 8];
    acc[0][c] = __builtin_amdgcn_mfma_f32_16x16x32_f16(afrag[0], bfrag, acc[0][c], 0, 0, 0);
    acc[1][c] = __builtin_amdgcn_mfma_f32_16x16x32_f16(afrag[1], bfrag, acc[1][c], 0, 0, 0);
  }
  float bi[8];
  #pragma unroll
  for (int c = 0; c < 8; ++c) bi[c] = bias[c * 16 + lr];
  #pragma unroll
  for (int rt = 0; rt < 2; ++rt)
    #pragma unroll
    for (int c = 0; c < 8; ++c)
      #pragma unroll
      for (int reg = 0; reg < 4; ++reg) {
        float v = acc[rt][c][reg] + bi[c];
        lt[wave][rt * 16 + lk * 4 + reg][c * 16 + lr] = __float2half(sigm(v));
      }
  __syncthreads();
  #pragma unroll
  for (int it = 0; it < 8; ++it) {
    int idx = it * 64 + l;
    int row = idx >> 4, c16 = idx & 15;
    int grow = m0 + row;
    if (grow < NN) {
      uint4 v = *(const uint4*)&lt[wave][row][c16 * 8];
      ((uint4*)out)[(long)grow * 16 + c16] = v;
    }
  }
}

__global__ __launch_bounds__(256) void k_mm2_mfma(
    const __half* __restrict__ A1, const __half* __restrict__ A2,
    const __half* __restrict__ W, const float* __restrict__ bias,
    const float* __restrict__ w3l, const float* __restrict__ w3r,
    float* __restrict__ pp, float* __restrict__ qq) {
  int tid = threadIdx.x;
  int wave = tid >> 6;
  int l = tid & 63;
  int lr = l & 15;
  int lk = l >> 4;
  int m0 = blockIdx.x * 128 + wave * 32;
  f4v acc[2][8] = {};
  #pragma unroll
  for (int ks = 0; ks < 8; ++ks) {
    const __half* Asrc = (ks < 4) ? A1 : A2;
    int kk = (ks & 3) * 32 + lk * 8;
    h8v afrag[2];
    #pragma unroll
    for (int rt = 0; rt < 2; ++rt) {
      int row = m0 + rt * 16 + lr;
      h8v z = {};
      afrag[rt] = (row < NN) ? *(const h8v*)&Asrc[(long)row * 128 + kk] : z;
    }
    #pragma unroll
    for (int c = 0; c < 8; ++c) {
      h8v bfrag = *(const h8v*)&W[(long)(c * 16 + lr) * 256 + ks * 32 + lk * 8];
      acc[0][c] = __builtin_amdgcn_mfma_f32_16x16x32_f16(afrag[0], bfrag, acc[0][c], 0, 0, 0);
      acc[1][c] = __builtin_amdgcn_mfma_f32_16x16x32_f16(afrag[1], bfrag, acc[1][c], 0, 0, 0);
    }
  }
  float wl[8], wr[8], bi[8];
  #pragma unroll
  for (int c = 0; c < 8; ++c) {
    wl[c] = w3l[c * 16 + lr];
    wr[c] = w3r[c * 16 + lr];
    bi[c] = bias[c * 16 + lr];
  }
  #pragma unroll
  for (int rt = 0; rt < 2; ++rt) {
    #pragma unroll
    for (int reg = 0; reg < 4; ++reg) {
      float s1 = 0.0f, s2 = 0.0f;
      #pragma unroll
      for (int c = 0; c < 8; ++c) {
        float v = acc[rt][c][reg] + bi[c];
        float sg = sigm(v);
        s1 += sg * wl[c];
        s2 += sg * wr[c];
      }
      #pragma unroll
      for (int d = 1; d < 16; d <<= 1) {
        s1 += __shfl_xor(s1, d, 64);
        s2 += __shfl_xor(s2, d, 64);
      }
      int row = m0 + rt * 16 + lk * 4 + reg;
      if (lr == 0 && row < NN) { pp[row] = s1; qq[row] = s2; }
    }
  }
}

// ================= cooperative TAG phase =================
struct CoopArgs {
  const int* csr_off; const int* csr_src; const int* perm; const float* dis;
  const float* x;
  const float* t1aw; const float* t1ab; const float* t1bw; const float* t1bb;
  const float* t2aw; const float* t2ab; const float* t2bw; const float* t2bb;
  const float* pp; const float* qq; const float* s3b;
  const float* lw; const float* lb;
  float* Pa; __half* PTop; __half* zbuf0; __half* zbuf1;
  __half* x2a; float* P2;
  float* Pb; __half* x3a; float* P2b;
  float* x1s; float* x2s;
  float* uA1; float* uA2; float* uB1; float* uB2;
  float* out;
};

// dual D8 hop, interleaved [A|B] uint4 rows, both lanes act3 (prescale)
__device__ __forceinline__ void d8_dual_act3(
    const __half* src, const float* addA, const float* addB, __half* dst,
    const int* perm, const int* off, const int* srcarr, const float* dis) {
  const uint4* src4 = (const uint4*)src;
  int t = threadIdx.x & 1;
  const float4* addp = (const float4*)(t == 0 ? addA : addB);
  for (int g = blockIdx.x * 128 + (threadIdx.x >> 1); g < NN; g += gridDim.x * 128) {
    int node = perm[g];
    int s = off[node], e = off[node + 1];
    float acc[8] = {};
    int p = s;
    for (; p + 4 <= e; p += 4) {
      int s0 = srcarr[p], s1 = srcarr[p + 1], s2 = srcarr[p + 2], s3 = srcarr[p + 3];
      uint4 v0 = src4[(long)s0 * 2 + t], v1 = src4[(long)s1 * 2 + t];
      uint4 v2 = src4[(long)s2 * 2 + t], v3 = src4[(long)s3 * 2 + t];
      h8acc(v0, acc); h8acc(v1, acc); h8acc(v2, acc); h8acc(v3, acc);
    }
    for (; p < e; ++p) h8acc(src4[(long)srcarr[p] * 2 + t], acc);
    float dn = dis[node];
    float4 a0 = addp[(long)node * 2], a1 = addp[(long)node * 2 + 1];
    float4 r0 = make_float4((acc[0] * dn + a0.x) * dn, (acc[1] * dn + a0.y) * dn,
                            (acc[2] * dn + a0.z) * dn, (acc[3] * dn + a0.w) * dn);
    float4 r1 = make_float4((acc[4] * dn + a1.x) * dn, (acc[5] * dn + a1.y) * dn,
                            (acc[6] * dn + a1.z) * dn, (acc[7] * dn + a1.w) * dn);
    uint2 lo = pack4h(r0), hi = pack4h(r1);
    uint4 o; o.x = lo.x; o.y = lo.y; o.z = hi.x; o.w = hi.y;
    ((uint4*)dst)[(long)node * 2 + t] = o;
  }
}

// single-B D8 hop (reads B half = uint2 slots 2,3), act3
__device__ __forceinline__ void d8_single_act3(
    const __half* src, const float* addB, __half* dst,
    const int* perm, const int* off, const int* srcarr, const float* dis) {
  const uint2* src2 = (const uint2*)src;
  int t = threadIdx.x & 1;
  for (int g = blockIdx.x * 128 + (threadIdx.x >> 1); g < NN; g += gridDim.x * 128) {
    int node = perm[g];
    int s = off[node], e = off[node + 1];
    float4 acc = {0, 0, 0, 0};
    int p = s;
    for (; p + 4 <= e; p += 4) {
      int s0 = srcarr[p], s1 = srcarr[p + 1], s2 = srcarr[p + 2], s3 = srcarr[p + 3];
      acc = f4add(acc, f4add(f4add(h4f(src2[(long)s0 * 4 + 2 + t]), h4f(src2[(long)s1 * 4 + 2 + t])),
                             f4add(h4f(src2[(long)s2 * 4 + 2 + t]), h4f(src2[(long)s3 * 4 + 2 + t]))));
    }
    for (; p < e; ++p) acc = f4add(acc, h4f(src2[(long)srcarr[p] * 4 + 2 + t]));
    float dn = dis[node];
    float4 av = ((const float4*)addB)[(long)node * 2 + t];
    float4 r = make_float4((acc.x * dn + av.x) * dn, (acc.y * dn + av.y) * dn,
                           (acc.z * dn + av.z) * dn, (acc.w * dn + av.w) * dn);
    ((uint2*)dst)[(long)node * 4 + 2 + t] = pack4h(r);
  }
}

// dual D1 hop, act3 both
__device__ __forceinline__ void d1_dual_act3(
    const float* ua, const float* adda, const float* ub, const float* addb,
    float* outa, float* outb,
    const int* perm, const int* off, const int* srcarr, const float* dis) {
  int t = threadIdx.x & 3;
  for (int g = blockIdx.x * 64 + (threadIdx.x >> 2); g < NN; g += gridDim.x * 64) {
    int node = perm[g];
    int s = off[node], e = off[node + 1];
    float accA = 0.0f, accB = 0.0f;
    for (int p = s + t; p < e; p += 4) {
      int s0 = srcarr[p];
      accA += ua[s0];
      accB += ub[s0];
    }
    accA += __shfl_xor(accA, 1, 64); accA += __shfl_xor(accA, 2, 64);
    accB += __shfl_xor(accB, 1, 64); accB += __shfl_xor(accB, 2, 64);
    if (t == 0) {
      float sc = dis[node];
      outa[node] = (accA * sc + adda[node]) * sc;
      outb[node] = (accB * sc + addb[node]) * sc;
    }
  }
}

__device__ __forceinline__ void d1_single_act3(
    const float* ua, const float* adda, float* outa,
    const int* perm, const int* off, const int* srcarr, const float* dis) {
  int t = threadIdx.x & 3;
  for (int g = blockIdx.x * 64 + (threadIdx.x >> 2); g < NN; g += gridDim.x * 64) {
    int node = perm[g];
    int s = off[node], e = off[node + 1];
    float accA = 0.0f;
    for (int p = s + t; p < e; p += 4) accA += ua[srcarr[p]];
    accA += __shfl_xor(accA, 1, 64); accA += __shfl_xor(accA, 2, 64);
    if (t == 0) {
      float sc = dis[node];
      outa[node] = (accA * sc + adda[node]) * sc;
    }
  }
}

__global__ __launch_bounds__(256) void k_coop(CoopArgs A) {
  cg::grid_group grid = cg::this_grid();
  const size_t S8 = (size_t)NN * 8;
  const size_t S1 = (size_t)NN;

  // ---- L0: tagP8 (both chains, interleaved top) + x1s mean-hop ----
  {
    for (int i = blockIdx.x * 256 + threadIdx.x; i < NN; i += gridDim.x * 256) {
      float a[11];
      #pragma unroll
      for (int j = 0; j < 11; ++j) a[j] = A.x[(long)i * 11 + j];
      float dn = A.dis[i];
      // chain a: NH=4
      #pragma unroll
      for (int k = 0; k < 4; ++k) {
        float s[8];
        #pragma unroll
        for (int o = 0; o < 8; ++o) {
          float acc = 0.0f;
          #pragma unroll
          for (int j = 0; j < 11; ++j) acc += a[j] * A.t1aw[o * 44 + k * 11 + j];
          s[o] = acc;
        }
        if (k < 3) {
          float4* dst = (float4*)&A.Pa[((size_t)k * NN + i) * 8];
          dst[0] = make_float4(s[0], s[1], s[2], s[3]);
          dst[1] = make_float4(s[4], s[5], s[6], s[7]);
        } else {
          uint2 lo = pack4h(make_float4(s[0] * dn, s[1] * dn, s[2] * dn, s[3] * dn));
          uint2 hi = pack4h(make_float4(s[4] * dn, s[5] * dn, s[6] * dn, s[7] * dn));
          uint4 o4; o4.x = lo.x; o4.y = lo.y; o4.z = hi.x; o4.w = hi.y;
          ((uint4*)A.PTop)[(long)i * 2] = o4;
        }
      }
      // chain b: NH=7
      #pragma unroll
      for (int k = 0; k < 7; ++k) {
        float s[8];
        #pragma unroll
        for (int o = 0; o < 8; ++o) {
          float acc = 0.0f;
          #pragma unroll
          for (int j = 0; j < 11; ++j) acc += a[j] * A.t1bw[o * 77 + k * 11 + j];
          s[o] = acc;
        }
        if (k < 6) {
          float4* dst = (float4*)&A.Pb[((size_t)k * NN + i) * 8];
          dst[0] = make_float4(s[0], s[1], s[2], s[3]);
          dst[1] = make_float4(s[4], s[5], s[6], s[7]);
        } else {
          uint2 lo = pack4h(make_float4(s[0] * dn, s[1] * dn, s[2] * dn, s[3] * dn));
          uint2 hi = pack4h(make_float4(s[4] * dn, s[5] * dn, s[6] * dn, s[7] * dn));
          uint4 o4; o4.x = lo.x; o4.y = lo.y; o4.z = hi.x; o4.w = hi.y;
          ((uint4*)A.PTop)[(long)i * 2 + 1] = o4;
        }
      }
    }
    // x1s: SAGE3 mean-hop (MODE 0) + relu
    int t = threadIdx.x & 3;
    for (int g = blockIdx.x * 64 + (threadIdx.x >> 2); g < NN; g += gridDim.x * 64) {
      int node = A.perm[g];
      int s = A.csr_off[node], e = A.csr_off[node + 1];
      float acc = 0.0f;
      for (int p = s + t; p < e; p += 4) acc += A.pp[A.csr_src[p]];
      acc += __shfl_xor(acc, 1, 64); acc += __shfl_xor(acc, 2, 64);
      if (t == 0) {
        int c = e - s;
        float sc = 1.0f / (float)(c > 0 ? c : 1);
        A.x1s[node] = fmaxf(acc * sc + A.qq[node] + A.s3b[0], 0.0f);
      }
    }
  }
  grid.sync();
  // ---- L1, L2: dual D8 act3 ----
  d8_dual_act3(A.PTop, A.Pa + 2 * S8, A.Pb + 5 * S8, A.zbuf0,
               A.perm, A.csr_off, A.csr_src, A.dis);
  grid.sync();
  d8_dual_act3(A.zbuf0, A.Pa + 1 * S8, A.Pb + 4 * S8, A.zbuf1,
               A.perm, A.csr_off, A.csr_src, A.dis);
  grid.sync();
  // ---- L3: dual; lane0 -> x2a (sigmoid + t1ab), lane1 -> zbuf0 B (act3) ----
  {
    const uint4* src4 = (const uint4*)A.zbuf1;
    int t = threadIdx.x & 1;
    for (int g = blockIdx.x * 128 + (threadIdx.x >> 1); g < NN; g += gridDim.x * 128) {
      int node = A.perm[g];
      int s = A.csr_off[node], e = A.csr_off[node + 1];
      float acc[8] = {};
      int p = s;
      for (; p + 4 <= e; p += 4) {
        int s0 = A.csr_src[p], s1 = A.csr_src[p + 1], s2 = A.csr_src[p + 2], s3 = A.csr_src[p + 3];
        h8acc(src4[(long)s0 * 2 + t], acc); h8acc(src4[(long)s1 * 2 + t], acc);
        h8acc(src4[(long)s2 * 2 + t], acc); h8acc(src4[(long)s3 * 2 + t], acc);
      }
      for (; p < e; ++p) h8acc(src4[(long)A.csr_src[p] * 2 + t], acc);
      float dn = A.dis[node];
      if (t == 0) {
        const float4* addp = (const float4*)A.Pa;
        float4 a0 = addp[(long)node * 2], a1 = addp[(long)node * 2 + 1];
        float4 b0 = ((const float4*)A.t1ab)[0], b1 = ((const float4*)A.t1ab)[1];
        float4 r0 = make_float4(sigm(acc[0] * dn + a0.x + b0.x), sigm(acc[1] * dn + a0.y + b0.y),
                                sigm(acc[2] * dn + a0.z + b0.z), sigm(acc[3] * dn + a0.w + b0.w));
        float4 r1 = make_float4(sigm(acc[4] * dn + a1.x + b1.x), sigm(acc[5] * dn + a1.y + b1.y),
                                sigm(acc[6] * dn + a1.z + b1.z), sigm(acc[7] * dn + a1.w + b1.w));
        uint2 lo = pack4h(r0), hi = pack4h(r1);
        uint4 o; o.x = lo.x; o.y = lo.y; o.z = hi.x; o.w = hi.y;
        ((uint4*)A.x2a)[node] = o;
      } else {
        const float4* addp = (const float4*)(A.Pb + 3 * S8);
        float4 a0 = addp[(long)node * 2], a1 = addp[(long)node * 2 + 1];
        float4 r0 = make_float4((acc[0] * dn + a0.x) * dn, (acc[1] * dn + a0.y) * dn,
                                (acc[2] * dn + a0.z) * dn, (acc[3] * dn + a0.w) * dn);
        float4 r1 = make_float4((acc[4] * dn + a1.x) * dn, (acc[5] * dn + a1.y) * dn,
                                (acc[6] * dn + a1.z) * dn, (acc[7] * dn + a1.w) * dn);
        uint2 lo = pack4h(r0), hi = pack4h(r1);
        uint4 o; o.x = lo.x; o.y = lo.y; o.z = hi.x; o.w = hi.y;
        ((uint4*)A.zbuf0)[(long)node * 2 + 1] = o;
      }
    }
  }
  grid.sync();
  // ---- L4: single B (zbuf0->zbuf1) + tagP1<4> (x2a -> P2) ----
  d8_single_act3(A.zbuf0, A.Pb + 2 * S8, A.zbuf1, A.perm, A.csr_off, A.csr_src, A.dis);
  for (int i = blockIdx.x * 256 + threadIdx.x; i < NN; i += gridDim.x * 256) {
    uint4 v = ((const uint4*)A.x2a)[i];
    float4 lo = h4f(make_uint2(v.x, v.y)), hi = h4f(make_uint2(v.z, v.w));
    float a[8] = {lo.x, lo.y, lo.z, lo.w, hi.x, hi.y, hi.z, hi.w};
    #pragma unroll
    for (int k = 0; k < 4; ++k) {
      float s = 0.0f;
      #pragma unroll
      for (int j = 0; j < 8; ++j) s += a[j] * A.t2aw[k * 8 + j];
      if (k == 3) s *= A.dis[i];
      A.P2[(size_t)k * NN + i] = s;
    }
  }
  grid.sync();
  // ---- L5: single B (zbuf1->zbuf0) ----
  d8_single_act3(A.zbuf1, A.Pb + 1 * S8, A.zbuf0, A.perm, A.csr_off, A.csr_src, A.dis);
  grid.sync();
  // ---- L6: single B -> x3a (sigmoid + t1bb) ----
  {
    const uint2* src2 = (const uint2*)A.zbuf0;
    int t = threadIdx.x & 1;
    for (int g = blockIdx.x * 128 + (threadIdx.x >> 1); g < NN; g += gridDim.x * 128) {
      int node = A.perm[g];
      int s = A.csr_off[node], e = A.csr_off[node + 1];
      float4 acc = {0, 0, 0, 0};
      int p = s;
      for (; p + 4 <= e; p += 4) {
        int s0 = A.csr_src[p], s1 = A.csr_src[p + 1], s2 = A.csr_src[p + 2], s3 = A.csr_src[p + 3];
        acc = f4add(acc, f4add(f4add(h4f(src2[(long)s0 * 4 + 2 + t]), h4f(src2[(long)s1 * 4 + 2 + t])),
                               f4add(h4f(src2[(long)s2 * 4 + 2 + t]), h4f(src2[(long)s3 * 4 + 2 + t]))));
      }
      for (; p < e; ++p) acc = f4add(acc, h4f(src2[(long)A.csr_src[p] * 4 + 2 + t]));
      float dn = A.dis[node];
      float4 av = ((const float4*)A.Pb)[(long)node * 2 + t];
      float4 bv = ((const float4*)A.t1bb)[t];
      float4 r = make_float4(sigm(acc.x * dn + av.x + bv.x), sigm(acc.y * dn + av.y + bv.y),
                             sigm(acc.z * dn + av.z + bv.z), sigm(acc.w * dn + av.w + bv.w));
      ((uint2*)A.x3a)[(long)node * 2 + t] = pack4h(r);
    }
  }
  grid.sync();
  // ---- L7: tagP1<7> (x3a -> P2b) ----
  for (int i = blockIdx.x * 256 + threadIdx.x; i < NN; i += gridDim.x * 256) {
    uint4 v = ((const uint4*)A.x3a)[i];
    float4 lo = h4f(make_uint2(v.x, v.y)), hi = h4f(make_uint2(v.z, v.w));
    float a[8] = {lo.x, lo.y, lo.z, lo.w, hi.x, hi.y, hi.z, hi.w};
    #pragma unroll
    for (int k = 0; k < 7; ++k) {
      float s = 0.0f;
      #pragma unroll
      for (int j = 0; j < 8; ++j) s += a[j] * A.t2bw[k * 8 + j];
      if (k == 6) s *= A.dis[i];
      A.P2b[(size_t)k * NN + i] = s;
    }
  }
  grid.sync();
  // ---- L8..L10: D1 duals ----
  d1_dual_act3(A.P2 + 3 * S1, A.P2 + 2 * S1, A.P2b + 6 * S1, A.P2b + 5 * S1,
               A.uA1, A.uB1, A.perm, A.csr_off, A.csr_src, A.dis);
  grid.sync();
  d1_dual_act3(A.uA1, A.P2 + 1 * S1, A.uB1, A.P2b + 4 * S1,
               A.uA2, A.uB2, A.perm, A.csr_off, A.csr_src, A.dis);
  grid.sync();
  {
    // x2s (relu + t2ab bias) and uB1 (act3)
    int t = threadIdx.x & 3;
    for (int g = blockIdx.x * 64 + (threadIdx.x >> 2); g < NN; g += gridDim.x * 64) {
      int node = A.perm[g];
      int s = A.csr_off[node], e = A.csr_off[node + 1];
      float accA = 0.0f, accB = 0.0f;
      for (int p = s + t; p < e; p += 4) {
        int s0 = A.csr_src[p];
        accA += A.uA2[s0];
        accB += A.uB2[s0];
      }
      accA += __shfl_xor(accA, 1, 64); accA += __shfl_xor(accA, 2, 64);
      accB += __shfl_xor(accB, 1, 64); accB += __shfl_xor(accB, 2, 64);
      if (t == 0) {
        float sc = A.dis[node];
        A.x2s[node] = fmaxf(accA * sc + A.P2[node] + A.t2ab[0], 0.0f);
        A.uB1[node] = (accB * sc + A.P2b[3 * S1 + node]) * sc;
      }
    }
  }
  grid.sync();
  // ---- L11, L12: D1 singles ----
  d1_single_act3(A.uB1, A.P2b + 2 * S1, A.uB2, A.perm, A.csr_off, A.csr_src, A.dis);
  grid.sync();
  d1_single_act3(A.uB2, A.P2b + 1 * S1, A.uB1, A.perm, A.csr_off, A.csr_src, A.dis);
  grid.sync();
  // ---- L13: final hop + combine ----
  {
    int t = threadIdx.x & 3;
    for (int g = blockIdx.x * 64 + (threadIdx.x >> 2); g < NN; g += gridDim.x * 64) {
      int node = A.perm[g];
      int s = A.csr_off[node], e = A.csr_off[node + 1];
      float acc = 0.0f;
      for (int p = s + t; p < e; p += 4) acc += A.uB1[A.csr_src[p]];
      acc += __shfl_xor(acc, 1, 64); acc += __shfl_xor(acc, 2, 64);
      if (t == 0) {
        float x3v = fmaxf(acc * A.dis[node] + A.P2b[node] + A.t2bb[0], 0.0f);
        float v = A.x1s[node] * A.lw[0] + A.x2s[node] * A.lw[1] + x3v * A.lw[2] + A.lb[0];
        A.out[node] = fmaxf(v, 0.0f);
      }
    }
  }
}

extern "C" void kernel_launch(void* const* d_in, const int* in_sizes, int n_in,
                              void* d_out, int out_size, void* d_ws, size_t ws_size,
                              hipStream_t stream) {
  const float* x    = (const float*)d_in[0];
  const int*   ei   = (const int*)d_in[1];
  const float* s1wl = (const float*)d_in[2];
  const float* s1wr = (const float*)d_in[3];
  const float* s1b  = (const float*)d_in[4];
  const float* s2wl = (const float*)d_in[5];
  const float* s2wr = (const float*)d_in[6];
  const float* s2b  = (const float*)d_in[7];
  const float* s3wl = (const float*)d_in[8];
  const float* s3wr = (const float*)d_in[9];
  const float* s3b  = (const float*)d_in[10];
  const float* t1aw = (const float*)d_in[11];
  const float* t1ab = (const float*)d_in[12];
  const float* t2aw = (const float*)d_in[13];
  const float* t2ab = (const float*)d_in[14];
  const float* t1bw = (const float*)d_in[15];
  const float* t1bb = (const float*)d_in[16];
  const float* t2bw = (const float*)d_in[17];
  const float* t2bb = (const float*)d_in[18];
  const float* lw   = (const float*)d_in[19];
  const float* lb   = (const float*)d_in[20];
  float* out = (float*)d_out;

  char* basep = (char*)d_ws;
  size_t off = 0;
  auto alloc = [&](size_t bytes) -> void* {
    void* ptr = basep + off;
    off = (off + bytes + 255) & ~(size_t)255;
    return ptr;
  };
  int*      cnt     = (int*)alloc((size_t)NN * 4);
  int*      csr_off = (int*)alloc((size_t)(NN + 1) * 4);
  float*    dis     = (float*)alloc((size_t)NN * 4);
  int*      csr_src = (int*)alloc((size_t)EE * 4);
  unsigned* pairs   = (unsigned*)alloc((size_t)EE * 4);
  int*      perm    = (int*)alloc((size_t)NN * 4);
  int*      ghist   = (int*)alloc(256 * 4);   // contiguous zero block start
  int*      gcur    = (int*)alloc(256 * 4);
  int*      bexclB  = (int*)alloc(256 * 4);
  int*      hist    = (int*)alloc(NBIN * 4);
  int*      bincur  = (int*)alloc(NBIN * 4);  // contiguous zero block end
  float*    x1s     = (float*)alloc((size_t)NN * 4);
  float*    x2s     = (float*)alloc((size_t)NN * 4);
  float*    pp      = (float*)alloc((size_t)NN * 4);
  float*    qq      = (float*)alloc((size_t)NN * 4);
  float*    uA1     = (float*)alloc((size_t)NN * 4);
  float*    uA2     = (float*)alloc((size_t)NN * 4);
  float*    uB1     = (float*)alloc((size_t)NN * 4);
  float*    uB2     = (float*)alloc((size_t)NN * 4);
  __half*   x12h    = (__half*)alloc((size_t)NN * 12 * 2);
  __half*   A32     = (__half*)alloc((size_t)NN * 32 * 2);
  __half*   w1h     = (__half*)alloc((size_t)128 * 32 * 2);
  __half*   w2h     = (__half*)alloc((size_t)128 * 256 * 2);
  __half*   x1a_h   = (__half*)alloc((size_t)NN * 128 * 2);   // region1 overlay after mm2
  __half*   mean128_h = (__half*)alloc((size_t)NN * 128 * 2);
  float*    region2 = (float*)alloc((size_t)NN * 60 * 4);

  // Region 1 overlay (x1a_h = 64N f32-equiv; reused after k_mm2_mfma):
  float* r1 = (float*)x1a_h;
  float*  Pa    = r1;                              // [3][N][8] = 24N
  __half* PTop  = (__half*)(r1 + (size_t)NN * 24); // [N][16] interleaved = 8N
  __half* zbuf0 = (__half*)(r1 + (size_t)NN * 32); // [N][16] = 8N
  __half* zbuf1 = (__half*)(r1 + (size_t)NN * 40); // [N][16] = 8N
  __half* x2a   = (__half*)(r1 + (size_t)NN * 48); // [N][8]  = 4N
  float*  P2    = r1 + (size_t)NN * 52;            // [4][N]  = 4N   (56N <= 64N)
  // Region 2 (60N):
  float*  Pb    = region2;                         // [6][N][8] = 48N
  __half* x3a   = (__half*)(region2 + (size_t)NN * 48); // [N][8] = 4N
  float*  P2b   = region2 + (size_t)NN * 52;       // [7][N] = 7N  (59N <= 60N)

  // ---- CSR build (bucketed) ----
  hipMemsetAsync(ghist, 0, 3840, stream);  // zeroes ghist..bincur contiguous block
  k_bhist<<<512, 256, 0, stream>>>(ei, ghist);
  k_b196scan<<<1, 256, 0, stream>>>(ghist, gcur, bexclB, csr_off);
  k_split<<<(EE + 4095) / 4096, 256, 0, stream>>>(ei, gcur, pairs);
  k_bbuild<<<NBK, 256, 0, stream>>>(pairs, bexclB, cnt, csr_off, dis, csr_src);

  // ---- degree sort ----
  k_hist<<<(NN + 255) / 256, 256, 0, stream>>>(cnt, hist);
  k_binscan<<<1, 64, 0, stream>>>(hist, bincur);
  k_scatter<<<(NN + 255) / 256, 256, 0, stream>>>(cnt, bincur, perm);

  // ---- fused prep ----
  k_prep<<<PREP_B0 + PREP_B1 + 16 + 128, 256, 0, stream>>>(
      x, s1wl, s1wr, s2wl, s2wr, x12h, A32, w1h, w2h);

  // ---- SAGE chain ----
  k_gmean12h<<<(NN + 63) / 64, 256, 0, stream>>>(x12h, perm, csr_off, csr_src, A32);
  k_mm1_mfma<<<(NN + 127) / 128, 256, 0, stream>>>(A32, w1h, s1b, x1a_h);
  k_gather128<<<(NN + 15) / 16, 256, 0, stream>>>(x1a_h, perm, csr_off, csr_src, mean128_h);
  k_mm2_mfma<<<(NN + 127) / 128, 256, 0, stream>>>(mean128_h, x1a_h, w2h, s2b, s3wl, s3wr, pp, qq);

  // ---- cooperative TAG phase (tagP8, x1s, all hops, tagP1s, final) ----
  CoopArgs ca;
  ca.csr_off = csr_off; ca.csr_src = csr_src; ca.perm = perm; ca.dis = dis;
  ca.x = x;
  ca.t1aw = t1aw; ca.t1ab = t1ab; ca.t1bw = t1bw; ca.t1bb = t1bb;
  ca.t2aw = t2aw; ca.t2ab = t2ab; ca.t2bw = t2bw; ca.t2bb = t2bb;
  ca.pp = pp; ca.qq = qq; ca.s3b = s3b;
  ca.lw = lw; ca.lb = lb;
  ca.Pa = Pa; ca.PTop = PTop; ca.zbuf0 = zbuf0; ca.zbuf1 = zbuf1;
  ca.x2a = x2a; ca.P2 = P2;
  ca.Pb = Pb; ca.x3a = x3a; ca.P2b = P2b;
  ca.x1s = x1s; ca.x2s = x2s;
  ca.uA1 = uA1; ca.uA2 = uA2; ca.uB1 = uB1; ca.uB2 = uB2;
  ca.out = out;

  int maxBlocksPerCU = 0;
  hipOccupancyMaxActiveBlocksPerMultiprocessor(&maxBlocksPerCU, k_coop, 256, 0);
  int GRID = (maxBlocksPerCU > 0) ? maxBlocksPerCU * 256 : 256;
  if (GRID > 1024) GRID = 1024;
  if (GRID < 64) GRID = 64;
  void* kargs[] = { &ca };
  hipLaunchCooperativeKernel((const void*)k_coop, dim3(GRID), dim3(256), kargs, 0, stream);
}

// Round 8
// 509.041 us; speedup vs baseline: 2.8727x; 2.8727x over previous
//
#include <hip/hip_runtime.h>
#include <hip/hip_bf16.h>
#include <hip/hip_fp16.h>

#define NN 100000
#define EE 1600000
#define NBIN 64
#define BSH 9
#define BSZ 512
#define NBK 196   // ceil(NN/512)

typedef _Float16 h8v __attribute__((ext_vector_type(8)));
typedef float f4v __attribute__((ext_vector_type(4)));

__device__ __forceinline__ float sigm(float v) { return 1.0f / (1.0f + expf(-v)); }
__device__ __forceinline__ float4 f4add(float4 a, float4 b) {
  a.x += b.x; a.y += b.y; a.z += b.z; a.w += b.w; return a;
}
__device__ __forceinline__ float4 h4f(uint2 v) {
  __half2 a = *reinterpret_cast<__half2*>(&v.x);
  __half2 b = *reinterpret_cast<__half2*>(&v.y);
  float2 fa = __half22float2(a), fb = __half22float2(b);
  return make_float4(fa.x, fa.y, fb.x, fb.y);
}
__device__ __forceinline__ void h8acc(uint4 v, float* a) {
  float4 lo = h4f(make_uint2(v.x, v.y));
  float4 hi = h4f(make_uint2(v.z, v.w));
  a[0] += lo.x; a[1] += lo.y; a[2] += lo.z; a[3] += lo.w;
  a[4] += hi.x; a[5] += hi.y; a[6] += hi.z; a[7] += hi.w;
}
__device__ __forceinline__ uint2 pack4h(float4 r) {
  __half2 q0 = __floats2half2_rn(r.x, r.y), q1 = __floats2half2_rn(r.z, r.w);
  uint2 o; o.x = *(unsigned*)&q0; o.y = *(unsigned*)&q1; return o;
}

// ================= CSR build + fused prep =================
#define BH_B 512
#define PREP_B0 ((NN * 12 + 255) / 256)
#define PREP_B1 ((NN + 255) / 256)
__global__ __launch_bounds__(256) void k_bhist_prep(
    const int* __restrict__ ei, int* __restrict__ ghist,
    const float* __restrict__ x, const float* __restrict__ s1wl, const float* __restrict__ s1wr,
    const float* __restrict__ s2wl, const float* __restrict__ s2wr,
    __half* __restrict__ x12h, __half* __restrict__ A32,
    __half* __restrict__ w1h, __half* __restrict__ w2h) {
  __shared__ int lh[NBK];
  int bid = blockIdx.x;
  if (bid < BH_B) {
    for (int j = threadIdx.x; j < NBK; j += 256) lh[j] = 0;
    __syncthreads();
    for (int i = bid * 256 + threadIdx.x; i < EE; i += BH_B * 256)
      atomicAdd(&lh[ei[EE + i] >> BSH], 1);
    __syncthreads();
    for (int j = threadIdx.x; j < NBK; j += 256) {
      int v = lh[j];
      if (v) atomicAdd(&ghist[j], v);
    }
    return;
  }
  int pid = bid - BH_B;
  if (pid < PREP_B0) {
    int i = pid * 256 + threadIdx.x;
    if (i < NN * 12) {
      int n = i / 12, j = i - n * 12;
      x12h[i] = __float2half((j < 11) ? x[n * 11 + j] : 0.0f);
    }
  } else if (pid < PREP_B0 + PREP_B1) {
    int i = (pid - PREP_B0) * 256 + threadIdx.x;
    if (i < NN) {
      float a[11];
      #pragma unroll
      for (int j = 0; j < 11; ++j) a[j] = x[(long)i * 11 + j];
      uint2* row = (uint2*)(A32 + (long)i * 32);
      row[3] = make_uint2(0u, 0u);
      row[4] = pack4h(make_float4(a[0], a[1], a[2], a[3]));
      row[5] = pack4h(make_float4(a[4], a[5], a[6], a[7]));
      row[6] = pack4h(make_float4(a[8], a[9], a[10], 0.0f));
      row[7] = make_uint2(0u, 0u);
    }
  } else if (pid < PREP_B0 + PREP_B1 + 16) {
    int i = (pid - PREP_B0 - PREP_B1) * 256 + threadIdx.x;
    int o = i >> 5, k = i & 31;
    float v = 0.0f;
    if (k < 11) v = s1wl[o * 11 + k];
    else if (k >= 16 && k < 27) v = s1wr[o * 11 + (k - 16)];
    w1h[i] = __float2half(v);
  } else {
    int i = (pid - PREP_B0 - PREP_B1 - 16) * 256 + threadIdx.x;
    int o = i >> 8, k = i & 255;
    float v = (k < 128) ? s2wl[o * 128 + k] : s2wr[o * 128 + (k - 128)];
    w2h[i] = __float2half(v);
  }
}

__global__ void k_b196scan(const int* __restrict__ ghist, int* __restrict__ gcur,
                           int* __restrict__ bexclB, int* __restrict__ csr_off) {
  __shared__ int sh[256];
  int tid = threadIdx.x;
  int v = (tid < NBK) ? ghist[tid] : 0;
  sh[tid] = v;
  __syncthreads();
  for (int d = 1; d < 256; d <<= 1) {
    int t = (tid >= d) ? sh[tid - d] : 0;
    __syncthreads();
    sh[tid] += t;
    __syncthreads();
  }
  int excl = sh[tid] - v;
  if (tid < NBK) { gcur[tid] = excl; bexclB[tid] = excl; }
  if (tid == 0) { bexclB[NBK] = EE; csr_off[NN] = EE; }
}

// WG-local 196-way multi-split; packed u32 = src | (dst_lo << 17)
__global__ __launch_bounds__(256) void k_split(const int* __restrict__ ei,
                                               int* __restrict__ gcur,
                                               unsigned* __restrict__ pairs) {
  __shared__ int cntL[256];
  __shared__ int segO[256];
  __shared__ int curL[256];
  __shared__ int baseL[256];
  __shared__ unsigned stag[4096];
  __shared__ unsigned char bktL[4096];
  int tid = threadIdx.x;
  int tile0 = blockIdx.x * 4096;
  int tcnt = min(4096, EE - tile0);
  cntL[tid] = 0; curL[tid] = 0;
  __syncthreads();
  for (int i = tid; i < tcnt; i += 256)
    atomicAdd(&cntL[ei[EE + tile0 + i] >> BSH], 1);
  __syncthreads();
  int v = cntL[tid];
  segO[tid] = v;
  __syncthreads();
  for (int d = 1; d < 256; d <<= 1) {
    int t = (tid >= d) ? segO[tid - d] : 0;
    __syncthreads();
    segO[tid] += t;
    __syncthreads();
  }
  int excl = segO[tid] - v;
  __syncthreads();
  segO[tid] = excl;
  __syncthreads();
  for (int i = tid; i < tcnt; i += 256) {
    int s = ei[tile0 + i], dd = ei[EE + tile0 + i];
    int b = dd >> BSH;
    int slot = segO[b] + atomicAdd(&curL[b], 1);
    stag[slot] = (unsigned)s | ((unsigned)(dd & (BSZ - 1)) << 17);
    bktL[slot] = (unsigned char)b;
  }
  baseL[tid] = v ? atomicAdd(&gcur[tid], v) : 0;
  __syncthreads();
  for (int i = tid; i < tcnt; i += 256) {
    int b = bktL[i];
    pairs[baseL[b] + (i - segO[b])] = stag[i];
  }
}

// fused per-bucket count + scan + fill
__global__ __launch_bounds__(256) void k_bbuild(const unsigned* __restrict__ pairs,
                                                const int* __restrict__ bexclB,
                                                int* __restrict__ cnt, int* __restrict__ csr_off,
                                                float* __restrict__ dis, int* __restrict__ csr_src) {
  __shared__ int c[BSZ];
  __shared__ int ps[256];
  __shared__ int curB[BSZ];
  int tid = threadIdx.x;
  int b = blockIdx.x;
  int lo = b << BSH;
  for (int j = tid; j < BSZ; j += 256) c[j] = 0;
  __syncthreads();
  int s0e = bexclB[b], s1e = bexclB[b + 1];
  for (int i = s0e + tid; i < s1e; i += 256)
    atomicAdd(&c[pairs[i] >> 17], 1);
  __syncthreads();
  int a0 = c[2 * tid], a1 = c[2 * tid + 1];
  int pv = a0 + a1;
  ps[tid] = pv;
  __syncthreads();
  for (int d = 1; d < 256; d <<= 1) {
    int t = (tid >= d) ? ps[tid - d] : 0;
    __syncthreads();
    ps[tid] += t;
    __syncthreads();
  }
  int pex = ps[tid] - pv;
  int base = s0e + pex;
  int n0 = lo + 2 * tid, n1 = n0 + 1;
  if (n0 < NN) {
    csr_off[n0] = base; cnt[n0] = a0;
    dis[n0] = (a0 > 0) ? rsqrtf((float)a0) : 0.0f;
  }
  if (n1 < NN) {
    csr_off[n1] = base + a0; cnt[n1] = a1;
    dis[n1] = (a1 > 0) ? rsqrtf((float)a1) : 0.0f;
  }
  curB[2 * tid] = base;
  curB[2 * tid + 1] = base + a0;
  __syncthreads();
  for (int i = s0e + tid; i < s1e; i += 256) {
    unsigned pk = pairs[i];
    int p = atomicAdd(&curB[pk >> 17], 1);
    csr_src[p] = (int)(pk & 0x1FFFFu);
  }
}

// ================= degree sort (perm) =================
__global__ __launch_bounds__(256) void k_hist(const int* __restrict__ cnt, int* __restrict__ hist) {
  __shared__ int lh[NBIN];
  if (threadIdx.x < NBIN) lh[threadIdx.x] = 0;
  __syncthreads();
  int i = blockIdx.x * 256 + threadIdx.x;
  if (i < NN) atomicAdd(&lh[min(cnt[i], NBIN - 1)], 1);
  __syncthreads();
  if (threadIdx.x < NBIN) {
    int v = lh[threadIdx.x];
    if (v) atomicAdd(&hist[threadIdx.x], v);
  }
}
__global__ void k_binscan(const int* __restrict__ hist, int* __restrict__ bincur) {
  int tid = threadIdx.x;
  int v = hist[tid];
  int incl = v;
  for (int d = 1; d < 64; d <<= 1) {
    int t = __shfl_up(incl, d, 64);
    if (tid >= d) incl += t;
  }
  bincur[tid] = incl - v;
}
__global__ __launch_bounds__(256) void k_scatter(const int* __restrict__ cnt,
                                                 int* __restrict__ bincur,
                                                 int* __restrict__ perm) {
  __shared__ int lh[NBIN];
  __shared__ int lbase[NBIN];
  if (threadIdx.x < NBIN) lh[threadIdx.x] = 0;
  __syncthreads();
  int i = blockIdx.x * 256 + threadIdx.x;
  int b = 0, r = 0;
  bool valid = i < NN;
  if (valid) {
    b = min(cnt[i], NBIN - 1);
    r = atomicAdd(&lh[b], 1);
  }
  __syncthreads();
  if (threadIdx.x < NBIN) {
    int v = lh[threadIdx.x];
    lbase[threadIdx.x] = v ? atomicAdd(&bincur[threadIdx.x], v) : 0;
  }
  __syncthreads();
  if (valid) perm[lbase[b] + r] = i;
}

// ================= SAGE gathers =================
__global__ void k_gmean12h(const __half* __restrict__ x12h, const int* __restrict__ perm,
                           const int* __restrict__ off, const int* __restrict__ srcarr,
                           __half* __restrict__ A32) {
  int g = blockIdx.x * 64 + (threadIdx.x >> 2);
  int t = threadIdx.x & 3;
  if (g >= NN || t >= 3) return;
  int node = perm[g];
  int s = off[node], e = off[node + 1];
  const uint2* h2 = (const uint2*)x12h;
  float4 acc = {0, 0, 0, 0};
  int p = s;
  for (; p + 4 <= e; p += 4) {
    int s0 = srcarr[p], s1 = srcarr[p + 1], s2 = srcarr[p + 2], s3 = srcarr[p + 3];
    acc = f4add(acc, f4add(f4add(h4f(h2[(long)s0 * 3 + t]), h4f(h2[(long)s1 * 3 + t])),
                           f4add(h4f(h2[(long)s2 * 3 + t]), h4f(h2[(long)s3 * 3 + t]))));
  }
  for (; p < e; ++p) acc = f4add(acc, h4f(h2[(long)srcarr[p] * 3 + t]));
  int c = e - s;
  float inv = 1.0f / (float)(c > 0 ? c : 1);
  acc.x *= inv; acc.y *= inv; acc.z *= inv; acc.w *= inv;
  ((uint2*)A32)[(long)node * 8 + t] = pack4h(acc);
}

__global__ void k_gather128(const __half* __restrict__ h, const int* __restrict__ perm,
                            const int* __restrict__ off, const int* __restrict__ srcarr,
                            __half* __restrict__ outh) {
  int g = blockIdx.x * 16 + (threadIdx.x >> 4);
  int t = threadIdx.x & 15;
  if (g >= NN) return;
  int node = perm[g];
  int s = off[node], e = off[node + 1];
  const uint4* h4 = (const uint4*)h;
  float acc[8] = {};
  int p = s;
  for (; p + 4 <= e; p += 4) {
    int s0 = srcarr[p], s1 = srcarr[p + 1], s2 = srcarr[p + 2], s3 = srcarr[p + 3];
    uint4 r0 = h4[(long)s0 * 16 + t], r1 = h4[(long)s1 * 16 + t];
    uint4 r2 = h4[(long)s2 * 16 + t], r3 = h4[(long)s3 * 16 + t];
    h8acc(r0, acc); h8acc(r1, acc); h8acc(r2, acc); h8acc(r3, acc);
  }
  for (; p < e; ++p) h8acc(h4[(long)srcarr[p] * 16 + t], acc);
  int c = e - s;
  float inv = 1.0f / (float)(c > 0 ? c : 1);
  uint2 lo = pack4h(make_float4(acc[0] * inv, acc[1] * inv, acc[2] * inv, acc[3] * inv));
  uint2 hi = pack4h(make_float4(acc[4] * inv, acc[5] * inv, acc[6] * inv, acc[7] * inv));
  uint4 o; o.x = lo.x; o.y = lo.y; o.z = hi.x; o.w = hi.y;
  ((uint4*)outh)[(long)node * 16 + t] = o;
}

// ================= SAGE MFMA layers =================
__global__ __launch_bounds__(256) void k_mm1_mfma(
    const __half* __restrict__ A32, const __half* __restrict__ W32,
    const float* __restrict__ bias, __half* __restrict__ out) {
  __shared__ __half lt[4][32][136];
  int tid = threadIdx.x;
  int wave = tid >> 6, l = tid & 63;
  int lr = l & 15, lk = l >> 4;
  int m0 = blockIdx.x * 128 + wave * 32;
  f4v acc[2][8] = {};
  h8v afrag[2];
  #pragma unroll
  for (int rt = 0; rt < 2; ++rt) {
    int row = m0 + rt * 16 + lr;
    h8v z = {};
    afrag[rt] = (row < NN) ? *(const h8v*)&A32[(long)row * 32 + lk * 8] : z;
  }
  #pragma unroll
  for (int c = 0; c < 8; ++c) {
    h8v bfrag = *(const h8v*)&W32[(c * 16 + lr) * 32 + lk * 8];
    acc[0][c] = __builtin_amdgcn_mfma_f32_16x16x32_f16(afrag[0], bfrag, acc[0][c], 0, 0, 0);
    acc[1][c] = __builtin_amdgcn_mfma_f32_16x16x32_f16(afrag[1], bfrag, acc[1][c], 0, 0, 0);
  }
  float bi[8];
  #pragma unroll
  for (int c = 0; c < 8; ++c) bi[c] = bias[c * 16 + lr];
  #pragma unroll
  for (int rt = 0; rt < 2; ++rt)
    #pragma unroll
    for (int c = 0; c < 8; ++c)
      #pragma unroll
      for (int reg = 0; reg < 4; ++reg) {
        float v = acc[rt][c][reg] + bi[c];
        lt[wave][rt * 16 + lk * 4 + reg][c * 16 + lr] = __float2half(sigm(v));
      }
  __syncthreads();
  #pragma unroll
  for (int it = 0; it < 8; ++it) {
    int idx = it * 64 + l;
    int row = idx >> 4, c16 = idx & 15;
    int grow = m0 + row;
    if (grow < NN) {
      uint4 v = *(const uint4*)&lt[wave][row][c16 * 8];
      ((uint4*)out)[(long)grow * 16 + c16] = v;
    }
  }
}

__global__ __launch_bounds__(256) void k_mm2_mfma(
    const __half* __restrict__ A1, const __half* __restrict__ A2,
    const __half* __restrict__ W, const float* __restrict__ bias,
    const float* __restrict__ w3l, const float* __restrict__ w3r,
    float* __restrict__ pp, float* __restrict__ qq) {
  int tid = threadIdx.x;
  int wave = tid >> 6;
  int l = tid & 63;
  int lr = l & 15;
  int lk = l >> 4;
  int m0 = blockIdx.x * 128 + wave * 32;
  f4v acc[2][8] = {};
  #pragma unroll
  for (int ks = 0; ks < 8; ++ks) {
    const __half* Asrc = (ks < 4) ? A1 : A2;
    int kk = (ks & 3) * 32 + lk * 8;
    h8v afrag[2];
    #pragma unroll
    for (int rt = 0; rt < 2; ++rt) {
      int row = m0 + rt * 16 + lr;
      h8v z = {};
      afrag[rt] = (row < NN) ? *(const h8v*)&Asrc[(long)row * 128 + kk] : z;
    }
    #pragma unroll
    for (int c = 0; c < 8; ++c) {
      h8v bfrag = *(const h8v*)&W[(long)(c * 16 + lr) * 256 + ks * 32 + lk * 8];
      acc[0][c] = __builtin_amdgcn_mfma_f32_16x16x32_f16(afrag[0], bfrag, acc[0][c], 0, 0, 0);
      acc[1][c] = __builtin_amdgcn_mfma_f32_16x16x32_f16(afrag[1], bfrag, acc[1][c], 0, 0, 0);
    }
  }
  float wl[8], wr[8], bi[8];
  #pragma unroll
  for (int c = 0; c < 8; ++c) {
    wl[c] = w3l[c * 16 + lr];
    wr[c] = w3r[c * 16 + lr];
    bi[c] = bias[c * 16 + lr];
  }
  #pragma unroll
  for (int rt = 0; rt < 2; ++rt) {
    #pragma unroll
    for (int reg = 0; reg < 4; ++reg) {
      float s1 = 0.0f, s2 = 0.0f;
      #pragma unroll
      for (int c = 0; c < 8; ++c) {
        float v = acc[rt][c][reg] + bi[c];
        float sg = sigm(v);
        s1 += sg * wl[c];
        s2 += sg * wr[c];
      }
      #pragma unroll
      for (int d = 1; d < 16; d <<= 1) {
        s1 += __shfl_xor(s1, d, 64);
        s2 += __shfl_xor(s2, d, 64);
      }
      int row = m0 + rt * 16 + lk * 4 + reg;
      if (lr == 0 && row < NN) { pp[row] = s1; qq[row] = s2; }
    }
  }
}

// ================= TAG phase (discrete kernels) =================
// L0: tagP8 (both chains, interleaved top) + x1s mean-hop
__global__ __launch_bounds__(256) void k_tag0(
    const float* __restrict__ x, const float* __restrict__ t1aw, const float* __restrict__ t1bw,
    const float* __restrict__ dis,
    float* __restrict__ Pa, float* __restrict__ Pb, __half* __restrict__ PTop,
    const float* __restrict__ pp, const float* __restrict__ qq, const float* __restrict__ s3b,
    const int* __restrict__ perm, const int* __restrict__ csr_off, const int* __restrict__ csr_src,
    float* __restrict__ x1s) {
  for (int i = blockIdx.x * 256 + threadIdx.x; i < NN; i += gridDim.x * 256) {
    float a[11];
    #pragma unroll
    for (int j = 0; j < 11; ++j) a[j] = x[(long)i * 11 + j];
    float dn = dis[i];
    #pragma unroll
    for (int k = 0; k < 4; ++k) {
      float s[8];
      #pragma unroll
      for (int o = 0; o < 8; ++o) {
        float acc = 0.0f;
        #pragma unroll
        for (int j = 0; j < 11; ++j) acc += a[j] * t1aw[o * 44 + k * 11 + j];
        s[o] = acc;
      }
      if (k < 3) {
        float4* dst = (float4*)&Pa[((size_t)k * NN + i) * 8];
        dst[0] = make_float4(s[0], s[1], s[2], s[3]);
        dst[1] = make_float4(s[4], s[5], s[6], s[7]);
      } else {
        uint2 lo = pack4h(make_float4(s[0] * dn, s[1] * dn, s[2] * dn, s[3] * dn));
        uint2 hi = pack4h(make_float4(s[4] * dn, s[5] * dn, s[6] * dn, s[7] * dn));
        uint4 o4; o4.x = lo.x; o4.y = lo.y; o4.z = hi.x; o4.w = hi.y;
        ((uint4*)PTop)[(long)i * 2] = o4;
      }
    }
    #pragma unroll
    for (int k = 0; k < 7; ++k) {
      float s[8];
      #pragma unroll
      for (int o = 0; o < 8; ++o) {
        float acc = 0.0f;
        #pragma unroll
        for (int j = 0; j < 11; ++j) acc += a[j] * t1bw[o * 77 + k * 11 + j];
        s[o] = acc;
      }
      if (k < 6) {
        float4* dst = (float4*)&Pb[((size_t)k * NN + i) * 8];
        dst[0] = make_float4(s[0], s[1], s[2], s[3]);
        dst[1] = make_float4(s[4], s[5], s[6], s[7]);
      } else {
        uint2 lo = pack4h(make_float4(s[0] * dn, s[1] * dn, s[2] * dn, s[3] * dn));
        uint2 hi = pack4h(make_float4(s[4] * dn, s[5] * dn, s[6] * dn, s[7] * dn));
        uint4 o4; o4.x = lo.x; o4.y = lo.y; o4.z = hi.x; o4.w = hi.y;
        ((uint4*)PTop)[(long)i * 2 + 1] = o4;
      }
    }
  }
  int t = threadIdx.x & 3;
  for (int g = blockIdx.x * 64 + (threadIdx.x >> 2); g < NN; g += gridDim.x * 64) {
    int node = perm[g];
    int s = csr_off[node], e = csr_off[node + 1];
    float acc = 0.0f;
    for (int p = s + t; p < e; p += 4) acc += pp[csr_src[p]];
    acc += __shfl_xor(acc, 1, 64); acc += __shfl_xor(acc, 2, 64);
    if (t == 0) {
      int c = e - s;
      float sc = 1.0f / (float)(c > 0 ? c : 1);
      x1s[node] = fmaxf(acc * sc + qq[node] + s3b[0], 0.0f);
    }
  }
}

// dual D8 hop, interleaved [A|B] uint4 rows, both lanes act3 (prescale)
__global__ __launch_bounds__(256) void k_d8_dual(
    const __half* __restrict__ src, const float* __restrict__ addA,
    const float* __restrict__ addB, __half* __restrict__ dst,
    const int* __restrict__ perm, const int* __restrict__ off,
    const int* __restrict__ srcarr, const float* __restrict__ dis) {
  const uint4* src4 = (const uint4*)src;
  int t = threadIdx.x & 1;
  const float4* addp = (const float4*)(t == 0 ? addA : addB);
  int g = blockIdx.x * 128 + (threadIdx.x >> 1);
  if (g >= NN) return;
  int node = perm[g];
  int s = off[node], e = off[node + 1];
  float acc[8] = {};
  int p = s;
  for (; p + 4 <= e; p += 4) {
    int s0 = srcarr[p], s1 = srcarr[p + 1], s2 = srcarr[p + 2], s3 = srcarr[p + 3];
    h8acc(src4[(long)s0 * 2 + t], acc); h8acc(src4[(long)s1 * 2 + t], acc);
    h8acc(src4[(long)s2 * 2 + t], acc); h8acc(src4[(long)s3 * 2 + t], acc);
  }
  for (; p < e; ++p) h8acc(src4[(long)srcarr[p] * 2 + t], acc);
  float dn = dis[node];
  float4 a0 = addp[(long)node * 2], a1 = addp[(long)node * 2 + 1];
  float4 r0 = make_float4((acc[0] * dn + a0.x) * dn, (acc[1] * dn + a0.y) * dn,
                          (acc[2] * dn + a0.z) * dn, (acc[3] * dn + a0.w) * dn);
  float4 r1 = make_float4((acc[4] * dn + a1.x) * dn, (acc[5] * dn + a1.y) * dn,
                          (acc[6] * dn + a1.z) * dn, (acc[7] * dn + a1.w) * dn);
  uint2 lo = pack4h(r0), hi = pack4h(r1);
  uint4 o; o.x = lo.x; o.y = lo.y; o.z = hi.x; o.w = hi.y;
  ((uint4*)dst)[(long)node * 2 + t] = o;
}

// L3: lane0 -> sigmoid(A) + fused tagP1<4> -> P2; lane1 -> dstB B-half act3
__global__ __launch_bounds__(256) void k_d8_l3(
    const __half* __restrict__ src, const float* __restrict__ Pa0,
    const float* __restrict__ t1ab, const float* __restrict__ t2aw,
    const float* __restrict__ Pb3, __half* __restrict__ dstB, float* __restrict__ P2,
    const int* __restrict__ perm, const int* __restrict__ off,
    const int* __restrict__ srcarr, const float* __restrict__ dis) {
  const uint4* src4 = (const uint4*)src;
  int t = threadIdx.x & 1;
  int g = blockIdx.x * 128 + (threadIdx.x >> 1);
  if (g >= NN) return;
  int node = perm[g];
  int s = off[node], e = off[node + 1];
  float acc[8] = {};
  int p = s;
  for (; p + 4 <= e; p += 4) {
    int s0 = srcarr[p], s1 = srcarr[p + 1], s2 = srcarr[p + 2], s3 = srcarr[p + 3];
    h8acc(src4[(long)s0 * 2 + t], acc); h8acc(src4[(long)s1 * 2 + t], acc);
    h8acc(src4[(long)s2 * 2 + t], acc); h8acc(src4[(long)s3 * 2 + t], acc);
  }
  for (; p < e; ++p) h8acc(src4[(long)srcarr[p] * 2 + t], acc);
  float dn = dis[node];
  if (t == 0) {
    const float4* addp = (const float4*)Pa0;
    float4 a0 = addp[(long)node * 2], a1 = addp[(long)node * 2 + 1];
    float4 b0 = ((const float4*)t1ab)[0], b1 = ((const float4*)t1ab)[1];
    float a[8];
    a[0] = sigm(acc[0] * dn + a0.x + b0.x); a[1] = sigm(acc[1] * dn + a0.y + b0.y);
    a[2] = sigm(acc[2] * dn + a0.z + b0.z); a[3] = sigm(acc[3] * dn + a0.w + b0.w);
    a[4] = sigm(acc[4] * dn + a1.x + b1.x); a[5] = sigm(acc[5] * dn + a1.y + b1.y);
    a[6] = sigm(acc[6] * dn + a1.z + b1.z); a[7] = sigm(acc[7] * dn + a1.w + b1.w);
    #pragma unroll
    for (int k = 0; k < 4; ++k) {
      float sv = 0.0f;
      #pragma unroll
      for (int j = 0; j < 8; ++j) sv += a[j] * t2aw[k * 8 + j];
      if (k == 3) sv *= dn;
      P2[(size_t)k * NN + node] = sv;
    }
  } else {
    const float4* addp = (const float4*)Pb3;
    float4 a0 = addp[(long)node * 2], a1 = addp[(long)node * 2 + 1];
    float4 r0 = make_float4((acc[0] * dn + a0.x) * dn, (acc[1] * dn + a0.y) * dn,
                            (acc[2] * dn + a0.z) * dn, (acc[3] * dn + a0.w) * dn);
    float4 r1 = make_float4((acc[4] * dn + a1.x) * dn, (acc[5] * dn + a1.y) * dn,
                            (acc[6] * dn + a1.z) * dn, (acc[7] * dn + a1.w) * dn);
    uint2 lo = pack4h(r0), hi = pack4h(r1);
    uint4 o; o.x = lo.x; o.y = lo.y; o.z = hi.x; o.w = hi.y;
    ((uint4*)dstB)[(long)node * 2 + 1] = o;
  }
}

// single-B D8 hop (reads B half = uint2 slots 2,3), act3
__global__ __launch_bounds__(256) void k_d8_single(
    const __half* __restrict__ src, const float* __restrict__ addB, __half* __restrict__ dst,
    const int* __restrict__ perm, const int* __restrict__ off,
    const int* __restrict__ srcarr, const float* __restrict__ dis) {
  const uint2* src2 = (const uint2*)src;
  int t = threadIdx.x & 1;
  int g = blockIdx.x * 128 + (threadIdx.x >> 1);
  if (g >= NN) return;
  int node = perm[g];
  int s = off[node], e = off[node + 1];
  float4 acc = {0, 0, 0, 0};
  int p = s;
  for (; p + 4 <= e; p += 4) {
    int s0 = srcarr[p], s1 = srcarr[p + 1], s2 = srcarr[p + 2], s3 = srcarr[p + 3];
    acc = f4add(acc, f4add(f4add(h4f(src2[(long)s0 * 4 + 2 + t]), h4f(src2[(long)s1 * 4 + 2 + t])),
                           f4add(h4f(src2[(long)s2 * 4 + 2 + t]), h4f(src2[(long)s3 * 4 + 2 + t]))));
  }
  for (; p < e; ++p) acc = f4add(acc, h4f(src2[(long)srcarr[p] * 4 + 2 + t]));
  float dn = dis[node];
  float4 av = ((const float4*)addB)[(long)node * 2 + t];
  float4 r = make_float4((acc.x * dn + av.x) * dn, (acc.y * dn + av.y) * dn,
                         (acc.z * dn + av.z) * dn, (acc.w * dn + av.w) * dn);
  ((uint2*)dst)[(long)node * 4 + 2 + t] = pack4h(r);
}

// L6: single-B + sigmoid + fused tagP1<7> -> P2b (shfl to collect partner half)
__global__ __launch_bounds__(256) void k_d8_l6(
    const __half* __restrict__ src, const float* __restrict__ Pb0,
    const float* __restrict__ t1bb, const float* __restrict__ t2bw, float* __restrict__ P2b,
    const int* __restrict__ perm, const int* __restrict__ off,
    const int* __restrict__ srcarr, const float* __restrict__ dis) {
  const uint2* src2 = (const uint2*)src;
  int t = threadIdx.x & 1;
  int g = blockIdx.x * 128 + (threadIdx.x >> 1);
  if (g >= NN) return;
  int node = perm[g];
  int s = off[node], e = off[node + 1];
  float4 acc = {0, 0, 0, 0};
  int p = s;
  for (; p + 4 <= e; p += 4) {
    int s0 = srcarr[p], s1 = srcarr[p + 1], s2 = srcarr[p + 2], s3 = srcarr[p + 3];
    acc = f4add(acc, f4add(f4add(h4f(src2[(long)s0 * 4 + 2 + t]), h4f(src2[(long)s1 * 4 + 2 + t])),
                           f4add(h4f(src2[(long)s2 * 4 + 2 + t]), h4f(src2[(long)s3 * 4 + 2 + t]))));
  }
  for (; p < e; ++p) acc = f4add(acc, h4f(src2[(long)srcarr[p] * 4 + 2 + t]));
  float dn = dis[node];
  float4 av = ((const float4*)Pb0)[(long)node * 2 + t];
  float4 bv = ((const float4*)t1bb)[t];
  float4 r = make_float4(sigm(acc.x * dn + av.x + bv.x), sigm(acc.y * dn + av.y + bv.y),
                         sigm(acc.z * dn + av.z + bv.z), sigm(acc.w * dn + av.w + bv.w));
  float o0 = __shfl_xor(r.x, 1, 64), o1 = __shfl_xor(r.y, 1, 64);
  float o2 = __shfl_xor(r.z, 1, 64), o3 = __shfl_xor(r.w, 1, 64);
  if (t == 0) {
    float a[8] = {r.x, r.y, r.z, r.w, o0, o1, o2, o3};
    #pragma unroll
    for (int k = 0; k < 7; ++k) {
      float sv = 0.0f;
      #pragma unroll
      for (int j = 0; j < 8; ++j) sv += a[j] * t2bw[k * 8 + j];
      if (k == 6) sv *= dn;
      P2b[(size_t)k * NN + node] = sv;
    }
  }
}

// D1 gathers, pre-scaled f32 streams
template<int MODE>
__global__ void k_g1_dual(
    const float* __restrict__ ua, const float* __restrict__ adda,
    const float* __restrict__ biasa, int acta,
    const float* __restrict__ ub, const float* __restrict__ addb,
    const float* __restrict__ biasb, int actb,
    const int* __restrict__ perm, const int* __restrict__ off,
    const int* __restrict__ srcarr, const float* __restrict__ dis,
    float* __restrict__ outa, float* __restrict__ outb) {
  int g = blockIdx.x * 64 + (threadIdx.x >> 2);
  int t = threadIdx.x & 3;
  if (g >= NN) return;
  int node = perm[g];
  int s = off[node], e = off[node + 1];
  float accA = 0.0f, accB = 0.0f;
  for (int p = s + t; p < e; p += 4) {
    int s0 = srcarr[p];
    accA += ua[s0];
    accB += ub[s0];
  }
  accA += __shfl_xor(accA, 1, 64); accA += __shfl_xor(accA, 2, 64);
  accB += __shfl_xor(accB, 1, 64); accB += __shfl_xor(accB, 2, 64);
  if (t == 0) {
    float sc;
    if (MODE == 0) { int c = e - s; sc = 1.0f / (float)(c > 0 ? c : 1); }
    else sc = dis[node];
    float rA = accA * sc + adda[node];
    if (biasa) rA += biasa[0];
    if (acta == 3) rA *= sc; else if (acta == 2) rA = fmaxf(rA, 0.0f);
    outa[node] = rA;
    float rB = accB * sc + addb[node];
    if (biasb) rB += biasb[0];
    if (actb == 3) rB *= sc; else if (actb == 2) rB = fmaxf(rB, 0.0f);
    outb[node] = rB;
  }
}

template<int MODE>
__global__ void k_g1_single(
    const float* __restrict__ ua, const float* __restrict__ adda,
    const float* __restrict__ biasa, int acta,
    const int* __restrict__ perm, const int* __restrict__ off,
    const int* __restrict__ srcarr, const float* __restrict__ dis,
    float* __restrict__ outa) {
  int g = blockIdx.x * 64 + (threadIdx.x >> 2);
  int t = threadIdx.x & 3;
  if (g >= NN) return;
  int node = perm[g];
  int s = off[node], e = off[node + 1];
  float accA = 0.0f;
  for (int p = s + t; p < e; p += 4) accA += ua[srcarr[p]];
  accA += __shfl_xor(accA, 1, 64); accA += __shfl_xor(accA, 2, 64);
  if (t == 0) {
    float sc;
    if (MODE == 0) { int c = e - s; sc = 1.0f / (float)(c > 0 ? c : 1); }
    else sc = dis[node];
    float rA = accA * sc + adda[node];
    if (biasa) rA += biasa[0];
    if (acta == 3) rA *= sc; else if (acta == 2) rA = fmaxf(rA, 0.0f);
    outa[node] = rA;
  }
}

__global__ void k_g1_final(
    const float* __restrict__ ua, const float* __restrict__ adda,
    const float* __restrict__ biasa,
    const float* __restrict__ x1s, const float* __restrict__ x2s,
    const float* __restrict__ lw, const float* __restrict__ lb,
    const int* __restrict__ perm, const int* __restrict__ off,
    const int* __restrict__ srcarr, const float* __restrict__ dis,
    float* __restrict__ out) {
  int g = blockIdx.x * 64 + (threadIdx.x >> 2);
  int t = threadIdx.x & 3;
  if (g >= NN) return;
  int node = perm[g];
  int s = off[node], e = off[node + 1];
  float accA = 0.0f;
  for (int p = s + t; p < e; p += 4) accA += ua[srcarr[p]];
  accA += __shfl_xor(accA, 1, 64); accA += __shfl_xor(accA, 2, 64);
  if (t == 0) {
    float x3v = fmaxf(accA * dis[node] + adda[node] + biasa[0], 0.0f);
    float v = x1s[node] * lw[0] + x2s[node] * lw[1] + x3v * lw[2] + lb[0];
    out[node] = fmaxf(v, 0.0f);
  }
}

extern "C" void kernel_launch(void* const* d_in, const int* in_sizes, int n_in,
                              void* d_out, int out_size, void* d_ws, size_t ws_size,
                              hipStream_t stream) {
  const float* x    = (const float*)d_in[0];
  const int*   ei   = (const int*)d_in[1];
  const float* s1wl = (const float*)d_in[2];
  const float* s1wr = (const float*)d_in[3];
  const float* s1b  = (const float*)d_in[4];
  const float* s2wl = (const float*)d_in[5];
  const float* s2wr = (const float*)d_in[6];
  const float* s2b  = (const float*)d_in[7];
  const float* s3wl = (const float*)d_in[8];
  const float* s3wr = (const float*)d_in[9];
  const float* s3b  = (const float*)d_in[10];
  const float* t1aw = (const float*)d_in[11];
  const float* t1ab = (const float*)d_in[12];
  const float* t2aw = (const float*)d_in[13];
  const float* t2ab = (const float*)d_in[14];
  const float* t1bw = (const float*)d_in[15];
  const float* t1bb = (const float*)d_in[16];
  const float* t2bw = (const float*)d_in[17];
  const float* t2bb = (const float*)d_in[18];
  const float* lw   = (const float*)d_in[19];
  const float* lb   = (const float*)d_in[20];
  float* out = (float*)d_out;

  char* basep = (char*)d_ws;
  size_t off = 0;
  auto alloc = [&](size_t bytes) -> void* {
    void* ptr = basep + off;
    off = (off + bytes + 255) & ~(size_t)255;
    return ptr;
  };
  int*      cnt     = (int*)alloc((size_t)NN * 4);
  int*      csr_off = (int*)alloc((size_t)(NN + 1) * 4);
  float*    dis     = (float*)alloc((size_t)NN * 4);
  int*      csr_src = (int*)alloc((size_t)EE * 4);
  unsigned* pairs   = (unsigned*)alloc((size_t)EE * 4);
  int*      perm    = (int*)alloc((size_t)NN * 4);
  int*      ghist   = (int*)alloc(256 * 4);
  int*      gcur    = (int*)alloc(256 * 4);
  int*      bexclB  = (int*)alloc(256 * 4);
  int*      hist    = (int*)alloc(NBIN * 4);
  int*      bincur  = (int*)alloc(NBIN * 4);
  float*    x1s     = (float*)alloc((size_t)NN * 4);
  float*    x2s     = (float*)alloc((size_t)NN * 4);
  float*    pp      = (float*)alloc((size_t)NN * 4);
  float*    qq      = (float*)alloc((size_t)NN * 4);
  float*    uA1     = (float*)alloc((size_t)NN * 4);
  float*    uA2     = (float*)alloc((size_t)NN * 4);
  float*    uB1     = (float*)alloc((size_t)NN * 4);
  float*    uB2     = (float*)alloc((size_t)NN * 4);
  __half*   x12h    = (__half*)alloc((size_t)NN * 12 * 2);
  __half*   A32     = (__half*)alloc((size_t)NN * 32 * 2);
  __half*   w1h     = (__half*)alloc((size_t)128 * 32 * 2);
  __half*   w2h     = (__half*)alloc((size_t)128 * 256 * 2);
  __half*   x1a_h   = (__half*)alloc((size_t)NN * 128 * 2);
  __half*   mean128_h = (__half*)alloc((size_t)NN * 128 * 2);
  float*    region2 = (float*)alloc((size_t)NN * 56 * 4);

  // Region 1 overlay (x1a_h = 64N f32-equiv; reused after k_mm2_mfma):
  float* r1 = (float*)x1a_h;
  float*  Pa    = r1;                              // [3][N][8] = 24N
  __half* PTop  = (__half*)(r1 + (size_t)NN * 24); // [N][16] interleaved = 8N
  __half* zbuf0 = (__half*)(r1 + (size_t)NN * 32); // [N][16] = 8N
  __half* zbuf1 = (__half*)(r1 + (size_t)NN * 40); // [N][16] = 8N
  float*  P2    = r1 + (size_t)NN * 48;            // [4][N] = 4N  (52N <= 64N)
  // Region 2 (56N):
  float*  Pb    = region2;                         // [6][N][8] = 48N
  float*  P2b   = region2 + (size_t)NN * 48;       // [7][N] = 7N  (55N <= 56N)

  const size_t S8 = (size_t)NN * 8;
  const size_t S1 = (size_t)NN;

  // ---- CSR build (bucketed) + prep (merged into bhist launch) ----
  hipMemsetAsync(ghist, 0, 3840, stream);
  k_bhist_prep<<<BH_B + PREP_B0 + PREP_B1 + 16 + 128, 256, 0, stream>>>(
      ei, ghist, x, s1wl, s1wr, s2wl, s2wr, x12h, A32, w1h, w2h);
  k_b196scan<<<1, 256, 0, stream>>>(ghist, gcur, bexclB, csr_off);
  k_split<<<(EE + 4095) / 4096, 256, 0, stream>>>(ei, gcur, pairs);
  k_bbuild<<<NBK, 256, 0, stream>>>(pairs, bexclB, cnt, csr_off, dis, csr_src);

  // ---- degree sort ----
  k_hist<<<(NN + 255) / 256, 256, 0, stream>>>(cnt, hist);
  k_binscan<<<1, 64, 0, stream>>>(hist, bincur);
  k_scatter<<<(NN + 255) / 256, 256, 0, stream>>>(cnt, bincur, perm);

  // ---- SAGE chain ----
  k_gmean12h<<<(NN + 63) / 64, 256, 0, stream>>>(x12h, perm, csr_off, csr_src, A32);
  k_mm1_mfma<<<(NN + 127) / 128, 256, 0, stream>>>(A32, w1h, s1b, x1a_h);
  k_gather128<<<(NN + 15) / 16, 256, 0, stream>>>(x1a_h, perm, csr_off, csr_src, mean128_h);
  k_mm2_mfma<<<(NN + 127) / 128, 256, 0, stream>>>(mean128_h, x1a_h, w2h, s2b, s3wl, s3wr, pp, qq);

  // ---- TAG phase (discrete launches) ----
  k_tag0<<<(NN + 63) / 64, 256, 0, stream>>>(
      x, t1aw, t1bw, dis, Pa, Pb, PTop, pp, qq, s3b, perm, csr_off, csr_src, x1s);
  k_d8_dual<<<(NN + 127) / 128, 256, 0, stream>>>(
      PTop, Pa + 2 * S8, Pb + 5 * S8, zbuf0, perm, csr_off, csr_src, dis);
  k_d8_dual<<<(NN + 127) / 128, 256, 0, stream>>>(
      zbuf0, Pa + 1 * S8, Pb + 4 * S8, zbuf1, perm, csr_off, csr_src, dis);
  k_d8_l3<<<(NN + 127) / 128, 256, 0, stream>>>(
      zbuf1, Pa, t1ab, t2aw, Pb + 3 * S8, zbuf0, P2, perm, csr_off, csr_src, dis);
  k_d8_single<<<(NN + 127) / 128, 256, 0, stream>>>(
      zbuf0, Pb + 2 * S8, zbuf1, perm, csr_off, csr_src, dis);
  k_d8_single<<<(NN + 127) / 128, 256, 0, stream>>>(
      zbuf1, Pb + 1 * S8, zbuf0, perm, csr_off, csr_src, dis);
  k_d8_l6<<<(NN + 127) / 128, 256, 0, stream>>>(
      zbuf0, Pb, t1bb, t2bw, P2b, perm, csr_off, csr_src, dis);

  // ---- D1 hops ----
  k_g1_dual<1><<<(NN + 63) / 64, 256, 0, stream>>>(
      P2 + 3 * S1, P2 + 2 * S1, nullptr, 3,
      P2b + 6 * S1, P2b + 5 * S1, nullptr, 3,
      perm, csr_off, csr_src, dis, uA1, uB1);
  k_g1_dual<1><<<(NN + 63) / 64, 256, 0, stream>>>(
      uA1, P2 + 1 * S1, nullptr, 3,
      uB1, P2b + 4 * S1, nullptr, 3,
      perm, csr_off, csr_src, dis, uA2, uB2);
  k_g1_dual<1><<<(NN + 63) / 64, 256, 0, stream>>>(
      uA2, P2, t2ab, 2,
      uB2, P2b + 3 * S1, nullptr, 3,
      perm, csr_off, csr_src, dis, x2s, uB1);
  k_g1_single<1><<<(NN + 63) / 64, 256, 0, stream>>>(
      uB1, P2b + 2 * S1, nullptr, 3, perm, csr_off, csr_src, dis, uB2);
  k_g1_single<1><<<(NN + 63) / 64, 256, 0, stream>>>(
      uB2, P2b + 1 * S1, nullptr, 3, perm, csr_off, csr_src, dis, uB1);
  k_g1_final<<<(NN + 63) / 64, 256, 0, stream>>>(
      uB1, P2b, t2bb, x1s, x2s, lw, lb, perm, csr_off, csr_src, dis, out);
}

// Round 9
// 487.697 us; speedup vs baseline: 2.9984x; 1.0438x over previous
//
#include <hip/hip_runtime.h>
#include <hip/hip_bf16.h>
#include <hip/hip_fp16.h>

#define NN 100000
#define EE 1600000
#define NBIN 64
#define BSH 9
#define BSZ 512
#define NBK 196   // ceil(NN/512)

// grid segment sizes
#define GA 1563   // gmean12h blocks (64 nodes/block)
#define GT 391    // tagP8 blocks (256 nodes/block)
#define GM 782    // mm / d8 blocks (128 nodes/block)
#define GG 6250   // gather128 blocks (16 nodes/block)
#define G1 1563   // d1 blocks (64 nodes/block)

typedef _Float16 h8v __attribute__((ext_vector_type(8)));
typedef float f4v __attribute__((ext_vector_type(4)));

__device__ __forceinline__ float sigm(float v) { return 1.0f / (1.0f + expf(-v)); }
__device__ __forceinline__ float4 f4add(float4 a, float4 b) {
  a.x += b.x; a.y += b.y; a.z += b.z; a.w += b.w; return a;
}
__device__ __forceinline__ float4 h4f(uint2 v) {
  __half2 a = *reinterpret_cast<__half2*>(&v.x);
  __half2 b = *reinterpret_cast<__half2*>(&v.y);
  float2 fa = __half22float2(a), fb = __half22float2(b);
  return make_float4(fa.x, fa.y, fb.x, fb.y);
}
__device__ __forceinline__ void h8acc(uint4 v, float* a) {
  float4 lo = h4f(make_uint2(v.x, v.y));
  float4 hi = h4f(make_uint2(v.z, v.w));
  a[0] += lo.x; a[1] += lo.y; a[2] += lo.z; a[3] += lo.w;
  a[4] += hi.x; a[5] += hi.y; a[6] += hi.z; a[7] += hi.w;
}
__device__ __forceinline__ uint2 pack4h(float4 r) {
  __half2 q0 = __floats2half2_rn(r.x, r.y), q1 = __floats2half2_rn(r.z, r.w);
  uint2 o; o.x = *(unsigned*)&q0; o.y = *(unsigned*)&q1; return o;
}

// ================= CSR build + fused prep =================
#define BH_B 512
#define PREP_B0 ((NN * 12 + 255) / 256)
#define PREP_B1 ((NN + 255) / 256)
__global__ __launch_bounds__(256) void k_bhist_prep(
    const int* __restrict__ ei, int* __restrict__ ghist,
    const float* __restrict__ x, const float* __restrict__ s1wl, const float* __restrict__ s1wr,
    const float* __restrict__ s2wl, const float* __restrict__ s2wr,
    __half* __restrict__ x12h, __half* __restrict__ A32,
    __half* __restrict__ w1h, __half* __restrict__ w2h) {
  __shared__ int lh[NBK];
  int bid = blockIdx.x;
  if (bid < BH_B) {
    for (int j = threadIdx.x; j < NBK; j += 256) lh[j] = 0;
    __syncthreads();
    for (int i = bid * 256 + threadIdx.x; i < EE; i += BH_B * 256)
      atomicAdd(&lh[ei[EE + i] >> BSH], 1);
    __syncthreads();
    for (int j = threadIdx.x; j < NBK; j += 256) {
      int v = lh[j];
      if (v) atomicAdd(&ghist[j], v);
    }
    return;
  }
  int pid = bid - BH_B;
  if (pid < PREP_B0) {
    int i = pid * 256 + threadIdx.x;
    if (i < NN * 12) {
      int n = i / 12, j = i - n * 12;
      x12h[i] = __float2half((j < 11) ? x[n * 11 + j] : 0.0f);
    }
  } else if (pid < PREP_B0 + PREP_B1) {
    int i = (pid - PREP_B0) * 256 + threadIdx.x;
    if (i < NN) {
      float a[11];
      #pragma unroll
      for (int j = 0; j < 11; ++j) a[j] = x[(long)i * 11 + j];
      uint2* row = (uint2*)(A32 + (long)i * 32);
      row[3] = make_uint2(0u, 0u);
      row[4] = pack4h(make_float4(a[0], a[1], a[2], a[3]));
      row[5] = pack4h(make_float4(a[4], a[5], a[6], a[7]));
      row[6] = pack4h(make_float4(a[8], a[9], a[10], 0.0f));
      row[7] = make_uint2(0u, 0u);
    }
  } else if (pid < PREP_B0 + PREP_B1 + 16) {
    int i = (pid - PREP_B0 - PREP_B1) * 256 + threadIdx.x;
    int o = i >> 5, k = i & 31;
    float v = 0.0f;
    if (k < 11) v = s1wl[o * 11 + k];
    else if (k >= 16 && k < 27) v = s1wr[o * 11 + (k - 16)];
    w1h[i] = __float2half(v);
  } else {
    int i = (pid - PREP_B0 - PREP_B1 - 16) * 256 + threadIdx.x;
    int o = i >> 8, k = i & 255;
    float v = (k < 128) ? s2wl[o * 128 + k] : s2wr[o * 128 + (k - 128)];
    w2h[i] = __float2half(v);
  }
}

__global__ void k_b196scan(const int* __restrict__ ghist, int* __restrict__ gcur,
                           int* __restrict__ bexclB, int* __restrict__ csr_off) {
  __shared__ int sh[256];
  int tid = threadIdx.x;
  int v = (tid < NBK) ? ghist[tid] : 0;
  sh[tid] = v;
  __syncthreads();
  for (int d = 1; d < 256; d <<= 1) {
    int t = (tid >= d) ? sh[tid - d] : 0;
    __syncthreads();
    sh[tid] += t;
    __syncthreads();
  }
  int excl = sh[tid] - v;
  if (tid < NBK) { gcur[tid] = excl; bexclB[tid] = excl; }
  if (tid == 0) { bexclB[NBK] = EE; csr_off[NN] = EE; }
}

__global__ __launch_bounds__(256) void k_split(const int* __restrict__ ei,
                                               int* __restrict__ gcur,
                                               unsigned* __restrict__ pairs) {
  __shared__ int cntL[256];
  __shared__ int segO[256];
  __shared__ int curL[256];
  __shared__ int baseL[256];
  __shared__ unsigned stag[4096];
  __shared__ unsigned char bktL[4096];
  int tid = threadIdx.x;
  int tile0 = blockIdx.x * 4096;
  int tcnt = min(4096, EE - tile0);
  cntL[tid] = 0; curL[tid] = 0;
  __syncthreads();
  for (int i = tid; i < tcnt; i += 256)
    atomicAdd(&cntL[ei[EE + tile0 + i] >> BSH], 1);
  __syncthreads();
  int v = cntL[tid];
  segO[tid] = v;
  __syncthreads();
  for (int d = 1; d < 256; d <<= 1) {
    int t = (tid >= d) ? segO[tid - d] : 0;
    __syncthreads();
    segO[tid] += t;
    __syncthreads();
  }
  int excl = segO[tid] - v;
  __syncthreads();
  segO[tid] = excl;
  __syncthreads();
  for (int i = tid; i < tcnt; i += 256) {
    int s = ei[tile0 + i], dd = ei[EE + tile0 + i];
    int b = dd >> BSH;
    int slot = segO[b] + atomicAdd(&curL[b], 1);
    stag[slot] = (unsigned)s | ((unsigned)(dd & (BSZ - 1)) << 17);
    bktL[slot] = (unsigned char)b;
  }
  baseL[tid] = v ? atomicAdd(&gcur[tid], v) : 0;
  __syncthreads();
  for (int i = tid; i < tcnt; i += 256) {
    int b = bktL[i];
    pairs[baseL[b] + (i - segO[b])] = stag[i];
  }
}

// per-bucket count + scan + fill + degree-histogram (fused)
__global__ __launch_bounds__(256) void k_bbuild(const unsigned* __restrict__ pairs,
                                                const int* __restrict__ bexclB,
                                                int* __restrict__ cnt, int* __restrict__ csr_off,
                                                float* __restrict__ dis, int* __restrict__ csr_src,
                                                int* __restrict__ hist) {
  __shared__ int c[BSZ];
  __shared__ int ps[256];
  __shared__ int curB[BSZ];
  __shared__ int lhist[NBIN];
  int tid = threadIdx.x;
  int b = blockIdx.x;
  int lo = b << BSH;
  for (int j = tid; j < BSZ; j += 256) c[j] = 0;
  if (tid < NBIN) lhist[tid] = 0;
  __syncthreads();
  int s0e = bexclB[b], s1e = bexclB[b + 1];
  for (int i = s0e + tid; i < s1e; i += 256)
    atomicAdd(&c[pairs[i] >> 17], 1);
  __syncthreads();
  int a0 = c[2 * tid], a1 = c[2 * tid + 1];
  int pv = a0 + a1;
  ps[tid] = pv;
  __syncthreads();
  for (int d = 1; d < 256; d <<= 1) {
    int t = (tid >= d) ? ps[tid - d] : 0;
    __syncthreads();
    ps[tid] += t;
    __syncthreads();
  }
  int pex = ps[tid] - pv;
  int base = s0e + pex;
  int n0 = lo + 2 * tid, n1 = n0 + 1;
  if (n0 < NN) {
    csr_off[n0] = base; cnt[n0] = a0;
    dis[n0] = (a0 > 0) ? rsqrtf((float)a0) : 0.0f;
    atomicAdd(&lhist[min(a0, NBIN - 1)], 1);
  }
  if (n1 < NN) {
    csr_off[n1] = base + a0; cnt[n1] = a1;
    dis[n1] = (a1 > 0) ? rsqrtf((float)a1) : 0.0f;
    atomicAdd(&lhist[min(a1, NBIN - 1)], 1);
  }
  curB[2 * tid] = base;
  curB[2 * tid + 1] = base + a0;
  __syncthreads();
  for (int i = s0e + tid; i < s1e; i += 256) {
    unsigned pk = pairs[i];
    int p = atomicAdd(&curB[pk >> 17], 1);
    csr_src[p] = (int)(pk & 0x1FFFFu);
  }
  __syncthreads();
  if (tid < NBIN) {
    int v = lhist[tid];
    if (v) atomicAdd(&hist[tid], v);
  }
}

__global__ void k_binscan(const int* __restrict__ hist, int* __restrict__ bincur) {
  int tid = threadIdx.x;
  int v = hist[tid];
  int incl = v;
  for (int d = 1; d < 64; d <<= 1) {
    int t = __shfl_up(incl, d, 64);
    if (tid >= d) incl += t;
  }
  bincur[tid] = incl - v;
}
__global__ __launch_bounds__(256) void k_scatter(const int* __restrict__ cnt,
                                                 int* __restrict__ bincur,
                                                 int* __restrict__ perm) {
  __shared__ int lh[NBIN];
  __shared__ int lbase[NBIN];
  if (threadIdx.x < NBIN) lh[threadIdx.x] = 0;
  __syncthreads();
  int i = blockIdx.x * 256 + threadIdx.x;
  int b = 0, r = 0;
  bool valid = i < NN;
  if (valid) {
    b = min(cnt[i], NBIN - 1);
    r = atomicAdd(&lh[b], 1);
  }
  __syncthreads();
  if (threadIdx.x < NBIN) {
    int v = lh[threadIdx.x];
    lbase[threadIdx.x] = v ? atomicAdd(&bincur[threadIdx.x], v) : 0;
  }
  __syncthreads();
  if (valid) perm[lbase[b] + r] = i;
}

// ================= device bodies =================
__device__ void gmean12h_body(int bid, const __half* x12h, const int* perm,
                              const int* off, const int* srcarr, __half* A32) {
  int g = bid * 64 + (threadIdx.x >> 2);
  int t = threadIdx.x & 3;
  if (g >= NN || t >= 3) return;
  int node = perm[g];
  int s = off[node], e = off[node + 1];
  const uint2* h2 = (const uint2*)x12h;
  float4 acc = {0, 0, 0, 0};
  int p = s;
  for (; p + 4 <= e; p += 4) {
    int s0 = srcarr[p], s1 = srcarr[p + 1], s2 = srcarr[p + 2], s3 = srcarr[p + 3];
    acc = f4add(acc, f4add(f4add(h4f(h2[(long)s0 * 3 + t]), h4f(h2[(long)s1 * 3 + t])),
                           f4add(h4f(h2[(long)s2 * 3 + t]), h4f(h2[(long)s3 * 3 + t]))));
  }
  for (; p < e; ++p) acc = f4add(acc, h4f(h2[(long)srcarr[p] * 3 + t]));
  int c = e - s;
  float inv = 1.0f / (float)(c > 0 ? c : 1);
  acc.x *= inv; acc.y *= inv; acc.z *= inv; acc.w *= inv;
  ((uint2*)A32)[(long)node * 8 + t] = pack4h(acc);
}

__device__ void tagp8_body(int bid, const float* x, const float* t1aw, const float* t1bw,
                           const float* dis, float* Pa, float* Pb, __half* PTop) {
  int i = bid * 256 + threadIdx.x;
  if (i >= NN) return;
  float a[11];
  #pragma unroll
  for (int j = 0; j < 11; ++j) a[j] = x[(long)i * 11 + j];
  float dn = dis[i];
  #pragma unroll
  for (int k = 0; k < 4; ++k) {
    float s[8];
    #pragma unroll
    for (int o = 0; o < 8; ++o) {
      float acc = 0.0f;
      #pragma unroll
      for (int j = 0; j < 11; ++j) acc += a[j] * t1aw[o * 44 + k * 11 + j];
      s[o] = acc;
    }
    if (k < 3) {
      float4* dst = (float4*)&Pa[((size_t)k * NN + i) * 8];
      dst[0] = make_float4(s[0], s[1], s[2], s[3]);
      dst[1] = make_float4(s[4], s[5], s[6], s[7]);
    } else {
      uint2 lo = pack4h(make_float4(s[0] * dn, s[1] * dn, s[2] * dn, s[3] * dn));
      uint2 hi = pack4h(make_float4(s[4] * dn, s[5] * dn, s[6] * dn, s[7] * dn));
      uint4 o4; o4.x = lo.x; o4.y = lo.y; o4.z = hi.x; o4.w = hi.y;
      ((uint4*)PTop)[(long)i * 2] = o4;
    }
  }
  #pragma unroll
  for (int k = 0; k < 7; ++k) {
    float s[8];
    #pragma unroll
    for (int o = 0; o < 8; ++o) {
      float acc = 0.0f;
      #pragma unroll
      for (int j = 0; j < 11; ++j) acc += a[j] * t1bw[o * 77 + k * 11 + j];
      s[o] = acc;
    }
    if (k < 6) {
      float4* dst = (float4*)&Pb[((size_t)k * NN + i) * 8];
      dst[0] = make_float4(s[0], s[1], s[2], s[3]);
      dst[1] = make_float4(s[4], s[5], s[6], s[7]);
    } else {
      uint2 lo = pack4h(make_float4(s[0] * dn, s[1] * dn, s[2] * dn, s[3] * dn));
      uint2 hi = pack4h(make_float4(s[4] * dn, s[5] * dn, s[6] * dn, s[7] * dn));
      uint4 o4; o4.x = lo.x; o4.y = lo.y; o4.z = hi.x; o4.w = hi.y;
      ((uint4*)PTop)[(long)i * 2 + 1] = o4;
    }
  }
}

__device__ void d8_dual_body(int bid, const __half* src, const float* addA,
                             const float* addB, __half* dst,
                             const int* perm, const int* off,
                             const int* srcarr, const float* dis) {
  const uint4* src4 = (const uint4*)src;
  int t = threadIdx.x & 1;
  const float4* addp = (const float4*)(t == 0 ? addA : addB);
  int g = bid * 128 + (threadIdx.x >> 1);
  if (g >= NN) return;
  int node = perm[g];
  int s = off[node], e = off[node + 1];
  float acc[8] = {};
  int p = s;
  for (; p + 4 <= e; p += 4) {
    int s0 = srcarr[p], s1 = srcarr[p + 1], s2 = srcarr[p + 2], s3 = srcarr[p + 3];
    h8acc(src4[(long)s0 * 2 + t], acc); h8acc(src4[(long)s1 * 2 + t], acc);
    h8acc(src4[(long)s2 * 2 + t], acc); h8acc(src4[(long)s3 * 2 + t], acc);
  }
  for (; p < e; ++p) h8acc(src4[(long)srcarr[p] * 2 + t], acc);
  float dn = dis[node];
  float4 a0 = addp[(long)node * 2], a1 = addp[(long)node * 2 + 1];
  float4 r0 = make_float4((acc[0] * dn + a0.x) * dn, (acc[1] * dn + a0.y) * dn,
                          (acc[2] * dn + a0.z) * dn, (acc[3] * dn + a0.w) * dn);
  float4 r1 = make_float4((acc[4] * dn + a1.x) * dn, (acc[5] * dn + a1.y) * dn,
                          (acc[6] * dn + a1.z) * dn, (acc[7] * dn + a1.w) * dn);
  uint2 lo = pack4h(r0), hi = pack4h(r1);
  uint4 o; o.x = lo.x; o.y = lo.y; o.z = hi.x; o.w = hi.y;
  ((uint4*)dst)[(long)node * 2 + t] = o;
}

__device__ void d8_l3_body(int bid, const __half* src, const float* Pa0,
                           const float* t1ab, const float* t2aw,
                           const float* Pb3, __half* dstB, float* P2,
                           const int* perm, const int* off,
                           const int* srcarr, const float* dis) {
  const uint4* src4 = (const uint4*)src;
  int t = threadIdx.x & 1;
  int g = bid * 128 + (threadIdx.x >> 1);
  if (g >= NN) return;
  int node = perm[g];
  int s = off[node], e = off[node + 1];
  float acc[8] = {};
  int p = s;
  for (; p + 4 <= e; p += 4) {
    int s0 = srcarr[p], s1 = srcarr[p + 1], s2 = srcarr[p + 2], s3 = srcarr[p + 3];
    h8acc(src4[(long)s0 * 2 + t], acc); h8acc(src4[(long)s1 * 2 + t], acc);
    h8acc(src4[(long)s2 * 2 + t], acc); h8acc(src4[(long)s3 * 2 + t], acc);
  }
  for (; p < e; ++p) h8acc(src4[(long)srcarr[p] * 2 + t], acc);
  float dn = dis[node];
  if (t == 0) {
    const float4* addp = (const float4*)Pa0;
    float4 a0 = addp[(long)node * 2], a1 = addp[(long)node * 2 + 1];
    float4 b0 = ((const float4*)t1ab)[0], b1 = ((const float4*)t1ab)[1];
    float a[8];
    a[0] = sigm(acc[0] * dn + a0.x + b0.x); a[1] = sigm(acc[1] * dn + a0.y + b0.y);
    a[2] = sigm(acc[2] * dn + a0.z + b0.z); a[3] = sigm(acc[3] * dn + a0.w + b0.w);
    a[4] = sigm(acc[4] * dn + a1.x + b1.x); a[5] = sigm(acc[5] * dn + a1.y + b1.y);
    a[6] = sigm(acc[6] * dn + a1.z + b1.z); a[7] = sigm(acc[7] * dn + a1.w + b1.w);
    #pragma unroll
    for (int k = 0; k < 4; ++k) {
      float sv = 0.0f;
      #pragma unroll
      for (int j = 0; j < 8; ++j) sv += a[j] * t2aw[k * 8 + j];
      if (k == 3) sv *= dn;
      P2[(size_t)k * NN + node] = sv;
    }
  } else {
    const float4* addp = (const float4*)Pb3;
    float4 a0 = addp[(long)node * 2], a1 = addp[(long)node * 2 + 1];
    float4 r0 = make_float4((acc[0] * dn + a0.x) * dn, (acc[1] * dn + a0.y) * dn,
                            (acc[2] * dn + a0.z) * dn, (acc[3] * dn + a0.w) * dn);
    float4 r1 = make_float4((acc[4] * dn + a1.x) * dn, (acc[5] * dn + a1.y) * dn,
                            (acc[6] * dn + a1.z) * dn, (acc[7] * dn + a1.w) * dn);
    uint2 lo = pack4h(r0), hi = pack4h(r1);
    uint4 o; o.x = lo.x; o.y = lo.y; o.z = hi.x; o.w = hi.y;
    ((uint4*)dstB)[(long)node * 2 + 1] = o;
  }
}

__device__ void d8_single_body(int bid, const __half* src, const float* addB, __half* dst,
                               const int* perm, const int* off,
                               const int* srcarr, const float* dis) {
  const uint2* src2 = (const uint2*)src;
  int t = threadIdx.x & 1;
  int g = bid * 128 + (threadIdx.x >> 1);
  if (g >= NN) return;
  int node = perm[g];
  int s = off[node], e = off[node + 1];
  float4 acc = {0, 0, 0, 0};
  int p = s;
  for (; p + 4 <= e; p += 4) {
    int s0 = srcarr[p], s1 = srcarr[p + 1], s2 = srcarr[p + 2], s3 = srcarr[p + 3];
    acc = f4add(acc, f4add(f4add(h4f(src2[(long)s0 * 4 + 2 + t]), h4f(src2[(long)s1 * 4 + 2 + t])),
                           f4add(h4f(src2[(long)s2 * 4 + 2 + t]), h4f(src2[(long)s3 * 4 + 2 + t]))));
  }
  for (; p < e; ++p) acc = f4add(acc, h4f(src2[(long)srcarr[p] * 4 + 2 + t]));
  float dn = dis[node];
  float4 av = ((const float4*)addB)[(long)node * 2 + t];
  float4 r = make_float4((acc.x * dn + av.x) * dn, (acc.y * dn + av.y) * dn,
                         (acc.z * dn + av.z) * dn, (acc.w * dn + av.w) * dn);
  ((uint2*)dst)[(long)node * 4 + 2 + t] = pack4h(r);
}

__device__ void d8_l6_body(int bid, const __half* src, const float* Pb0,
                           const float* t1bb, const float* t2bw, float* P2b,
                           const int* perm, const int* off,
                           const int* srcarr, const float* dis) {
  const uint2* src2 = (const uint2*)src;
  int t = threadIdx.x & 1;
  int g = bid * 128 + (threadIdx.x >> 1);
  if (g >= NN) return;
  int node = perm[g];
  int s = off[node], e = off[node + 1];
  float4 acc = {0, 0, 0, 0};
  int p = s;
  for (; p + 4 <= e; p += 4) {
    int s0 = srcarr[p], s1 = srcarr[p + 1], s2 = srcarr[p + 2], s3 = srcarr[p + 3];
    acc = f4add(acc, f4add(f4add(h4f(src2[(long)s0 * 4 + 2 + t]), h4f(src2[(long)s1 * 4 + 2 + t])),
                           f4add(h4f(src2[(long)s2 * 4 + 2 + t]), h4f(src2[(long)s3 * 4 + 2 + t]))));
  }
  for (; p < e; ++p) acc = f4add(acc, h4f(src2[(long)srcarr[p] * 4 + 2 + t]));
  float dn = dis[node];
  float4 av = ((const float4*)Pb0)[(long)node * 2 + t];
  float4 bv = ((const float4*)t1bb)[t];
  float4 r = make_float4(sigm(acc.x * dn + av.x + bv.x), sigm(acc.y * dn + av.y + bv.y),
                         sigm(acc.z * dn + av.z + bv.z), sigm(acc.w * dn + av.w + bv.w));
  float o0 = __shfl_xor(r.x, 1, 64), o1 = __shfl_xor(r.y, 1, 64);
  float o2 = __shfl_xor(r.z, 1, 64), o3 = __shfl_xor(r.w, 1, 64);
  if (t == 0) {
    float a[8] = {r.x, r.y, r.z, r.w, o0, o1, o2, o3};
    #pragma unroll
    for (int k = 0; k < 7; ++k) {
      float sv = 0.0f;
      #pragma unroll
      for (int j = 0; j < 8; ++j) sv += a[j] * t2bw[k * 8 + j];
      if (k == 6) sv *= dn;
      P2b[(size_t)k * NN + node] = sv;
    }
  }
}

// d1 hop (tag-norm, prescaled input). act: 3=prescale-store, 2=relu+bias
__device__ void d1_body(int bid, const float* ua, const float* adda, const float* bias,
                        int act, float* outa, const int* perm, const int* off,
                        const int* srcarr, const float* dis) {
  int g = bid * 64 + (threadIdx.x >> 2);
  int t = threadIdx.x & 3;
  if (g >= NN) return;
  int node = perm[g];
  int s = off[node], e = off[node + 1];
  float accA = 0.0f;
  for (int p = s + t; p < e; p += 4) accA += ua[srcarr[p]];
  accA += __shfl_xor(accA, 1, 64); accA += __shfl_xor(accA, 2, 64);
  if (t == 0) {
    float sc = dis[node];
    float rA = accA * sc + adda[node];
    if (bias) rA += bias[0];
    if (act == 3) rA *= sc; else if (act == 2) rA = fmaxf(rA, 0.0f);
    outa[node] = rA;
  }
}

__device__ void x1s_body(int bid, const float* pp, const float* qq, const float* s3b,
                         const int* perm, const int* off, const int* srcarr,
                         float* x1s) {
  int g = bid * 64 + (threadIdx.x >> 2);
  int t = threadIdx.x & 3;
  if (g >= NN) return;
  int node = perm[g];
  int s = off[node], e = off[node + 1];
  float acc = 0.0f;
  for (int p = s + t; p < e; p += 4) acc += pp[srcarr[p]];
  acc += __shfl_xor(acc, 1, 64); acc += __shfl_xor(acc, 2, 64);
  if (t == 0) {
    int c = e - s;
    float sc = 1.0f / (float)(c > 0 ? c : 1);
    x1s[node] = fmaxf(acc * sc + qq[node] + s3b[0], 0.0f);
  }
}

__device__ void gather128_body(int bid, const __half* h, const int* perm,
                               const int* off, const int* srcarr, __half* outh) {
  int g = bid * 16 + (threadIdx.x >> 4);
  int t = threadIdx.x & 15;
  if (g >= NN) return;
  int node = perm[g];
  int s = off[node], e = off[node + 1];
  const uint4* h4 = (const uint4*)h;
  float acc[8] = {};
  int p = s;
  for (; p + 4 <= e; p += 4) {
    int s0 = srcarr[p], s1 = srcarr[p + 1], s2 = srcarr[p + 2], s3 = srcarr[p + 3];
    uint4 r0 = h4[(long)s0 * 16 + t], r1 = h4[(long)s1 * 16 + t];
    uint4 r2 = h4[(long)s2 * 16 + t], r3 = h4[(long)s3 * 16 + t];
    h8acc(r0, acc); h8acc(r1, acc); h8acc(r2, acc); h8acc(r3, acc);
  }
  for (; p < e; ++p) h8acc(h4[(long)srcarr[p] * 16 + t], acc);
  int c = e - s;
  float inv = 1.0f / (float)(c > 0 ? c : 1);
  uint2 lo = pack4h(make_float4(acc[0] * inv, acc[1] * inv, acc[2] * inv, acc[3] * inv));
  uint2 hi = pack4h(make_float4(acc[4] * inv, acc[5] * inv, acc[6] * inv, acc[7] * inv));
  uint4 o; o.x = lo.x; o.y = lo.y; o.z = hi.x; o.w = hi.y;
  ((uint4*)outh)[(long)node * 16 + t] = o;
}

__device__ void mm1_body(int bid, const __half* A32, const __half* W32,
                         const float* bias, __half* out, __half (*lt)[32][136]) {
  int tid = threadIdx.x;
  int wave = tid >> 6, l = tid & 63;
  int lr = l & 15, lk = l >> 4;
  int m0 = bid * 128 + wave * 32;
  f4v acc[2][8] = {};
  h8v afrag[2];
  #pragma unroll
  for (int rt = 0; rt < 2; ++rt) {
    int row = m0 + rt * 16 + lr;
    h8v z = {};
    afrag[rt] = (row < NN) ? *(const h8v*)&A32[(long)row * 32 + lk * 8] : z;
  }
  #pragma unroll
  for (int c = 0; c < 8; ++c) {
    h8v bfrag = *(const h8v*)&W32[(c * 16 + lr) * 32 + lk * 8];
    acc[0][c] = __builtin_amdgcn_mfma_f32_16x16x32_f16(afrag[0], bfrag, acc[0][c], 0, 0, 0);
    acc[1][c] = __builtin_amdgcn_mfma_f32_16x16x32_f16(afrag[1], bfrag, acc[1][c], 0, 0, 0);
  }
  float bi[8];
  #pragma unroll
  for (int c = 0; c < 8; ++c) bi[c] = bias[c * 16 + lr];
  #pragma unroll
  for (int rt = 0; rt < 2; ++rt)
    #pragma unroll
    for (int c = 0; c < 8; ++c)
      #pragma unroll
      for (int reg = 0; reg < 4; ++reg) {
        float v = acc[rt][c][reg] + bi[c];
        lt[wave][rt * 16 + lk * 4 + reg][c * 16 + lr] = __float2half(sigm(v));
      }
  __syncthreads();
  #pragma unroll
  for (int it = 0; it < 8; ++it) {
    int idx = it * 64 + l;
    int row = idx >> 4, c16 = idx & 15;
    int grow = m0 + row;
    if (grow < NN) {
      uint4 v = *(const uint4*)&lt[wave][row][c16 * 8];
      ((uint4*)out)[(long)grow * 16 + c16] = v;
    }
  }
}

__device__ void mm2_body(int bid, const __half* A1, const __half* A2,
                         const __half* W, const float* bias,
                         const float* w3l, const float* w3r,
                         float* pp, float* qq) {
  int tid = threadIdx.x;
  int wave = tid >> 6;
  int l = tid & 63;
  int lr = l & 15;
  int lk = l >> 4;
  int m0 = bid * 128 + wave * 32;
  f4v acc[2][8] = {};
  #pragma unroll
  for (int ks = 0; ks < 8; ++ks) {
    const __half* Asrc = (ks < 4) ? A1 : A2;
    int kk = (ks & 3) * 32 + lk * 8;
    h8v afrag[2];
    #pragma unroll
    for (int rt = 0; rt < 2; ++rt) {
      int row = m0 + rt * 16 + lr;
      h8v z = {};
      afrag[rt] = (row < NN) ? *(const h8v*)&Asrc[(long)row * 128 + kk] : z;
    }
    #pragma unroll
    for (int c = 0; c < 8; ++c) {
      h8v bfrag = *(const h8v*)&W[(long)(c * 16 + lr) * 256 + ks * 32 + lk * 8];
      acc[0][c] = __builtin_amdgcn_mfma_f32_16x16x32_f16(afrag[0], bfrag, acc[0][c], 0, 0, 0);
      acc[1][c] = __builtin_amdgcn_mfma_f32_16x16x32_f16(afrag[1], bfrag, acc[1][c], 0, 0, 0);
    }
  }
  float wl[8], wr[8], bi[8];
  #pragma unroll
  for (int c = 0; c < 8; ++c) {
    wl[c] = w3l[c * 16 + lr];
    wr[c] = w3r[c * 16 + lr];
    bi[c] = bias[c * 16 + lr];
  }
  #pragma unroll
  for (int rt = 0; rt < 2; ++rt) {
    #pragma unroll
    for (int reg = 0; reg < 4; ++reg) {
      float s1 = 0.0f, s2 = 0.0f;
      #pragma unroll
      for (int c = 0; c < 8; ++c) {
        float v = acc[rt][c][reg] + bi[c];
        float sg = sigm(v);
        s1 += sg * wl[c];
        s2 += sg * wr[c];
      }
      #pragma unroll
      for (int d = 1; d < 16; d <<= 1) {
        s1 += __shfl_xor(s1, d, 64);
        s2 += __shfl_xor(s2, d, 64);
      }
      int row = m0 + rt * 16 + lk * 4 + reg;
      if (lr == 0 && row < NN) { pp[row] = s1; qq[row] = s2; }
    }
  }
}

// ================= fused dispatches =================
__global__ __launch_bounds__(256) void k_fuseA(
    const __half* x12h, const int* perm, const int* off, const int* srcarr, __half* A32,
    const float* x, const float* t1aw, const float* t1bw, const float* dis,
    float* Pa, float* Pb, __half* PTop) {
  if (blockIdx.x < GA) gmean12h_body(blockIdx.x, x12h, perm, off, srcarr, A32);
  else tagp8_body(blockIdx.x - GA, x, t1aw, t1bw, dis, Pa, Pb, PTop);
}

__global__ __launch_bounds__(256) void k_fuseB(
    const __half* A32, const __half* W32, const float* s1b, __half* x1a,
    const __half* PTop, const float* Pa2, const float* Pb5, __half* zbuf0,
    const int* perm, const int* off, const int* srcarr, const float* dis) {
  __shared__ __half lt[4][32][136];
  if (blockIdx.x < GM) mm1_body(blockIdx.x, A32, W32, s1b, x1a, lt);
  else d8_dual_body(blockIdx.x - GM, PTop, Pa2, Pb5, zbuf0, perm, off, srcarr, dis);
}

__global__ __launch_bounds__(256) void k_fuseC(
    const __half* x1a, __half* mean128,
    const __half* zbuf0, const float* Pa1, const float* Pb4, __half* zbuf1,
    const int* perm, const int* off, const int* srcarr, const float* dis) {
  if (blockIdx.x < GG) gather128_body(blockIdx.x, x1a, perm, off, srcarr, mean128);
  else d8_dual_body(blockIdx.x - GG, zbuf0, Pa1, Pb4, zbuf1, perm, off, srcarr, dis);
}

__global__ __launch_bounds__(256) void k_fuseD(
    const __half* mean128, const __half* x1a, const __half* w2h, const float* s2b,
    const float* w3l, const float* w3r, float* pp, float* qq,
    const __half* zbuf1, const float* Pa0, const float* t1ab, const float* t2aw,
    const float* Pb3, __half* zbuf0, float* P2,
    const int* perm, const int* off, const int* srcarr, const float* dis) {
  if (blockIdx.x < GM) mm2_body(blockIdx.x, mean128, x1a, w2h, s2b, w3l, w3r, pp, qq);
  else d8_l3_body(blockIdx.x - GM, zbuf1, Pa0, t1ab, t2aw, Pb3, zbuf0, P2,
                  perm, off, srcarr, dis);
}

__global__ __launch_bounds__(256) void k_fuseE(
    const __half* zbuf0, const float* Pb2, __half* zbuf1,
    const float* pp, const float* qq, const float* s3b, float* x1s,
    const float* P2, float* uA1,
    const int* perm, const int* off, const int* srcarr, const float* dis) {
  if (blockIdx.x < GM)
    d8_single_body(blockIdx.x, zbuf0, Pb2, zbuf1, perm, off, srcarr, dis);
  else if (blockIdx.x < GM + G1)
    x1s_body(blockIdx.x - GM, pp, qq, s3b, perm, off, srcarr, x1s);
  else
    d1_body(blockIdx.x - GM - G1, P2 + 3 * (size_t)NN, P2 + 2 * (size_t)NN,
            nullptr, 3, uA1, perm, off, srcarr, dis);
}

__global__ __launch_bounds__(256) void k_fuseF(
    const __half* zbuf1, const float* Pb1, __half* zbuf0,
    const float* uA1, const float* P2, float* uA2,
    const int* perm, const int* off, const int* srcarr, const float* dis) {
  if (blockIdx.x < GM)
    d8_single_body(blockIdx.x, zbuf1, Pb1, zbuf0, perm, off, srcarr, dis);
  else
    d1_body(blockIdx.x - GM, uA1, P2 + 1 * (size_t)NN, nullptr, 3, uA2,
            perm, off, srcarr, dis);
}

__global__ __launch_bounds__(256) void k_fuseG(
    const __half* zbuf0, const float* Pb0, const float* t1bb, const float* t2bw,
    float* P2b, const float* uA2, const float* P2, const float* t2ab, float* x2s,
    const int* perm, const int* off, const int* srcarr, const float* dis) {
  if (blockIdx.x < GM)
    d8_l6_body(blockIdx.x, zbuf0, Pb0, t1bb, t2bw, P2b, perm, off, srcarr, dis);
  else
    d1_body(blockIdx.x - GM, uA2, P2, t2ab, 2, x2s, perm, off, srcarr, dis);
}

__global__ __launch_bounds__(256) void k_d1b(
    const float* ua, const float* adda, float* outa,
    const int* perm, const int* off, const int* srcarr, const float* dis) {
  d1_body(blockIdx.x, ua, adda, nullptr, 3, outa, perm, off, srcarr, dis);
}

__global__ __launch_bounds__(256) void k_g1_final(
    const float* ua, const float* adda, const float* biasa,
    const float* x1s, const float* x2s,
    const float* lw, const float* lb,
    const int* perm, const int* off, const int* srcarr, const float* dis,
    float* out) {
  int g = blockIdx.x * 64 + (threadIdx.x >> 2);
  int t = threadIdx.x & 3;
  if (g >= NN) return;
  int node = perm[g];
  int s = off[node], e = off[node + 1];
  float accA = 0.0f;
  for (int p = s + t; p < e; p += 4) accA += ua[srcarr[p]];
  accA += __shfl_xor(accA, 1, 64); accA += __shfl_xor(accA, 2, 64);
  if (t == 0) {
    float x3v = fmaxf(accA * dis[node] + adda[node] + biasa[0], 0.0f);
    float v = x1s[node] * lw[0] + x2s[node] * lw[1] + x3v * lw[2] + lb[0];
    out[node] = fmaxf(v, 0.0f);
  }
}

extern "C" void kernel_launch(void* const* d_in, const int* in_sizes, int n_in,
                              void* d_out, int out_size, void* d_ws, size_t ws_size,
                              hipStream_t stream) {
  const float* x    = (const float*)d_in[0];
  const int*   ei   = (const int*)d_in[1];
  const float* s1wl = (const float*)d_in[2];
  const float* s1wr = (const float*)d_in[3];
  const float* s1b  = (const float*)d_in[4];
  const float* s2wl = (const float*)d_in[5];
  const float* s2wr = (const float*)d_in[6];
  const float* s2b  = (const float*)d_in[7];
  const float* s3wl = (const float*)d_in[8];
  const float* s3wr = (const float*)d_in[9];
  const float* s3b  = (const float*)d_in[10];
  const float* t1aw = (const float*)d_in[11];
  const float* t1ab = (const float*)d_in[12];
  const float* t2aw = (const float*)d_in[13];
  const float* t2ab = (const float*)d_in[14];
  const float* t1bw = (const float*)d_in[15];
  const float* t1bb = (const float*)d_in[16];
  const float* t2bw = (const float*)d_in[17];
  const float* t2bb = (const float*)d_in[18];
  const float* lw   = (const float*)d_in[19];
  const float* lb   = (const float*)d_in[20];
  float* out = (float*)d_out;

  char* basep = (char*)d_ws;
  size_t off = 0;
  auto alloc = [&](size_t bytes) -> void* {
    void* ptr = basep + off;
    off = (off + bytes + 255) & ~(size_t)255;
    return ptr;
  };
  int*      cnt     = (int*)alloc((size_t)NN * 4);
  int*      csr_off = (int*)alloc((size_t)(NN + 1) * 4);
  float*    dis     = (float*)alloc((size_t)NN * 4);
  int*      csr_src = (int*)alloc((size_t)EE * 4);
  unsigned* pairs   = (unsigned*)alloc((size_t)EE * 4);
  int*      perm    = (int*)alloc((size_t)NN * 4);
  int*      ghist   = (int*)alloc(256 * 4);
  int*      gcur    = (int*)alloc(256 * 4);
  int*      bexclB  = (int*)alloc(256 * 4);
  int*      hist    = (int*)alloc(NBIN * 4);
  int*      bincur  = (int*)alloc(NBIN * 4);
  float*    x1s     = (float*)alloc((size_t)NN * 4);
  float*    x2s     = (float*)alloc((size_t)NN * 4);
  float*    pp      = (float*)alloc((size_t)NN * 4);
  float*    qq      = (float*)alloc((size_t)NN * 4);
  float*    uA1     = (float*)alloc((size_t)NN * 4);
  float*    uA2     = (float*)alloc((size_t)NN * 4);
  float*    uB1     = (float*)alloc((size_t)NN * 4);
  float*    uB2     = (float*)alloc((size_t)NN * 4);
  __half*   x12h    = (__half*)alloc((size_t)NN * 12 * 2);
  __half*   A32     = (__half*)alloc((size_t)NN * 32 * 2);
  __half*   w1h     = (__half*)alloc((size_t)128 * 32 * 2);
  __half*   w2h     = (__half*)alloc((size_t)128 * 256 * 2);
  __half*   x1a_h   = (__half*)alloc((size_t)NN * 128 * 2);
  __half*   mean128_h = (__half*)alloc((size_t)NN * 128 * 2);
  // TAG buffers now independent (no overlay — tagP8 runs concurrently with SAGE)
  float*    Pa    = (float*)alloc((size_t)NN * 24 * 4);   // [3][N][8]
  float*    Pb    = (float*)alloc((size_t)NN * 48 * 4);   // [6][N][8]
  __half*   PTop  = (__half*)alloc((size_t)NN * 16 * 2);  // [N][16] interleaved
  __half*   zbuf0 = (__half*)alloc((size_t)NN * 16 * 2);
  __half*   zbuf1 = (__half*)alloc((size_t)NN * 16 * 2);
  float*    P2    = (float*)alloc((size_t)NN * 4 * 4);    // [4][N]
  float*    P2b   = (float*)alloc((size_t)NN * 7 * 4);    // [7][N]

  const size_t S8 = (size_t)NN * 8;
  const size_t S1 = (size_t)NN;

  // ---- CSR build + prep ----
  hipMemsetAsync(ghist, 0, 3840, stream);
  k_bhist_prep<<<BH_B + PREP_B0 + PREP_B1 + 16 + 128, 256, 0, stream>>>(
      ei, ghist, x, s1wl, s1wr, s2wl, s2wr, x12h, A32, w1h, w2h);
  k_b196scan<<<1, 256, 0, stream>>>(ghist, gcur, bexclB, csr_off);
  k_split<<<(EE + 4095) / 4096, 256, 0, stream>>>(ei, gcur, pairs);
  k_bbuild<<<NBK, 256, 0, stream>>>(pairs, bexclB, cnt, csr_off, dis, csr_src, hist);
  k_binscan<<<1, 64, 0, stream>>>(hist, bincur);
  k_scatter<<<(NN + 255) / 256, 256, 0, stream>>>(cnt, bincur, perm);

  // ---- co-scheduled SAGE + TAG ----
  k_fuseA<<<GA + GT, 256, 0, stream>>>(
      x12h, perm, csr_off, csr_src, A32, x, t1aw, t1bw, dis, Pa, Pb, PTop);
  k_fuseB<<<GM + GM, 256, 0, stream>>>(
      A32, w1h, s1b, x1a_h, PTop, Pa + 2 * S8, Pb + 5 * S8, zbuf0,
      perm, csr_off, csr_src, dis);
  k_fuseC<<<GG + GM, 256, 0, stream>>>(
      x1a_h, mean128_h, zbuf0, Pa + 1 * S8, Pb + 4 * S8, zbuf1,
      perm, csr_off, csr_src, dis);
  k_fuseD<<<GM + GM, 256, 0, stream>>>(
      mean128_h, x1a_h, w2h, s2b, s3wl, s3wr, pp, qq,
      zbuf1, Pa, t1ab, t2aw, Pb + 3 * S8, zbuf0, P2,
      perm, csr_off, csr_src, dis);
  k_fuseE<<<GM + G1 + G1, 256, 0, stream>>>(
      zbuf0, Pb + 2 * S8, zbuf1, pp, qq, s3b, x1s, P2, uA1,
      perm, csr_off, csr_src, dis);
  k_fuseF<<<GM + G1, 256, 0, stream>>>(
      zbuf1, Pb + 1 * S8, zbuf0, uA1, P2, uA2,
      perm, csr_off, csr_src, dis);
  k_fuseG<<<GM + G1, 256, 0, stream>>>(
      zbuf0, Pb, t1bb, t2bw, P2b, uA2, P2, t2ab, x2s,
      perm, csr_off, csr_src, dis);

  // ---- d1b tail chain ----
  k_d1b<<<G1, 256, 0, stream>>>(P2b + 6 * S1, P2b + 5 * S1, uB1, perm, csr_off, csr_src, dis);
  k_d1b<<<G1, 256, 0, stream>>>(uB1, P2b + 4 * S1, uB2, perm, csr_off, csr_src, dis);
  k_d1b<<<G1, 256, 0, stream>>>(uB2, P2b + 3 * S1, uB1, perm, csr_off, csr_src, dis);
  k_d1b<<<G1, 256, 0, stream>>>(uB1, P2b + 2 * S1, uB2, perm, csr_off, csr_src, dis);
  k_d1b<<<G1, 256, 0, stream>>>(uB2, P2b + 1 * S1, uB1, perm, csr_off, csr_src, dis);
  k_g1_final<<<G1, 256, 0, stream>>>(
      uB1, P2b, t2bb, x1s, x2s, lw, lb, perm, csr_off, csr_src, dis, out);
}

// Round 10
// 483.672 us; speedup vs baseline: 3.0234x; 1.0083x over previous
//
#include <hip/hip_runtime.h>
#include <hip/hip_bf16.h>
#include <hip/hip_fp16.h>

#define NN 100000
#define EE 1600000
#define NBIN 64
#define BSH 9
#define BSZ 512
#define NBK 196   // ceil(NN/512)

// grid segment sizes
#define GA 1563   // gmean12h blocks (64 nodes/block)
#define GT 391    // tagP8-top blocks (256 nodes/block)
#define GM 782    // mm / d8 blocks (128 nodes/block)
#define G1 1563   // d1 blocks (64 nodes/block)
#define SPB 391   // split blocks (4096 edges/block)
#define TGA 391   // tagP8-adds blocks (256 nodes/block)

typedef _Float16 h8v __attribute__((ext_vector_type(8)));
typedef float f4v __attribute__((ext_vector_type(4)));

__device__ __forceinline__ float sigm(float v) { return 1.0f / (1.0f + expf(-v)); }
__device__ __forceinline__ float4 f4add(float4 a, float4 b) {
  a.x += b.x; a.y += b.y; a.z += b.z; a.w += b.w; return a;
}
__device__ __forceinline__ float4 h4f(uint2 v) {
  __half2 a = *reinterpret_cast<__half2*>(&v.x);
  __half2 b = *reinterpret_cast<__half2*>(&v.y);
  float2 fa = __half22float2(a), fb = __half22float2(b);
  return make_float4(fa.x, fa.y, fb.x, fb.y);
}
__device__ __forceinline__ void h8acc(uint4 v, float* a) {
  float4 lo = h4f(make_uint2(v.x, v.y));
  float4 hi = h4f(make_uint2(v.z, v.w));
  a[0] += lo.x; a[1] += lo.y; a[2] += lo.z; a[3] += lo.w;
  a[4] += hi.x; a[5] += hi.y; a[6] += hi.z; a[7] += hi.w;
}
__device__ __forceinline__ uint2 pack4h(float4 r) {
  __half2 q0 = __floats2half2_rn(r.x, r.y), q1 = __floats2half2_rn(r.z, r.w);
  uint2 o; o.x = *(unsigned*)&q0; o.y = *(unsigned*)&q1; return o;
}

// ================= CSR build + fused prep =================
#define BH_B 512
#define PREP_B0 ((NN * 12 + 255) / 256)
#define PREP_B1 ((NN + 255) / 256)
__global__ __launch_bounds__(256) void k_bhist_prep(
    const int* __restrict__ ei, int* __restrict__ ghist,
    const float* __restrict__ x, const float* __restrict__ s1wl, const float* __restrict__ s1wr,
    const float* __restrict__ s2wl, const float* __restrict__ s2wr,
    __half* __restrict__ x12h, __half* __restrict__ A32,
    __half* __restrict__ w1h, __half* __restrict__ w2h) {
  __shared__ int lh[NBK];
  int bid = blockIdx.x;
  if (bid < BH_B) {
    for (int j = threadIdx.x; j < NBK; j += 256) lh[j] = 0;
    __syncthreads();
    for (int i = bid * 256 + threadIdx.x; i < EE; i += BH_B * 256)
      atomicAdd(&lh[ei[EE + i] >> BSH], 1);
    __syncthreads();
    for (int j = threadIdx.x; j < NBK; j += 256) {
      int v = lh[j];
      if (v) atomicAdd(&ghist[j], v);
    }
    return;
  }
  int pid = bid - BH_B;
  if (pid < PREP_B0) {
    int i = pid * 256 + threadIdx.x;
    if (i < NN * 12) {
      int n = i / 12, j = i - n * 12;
      x12h[i] = __float2half((j < 11) ? x[n * 11 + j] : 0.0f);
    }
  } else if (pid < PREP_B0 + PREP_B1) {
    int i = (pid - PREP_B0) * 256 + threadIdx.x;
    if (i < NN) {
      float a[11];
      #pragma unroll
      for (int j = 0; j < 11; ++j) a[j] = x[(long)i * 11 + j];
      uint2* row = (uint2*)(A32 + (long)i * 32);
      row[3] = make_uint2(0u, 0u);
      row[4] = pack4h(make_float4(a[0], a[1], a[2], a[3]));
      row[5] = pack4h(make_float4(a[4], a[5], a[6], a[7]));
      row[6] = pack4h(make_float4(a[8], a[9], a[10], 0.0f));
      row[7] = make_uint2(0u, 0u);
    }
  } else if (pid < PREP_B0 + PREP_B1 + 16) {
    int i = (pid - PREP_B0 - PREP_B1) * 256 + threadIdx.x;
    int o = i >> 5, k = i & 31;
    float v = 0.0f;
    if (k < 11) v = s1wl[o * 11 + k];
    else if (k >= 16 && k < 27) v = s1wr[o * 11 + (k - 16)];
    w1h[i] = __float2half(v);
  } else {
    int i = (pid - PREP_B0 - PREP_B1 - 16) * 256 + threadIdx.x;
    int o = i >> 8, k = i & 255;
    float v = (k < 128) ? s2wl[o * 128 + k] : s2wr[o * 128 + (k - 128)];
    w2h[i] = __float2half(v);
  }
}

__global__ void k_b196scan(const int* __restrict__ ghist, int* __restrict__ gcur,
                           int* __restrict__ bexclB, int* __restrict__ csr_off) {
  __shared__ int sh[256];
  int tid = threadIdx.x;
  int v = (tid < NBK) ? ghist[tid] : 0;
  sh[tid] = v;
  __syncthreads();
  for (int d = 1; d < 256; d <<= 1) {
    int t = (tid >= d) ? sh[tid - d] : 0;
    __syncthreads();
    sh[tid] += t;
    __syncthreads();
  }
  int excl = sh[tid] - v;
  if (tid < NBK) { gcur[tid] = excl; bexclB[tid] = excl; }
  if (tid == 0) { bexclB[NBK] = EE; csr_off[NN] = EE; }
}

// unscaled TAG first-linear slices (no dis dependency)
__device__ void tagp8_adds_body(int bid, const float* x, const float* t1aw,
                                const float* t1bw, float* Pa, float* Pb) {
  int i = bid * 256 + threadIdx.x;
  if (i >= NN) return;
  float a[11];
  #pragma unroll
  for (int j = 0; j < 11; ++j) a[j] = x[(long)i * 11 + j];
  #pragma unroll
  for (int k = 0; k < 3; ++k) {
    float s[8];
    #pragma unroll
    for (int o = 0; o < 8; ++o) {
      float acc = 0.0f;
      #pragma unroll
      for (int j = 0; j < 11; ++j) acc += a[j] * t1aw[o * 44 + k * 11 + j];
      s[o] = acc;
    }
    float4* dst = (float4*)&Pa[((size_t)k * NN + i) * 8];
    dst[0] = make_float4(s[0], s[1], s[2], s[3]);
    dst[1] = make_float4(s[4], s[5], s[6], s[7]);
  }
  #pragma unroll
  for (int k = 0; k < 6; ++k) {
    float s[8];
    #pragma unroll
    for (int o = 0; o < 8; ++o) {
      float acc = 0.0f;
      #pragma unroll
      for (int j = 0; j < 11; ++j) acc += a[j] * t1bw[o * 77 + k * 11 + j];
      s[o] = acc;
    }
    float4* dst = (float4*)&Pb[((size_t)k * NN + i) * 8];
    dst[0] = make_float4(s[0], s[1], s[2], s[3]);
    dst[1] = make_float4(s[4], s[5], s[6], s[7]);
  }
}

// split + co-scheduled tagP8-adds
__global__ __launch_bounds__(256) void k_split_tag(
    const int* __restrict__ ei, int* __restrict__ gcur, unsigned* __restrict__ pairs,
    const float* __restrict__ x, const float* __restrict__ t1aw,
    const float* __restrict__ t1bw, float* __restrict__ Pa, float* __restrict__ Pb) {
  if (blockIdx.x >= SPB) {
    tagp8_adds_body(blockIdx.x - SPB, x, t1aw, t1bw, Pa, Pb);
    return;
  }
  __shared__ int cntL[256];
  __shared__ int segO[256];
  __shared__ int curL[256];
  __shared__ int baseL[256];
  __shared__ unsigned stag[4096];
  __shared__ unsigned char bktL[4096];
  int tid = threadIdx.x;
  int tile0 = blockIdx.x * 4096;
  int tcnt = min(4096, EE - tile0);
  cntL[tid] = 0; curL[tid] = 0;
  __syncthreads();
  for (int i = tid; i < tcnt; i += 256)
    atomicAdd(&cntL[ei[EE + tile0 + i] >> BSH], 1);
  __syncthreads();
  int v = cntL[tid];
  segO[tid] = v;
  __syncthreads();
  for (int d = 1; d < 256; d <<= 1) {
    int t = (tid >= d) ? segO[tid - d] : 0;
    __syncthreads();
    segO[tid] += t;
    __syncthreads();
  }
  int excl = segO[tid] - v;
  __syncthreads();
  segO[tid] = excl;
  __syncthreads();
  for (int i = tid; i < tcnt; i += 256) {
    int s = ei[tile0 + i], dd = ei[EE + tile0 + i];
    int b = dd >> BSH;
    int slot = segO[b] + atomicAdd(&curL[b], 1);
    stag[slot] = (unsigned)s | ((unsigned)(dd & (BSZ - 1)) << 17);
    bktL[slot] = (unsigned char)b;
  }
  baseL[tid] = v ? atomicAdd(&gcur[tid], v) : 0;
  __syncthreads();
  for (int i = tid; i < tcnt; i += 256) {
    int b = bktL[i];
    pairs[baseL[b] + (i - segO[b])] = stag[i];
  }
}

// per-bucket count + scan + fill + degree-histogram (fused)
__global__ __launch_bounds__(256) void k_bbuild(const unsigned* __restrict__ pairs,
                                                const int* __restrict__ bexclB,
                                                int* __restrict__ cnt, int* __restrict__ csr_off,
                                                float* __restrict__ dis, int* __restrict__ csr_src,
                                                int* __restrict__ hist) {
  __shared__ int c[BSZ];
  __shared__ int ps[256];
  __shared__ int curB[BSZ];
  __shared__ int lhist[NBIN];
  int tid = threadIdx.x;
  int b = blockIdx.x;
  int lo = b << BSH;
  for (int j = tid; j < BSZ; j += 256) c[j] = 0;
  if (tid < NBIN) lhist[tid] = 0;
  __syncthreads();
  int s0e = bexclB[b], s1e = bexclB[b + 1];
  for (int i = s0e + tid; i < s1e; i += 256)
    atomicAdd(&c[pairs[i] >> 17], 1);
  __syncthreads();
  int a0 = c[2 * tid], a1 = c[2 * tid + 1];
  int pv = a0 + a1;
  ps[tid] = pv;
  __syncthreads();
  for (int d = 1; d < 256; d <<= 1) {
    int t = (tid >= d) ? ps[tid - d] : 0;
    __syncthreads();
    ps[tid] += t;
    __syncthreads();
  }
  int pex = ps[tid] - pv;
  int base = s0e + pex;
  int n0 = lo + 2 * tid, n1 = n0 + 1;
  if (n0 < NN) {
    csr_off[n0] = base; cnt[n0] = a0;
    dis[n0] = (a0 > 0) ? rsqrtf((float)a0) : 0.0f;
    atomicAdd(&lhist[min(a0, NBIN - 1)], 1);
  }
  if (n1 < NN) {
    csr_off[n1] = base + a0; cnt[n1] = a1;
    dis[n1] = (a1 > 0) ? rsqrtf((float)a1) : 0.0f;
    atomicAdd(&lhist[min(a1, NBIN - 1)], 1);
  }
  curB[2 * tid] = base;
  curB[2 * tid + 1] = base + a0;
  __syncthreads();
  for (int i = s0e + tid; i < s1e; i += 256) {
    unsigned pk = pairs[i];
    int p = atomicAdd(&curB[pk >> 17], 1);
    csr_src[p] = (int)(pk & 0x1FFFFu);
  }
  __syncthreads();
  if (tid < NBIN) {
    int v = lhist[tid];
    if (v) atomicAdd(&hist[tid], v);
  }
}

__global__ void k_binscan(const int* __restrict__ hist, int* __restrict__ bincur) {
  int tid = threadIdx.x;
  int v = hist[tid];
  int incl = v;
  for (int d = 1; d < 64; d <<= 1) {
    int t = __shfl_up(incl, d, 64);
    if (tid >= d) incl += t;
  }
  bincur[tid] = incl - v;
}
__global__ __launch_bounds__(256) void k_scatter(const int* __restrict__ cnt,
                                                 int* __restrict__ bincur,
                                                 int* __restrict__ perm) {
  __shared__ int lh[NBIN];
  __shared__ int lbase[NBIN];
  if (threadIdx.x < NBIN) lh[threadIdx.x] = 0;
  __syncthreads();
  int i = blockIdx.x * 256 + threadIdx.x;
  int b = 0, r = 0;
  bool valid = i < NN;
  if (valid) {
    b = min(cnt[i], NBIN - 1);
    r = atomicAdd(&lh[b], 1);
  }
  __syncthreads();
  if (threadIdx.x < NBIN) {
    int v = lh[threadIdx.x];
    lbase[threadIdx.x] = v ? atomicAdd(&bincur[threadIdx.x], v) : 0;
  }
  __syncthreads();
  if (valid) perm[lbase[b] + r] = i;
}

// ================= device bodies =================
__device__ void gmean12h_body(int bid, const __half* x12h, const int* perm,
                              const int* off, const int* srcarr, __half* A32) {
  int g = bid * 64 + (threadIdx.x >> 2);
  int t = threadIdx.x & 3;
  if (g >= NN || t >= 3) return;
  int node = perm[g];
  int s = off[node], e = off[node + 1];
  const uint2* h2 = (const uint2*)x12h;
  float4 acc = {0, 0, 0, 0};
  int p = s;
  for (; p + 4 <= e; p += 4) {
    int s0 = srcarr[p], s1 = srcarr[p + 1], s2 = srcarr[p + 2], s3 = srcarr[p + 3];
    acc = f4add(acc, f4add(f4add(h4f(h2[(long)s0 * 3 + t]), h4f(h2[(long)s1 * 3 + t])),
                           f4add(h4f(h2[(long)s2 * 3 + t]), h4f(h2[(long)s3 * 3 + t]))));
  }
  for (; p < e; ++p) acc = f4add(acc, h4f(h2[(long)srcarr[p] * 3 + t]));
  int c = e - s;
  float inv = 1.0f / (float)(c > 0 ? c : 1);
  acc.x *= inv; acc.y *= inv; acc.z *= inv; acc.w *= inv;
  ((uint2*)A32)[(long)node * 8 + t] = pack4h(acc);
}

__device__ void tagp8_top_body(int bid, const float* x, const float* t1aw, const float* t1bw,
                               const float* dis, __half* PTop) {
  int i = bid * 256 + threadIdx.x;
  if (i >= NN) return;
  float a[11];
  #pragma unroll
  for (int j = 0; j < 11; ++j) a[j] = x[(long)i * 11 + j];
  float dn = dis[i];
  {
    float s[8];
    #pragma unroll
    for (int o = 0; o < 8; ++o) {
      float acc = 0.0f;
      #pragma unroll
      for (int j = 0; j < 11; ++j) acc += a[j] * t1aw[o * 44 + 3 * 11 + j];
      s[o] = acc;
    }
    uint2 lo = pack4h(make_float4(s[0] * dn, s[1] * dn, s[2] * dn, s[3] * dn));
    uint2 hi = pack4h(make_float4(s[4] * dn, s[5] * dn, s[6] * dn, s[7] * dn));
    uint4 o4; o4.x = lo.x; o4.y = lo.y; o4.z = hi.x; o4.w = hi.y;
    ((uint4*)PTop)[(long)i * 2] = o4;
  }
  {
    float s[8];
    #pragma unroll
    for (int o = 0; o < 8; ++o) {
      float acc = 0.0f;
      #pragma unroll
      for (int j = 0; j < 11; ++j) acc += a[j] * t1bw[o * 77 + 6 * 11 + j];
      s[o] = acc;
    }
    uint2 lo = pack4h(make_float4(s[0] * dn, s[1] * dn, s[2] * dn, s[3] * dn));
    uint2 hi = pack4h(make_float4(s[4] * dn, s[5] * dn, s[6] * dn, s[7] * dn));
    uint4 o4; o4.x = lo.x; o4.y = lo.y; o4.z = hi.x; o4.w = hi.y;
    ((uint4*)PTop)[(long)i * 2 + 1] = o4;
  }
}

__device__ void d8_dual_body(int bid, const __half* src, const float* addA,
                             const float* addB, __half* dst,
                             const int* perm, const int* off,
                             const int* srcarr, const float* dis) {
  const uint4* src4 = (const uint4*)src;
  int t = threadIdx.x & 1;
  const float4* addp = (const float4*)(t == 0 ? addA : addB);
  int g = bid * 128 + (threadIdx.x >> 1);
  if (g >= NN) return;
  int node = perm[g];
  int s = off[node], e = off[node + 1];
  float acc[8] = {};
  int p = s;
  for (; p + 4 <= e; p += 4) {
    int s0 = srcarr[p], s1 = srcarr[p + 1], s2 = srcarr[p + 2], s3 = srcarr[p + 3];
    h8acc(src4[(long)s0 * 2 + t], acc); h8acc(src4[(long)s1 * 2 + t], acc);
    h8acc(src4[(long)s2 * 2 + t], acc); h8acc(src4[(long)s3 * 2 + t], acc);
  }
  for (; p < e; ++p) h8acc(src4[(long)srcarr[p] * 2 + t], acc);
  float dn = dis[node];
  float4 a0 = addp[(long)node * 2], a1 = addp[(long)node * 2 + 1];
  float4 r0 = make_float4((acc[0] * dn + a0.x) * dn, (acc[1] * dn + a0.y) * dn,
                          (acc[2] * dn + a0.z) * dn, (acc[3] * dn + a0.w) * dn);
  float4 r1 = make_float4((acc[4] * dn + a1.x) * dn, (acc[5] * dn + a1.y) * dn,
                          (acc[6] * dn + a1.z) * dn, (acc[7] * dn + a1.w) * dn);
  uint2 lo = pack4h(r0), hi = pack4h(r1);
  uint4 o; o.x = lo.x; o.y = lo.y; o.z = hi.x; o.w = hi.y;
  ((uint4*)dst)[(long)node * 2 + t] = o;
}

__device__ void d8_l3_body(int bid, const __half* src, const float* Pa0,
                           const float* t1ab, const float* t2aw,
                           const float* Pb3, __half* dstB, float* P2,
                           const int* perm, const int* off,
                           const int* srcarr, const float* dis) {
  const uint4* src4 = (const uint4*)src;
  int t = threadIdx.x & 1;
  int g = bid * 128 + (threadIdx.x >> 1);
  if (g >= NN) return;
  int node = perm[g];
  int s = off[node], e = off[node + 1];
  float acc[8] = {};
  int p = s;
  for (; p + 4 <= e; p += 4) {
    int s0 = srcarr[p], s1 = srcarr[p + 1], s2 = srcarr[p + 2], s3 = srcarr[p + 3];
    h8acc(src4[(long)s0 * 2 + t], acc); h8acc(src4[(long)s1 * 2 + t], acc);
    h8acc(src4[(long)s2 * 2 + t], acc); h8acc(src4[(long)s3 * 2 + t], acc);
  }
  for (; p < e; ++p) h8acc(src4[(long)srcarr[p] * 2 + t], acc);
  float dn = dis[node];
  if (t == 0) {
    const float4* addp = (const float4*)Pa0;
    float4 a0 = addp[(long)node * 2], a1 = addp[(long)node * 2 + 1];
    float4 b0 = ((const float4*)t1ab)[0], b1 = ((const float4*)t1ab)[1];
    float a[8];
    a[0] = sigm(acc[0] * dn + a0.x + b0.x); a[1] = sigm(acc[1] * dn + a0.y + b0.y);
    a[2] = sigm(acc[2] * dn + a0.z + b0.z); a[3] = sigm(acc[3] * dn + a0.w + b0.w);
    a[4] = sigm(acc[4] * dn + a1.x + b1.x); a[5] = sigm(acc[5] * dn + a1.y + b1.y);
    a[6] = sigm(acc[6] * dn + a1.z + b1.z); a[7] = sigm(acc[7] * dn + a1.w + b1.w);
    #pragma unroll
    for (int k = 0; k < 4; ++k) {
      float sv = 0.0f;
      #pragma unroll
      for (int j = 0; j < 8; ++j) sv += a[j] * t2aw[k * 8 + j];
      if (k == 3) sv *= dn;
      P2[(size_t)k * NN + node] = sv;
    }
  } else {
    const float4* addp = (const float4*)Pb3;
    float4 a0 = addp[(long)node * 2], a1 = addp[(long)node * 2 + 1];
    float4 r0 = make_float4((acc[0] * dn + a0.x) * dn, (acc[1] * dn + a0.y) * dn,
                            (acc[2] * dn + a0.z) * dn, (acc[3] * dn + a0.w) * dn);
    float4 r1 = make_float4((acc[4] * dn + a1.x) * dn, (acc[5] * dn + a1.y) * dn,
                            (acc[6] * dn + a1.z) * dn, (acc[7] * dn + a1.w) * dn);
    uint2 lo = pack4h(r0), hi = pack4h(r1);
    uint4 o; o.x = lo.x; o.y = lo.y; o.z = hi.x; o.w = hi.y;
    ((uint4*)dstB)[(long)node * 2 + 1] = o;
  }
}

__device__ void d8_single_body(int bid, const __half* src, const float* addB, __half* dst,
                               const int* perm, const int* off,
                               const int* srcarr, const float* dis) {
  const uint2* src2 = (const uint2*)src;
  int t = threadIdx.x & 1;
  int g = bid * 128 + (threadIdx.x >> 1);
  if (g >= NN) return;
  int node = perm[g];
  int s = off[node], e = off[node + 1];
  float4 acc = {0, 0, 0, 0};
  int p = s;
  for (; p + 4 <= e; p += 4) {
    int s0 = srcarr[p], s1 = srcarr[p + 1], s2 = srcarr[p + 2], s3 = srcarr[p + 3];
    acc = f4add(acc, f4add(f4add(h4f(src2[(long)s0 * 4 + 2 + t]), h4f(src2[(long)s1 * 4 + 2 + t])),
                           f4add(h4f(src2[(long)s2 * 4 + 2 + t]), h4f(src2[(long)s3 * 4 + 2 + t]))));
  }
  for (; p < e; ++p) acc = f4add(acc, h4f(src2[(long)srcarr[p] * 4 + 2 + t]));
  float dn = dis[node];
  float4 av = ((const float4*)addB)[(long)node * 2 + t];
  float4 r = make_float4((acc.x * dn + av.x) * dn, (acc.y * dn + av.y) * dn,
                         (acc.z * dn + av.z) * dn, (acc.w * dn + av.w) * dn);
  ((uint2*)dst)[(long)node * 4 + 2 + t] = pack4h(r);
}

__device__ void d8_l6_body(int bid, const __half* src, const float* Pb0,
                           const float* t1bb, const float* t2bw, float* P2b,
                           const int* perm, const int* off,
                           const int* srcarr, const float* dis) {
  const uint2* src2 = (const uint2*)src;
  int t = threadIdx.x & 1;
  int g = bid * 128 + (threadIdx.x >> 1);
  if (g >= NN) return;
  int node = perm[g];
  int s = off[node], e = off[node + 1];
  float4 acc = {0, 0, 0, 0};
  int p = s;
  for (; p + 4 <= e; p += 4) {
    int s0 = srcarr[p], s1 = srcarr[p + 1], s2 = srcarr[p + 2], s3 = srcarr[p + 3];
    acc = f4add(acc, f4add(f4add(h4f(src2[(long)s0 * 4 + 2 + t]), h4f(src2[(long)s1 * 4 + 2 + t])),
                           f4add(h4f(src2[(long)s2 * 4 + 2 + t]), h4f(src2[(long)s3 * 4 + 2 + t]))));
  }
  for (; p < e; ++p) acc = f4add(acc, h4f(src2[(long)srcarr[p] * 4 + 2 + t]));
  float dn = dis[node];
  float4 av = ((const float4*)Pb0)[(long)node * 2 + t];
  float4 bv = ((const float4*)t1bb)[t];
  float4 r = make_float4(sigm(acc.x * dn + av.x + bv.x), sigm(acc.y * dn + av.y + bv.y),
                         sigm(acc.z * dn + av.z + bv.z), sigm(acc.w * dn + av.w + bv.w));
  float o0 = __shfl_xor(r.x, 1, 64), o1 = __shfl_xor(r.y, 1, 64);
  float o2 = __shfl_xor(r.z, 1, 64), o3 = __shfl_xor(r.w, 1, 64);
  if (t == 0) {
    float a[8] = {r.x, r.y, r.z, r.w, o0, o1, o2, o3};
    #pragma unroll
    for (int k = 0; k < 7; ++k) {
      float sv = 0.0f;
      #pragma unroll
      for (int j = 0; j < 8; ++j) sv += a[j] * t2bw[k * 8 + j];
      if (k == 6) sv *= dn;
      P2b[(size_t)k * NN + node] = sv;
    }
  }
}

__device__ void d1_body(int bid, const float* ua, const float* adda, const float* bias,
                        int act, float* outa, const int* perm, const int* off,
                        const int* srcarr, const float* dis) {
  int g = bid * 64 + (threadIdx.x >> 2);
  int t = threadIdx.x & 3;
  if (g >= NN) return;
  int node = perm[g];
  int s = off[node], e = off[node + 1];
  float accA = 0.0f;
  for (int p = s + t; p < e; p += 4) accA += ua[srcarr[p]];
  accA += __shfl_xor(accA, 1, 64); accA += __shfl_xor(accA, 2, 64);
  if (t == 0) {
    float sc = dis[node];
    float rA = accA * sc + adda[node];
    if (bias) rA += bias[0];
    if (act == 3) rA *= sc; else if (act == 2) rA = fmaxf(rA, 0.0f);
    outa[node] = rA;
  }
}

__device__ void x1s_body(int bid, const float* pp, const float* qq, const float* s3b,
                         const int* perm, const int* off, const int* srcarr,
                         float* x1s) {
  int g = bid * 64 + (threadIdx.x >> 2);
  int t = threadIdx.x & 3;
  if (g >= NN) return;
  int node = perm[g];
  int s = off[node], e = off[node + 1];
  float acc = 0.0f;
  for (int p = s + t; p < e; p += 4) acc += pp[srcarr[p]];
  acc += __shfl_xor(acc, 1, 64); acc += __shfl_xor(acc, 2, 64);
  if (t == 0) {
    int c = e - s;
    float sc = 1.0f / (float)(c > 0 ? c : 1);
    x1s[node] = fmaxf(acc * sc + qq[node] + s3b[0], 0.0f);
  }
}

__device__ void mm1_body(int bid, const __half* A32, const __half* W32,
                         const float* bias, __half* out, __half (*lt)[32][136]) {
  int tid = threadIdx.x;
  int wave = tid >> 6, l = tid & 63;
  int lr = l & 15, lk = l >> 4;
  int m0 = bid * 128 + wave * 32;
  f4v acc[2][8] = {};
  h8v afrag[2];
  #pragma unroll
  for (int rt = 0; rt < 2; ++rt) {
    int row = m0 + rt * 16 + lr;
    h8v z = {};
    afrag[rt] = (row < NN) ? *(const h8v*)&A32[(long)row * 32 + lk * 8] : z;
  }
  #pragma unroll
  for (int c = 0; c < 8; ++c) {
    h8v bfrag = *(const h8v*)&W32[(c * 16 + lr) * 32 + lk * 8];
    acc[0][c] = __builtin_amdgcn_mfma_f32_16x16x32_f16(afrag[0], bfrag, acc[0][c], 0, 0, 0);
    acc[1][c] = __builtin_amdgcn_mfma_f32_16x16x32_f16(afrag[1], bfrag, acc[1][c], 0, 0, 0);
  }
  float bi[8];
  #pragma unroll
  for (int c = 0; c < 8; ++c) bi[c] = bias[c * 16 + lr];
  #pragma unroll
  for (int rt = 0; rt < 2; ++rt)
    #pragma unroll
    for (int c = 0; c < 8; ++c)
      #pragma unroll
      for (int reg = 0; reg < 4; ++reg) {
        float v = acc[rt][c][reg] + bi[c];
        lt[wave][rt * 16 + lk * 4 + reg][c * 16 + lr] = __float2half(sigm(v));
      }
  __syncthreads();
  #pragma unroll
  for (int it = 0; it < 8; ++it) {
    int idx = it * 64 + l;
    int row = idx >> 4, c16 = idx & 15;
    int grow = m0 + row;
    if (grow < NN) {
      uint4 v = *(const uint4*)&lt[wave][row][c16 * 8];
      ((uint4*)out)[(long)grow * 16 + c16] = v;
    }
  }
}

// fused gather128 + mm2: gathers means into LDS (two 64-col passes), MFMA from LDS
__device__ void gmm2_body(int bid, const __half* x1a, const __half* W,
                          const float* bias, const float* w3l, const float* w3r,
                          float* pp, float* qq,
                          const int* perm, const int* off, const int* srcarr,
                          __half (*lt)[72]) {
  int tid = threadIdx.x;
  int m0 = bid * 128;
  const uint4* h4 = (const uint4*)x1a;
  int wave = tid >> 6, l = tid & 63;
  int lr = l & 15, lk = l >> 4;
  int mrow0 = m0 + wave * 32;
  f4v acc[2][8] = {};

  #pragma unroll
  for (int half = 0; half < 2; ++half) {
    int t8 = tid & 7;
    int colu = half * 8 + t8;           // uint4 index in 128-half row (16 per row)
    #pragma unroll
    for (int it = 0; it < 4; ++it) {
      int gl = (tid >> 3) + 32 * it;    // 0..127
      int g = m0 + gl;
      float a[8] = {};
      if (g < NN) {
        int node = perm[g];
        int s = off[node], e = off[node + 1];
        int p = s;
        for (; p + 4 <= e; p += 4) {
          int s0 = srcarr[p], s1 = srcarr[p + 1], s2 = srcarr[p + 2], s3 = srcarr[p + 3];
          h8acc(h4[(long)s0 * 16 + colu], a); h8acc(h4[(long)s1 * 16 + colu], a);
          h8acc(h4[(long)s2 * 16 + colu], a); h8acc(h4[(long)s3 * 16 + colu], a);
        }
        for (; p < e; ++p) h8acc(h4[(long)srcarr[p] * 16 + colu], a);
        int c = e - s;
        float inv = 1.0f / (float)(c > 0 ? c : 1);
        #pragma unroll
        for (int j = 0; j < 8; ++j) a[j] *= inv;
      }
      uint2 lo = pack4h(make_float4(a[0], a[1], a[2], a[3]));
      uint2 hi = pack4h(make_float4(a[4], a[5], a[6], a[7]));
      uint4 o; o.x = lo.x; o.y = lo.y; o.z = hi.x; o.w = hi.y;
      *(uint4*)&lt[gl][t8 * 8] = o;
    }
    __syncthreads();
    #pragma unroll
    for (int ks2 = 0; ks2 < 2; ++ks2) {
      int ks = half * 2 + ks2;
      h8v afrag[2];
      #pragma unroll
      for (int rt = 0; rt < 2; ++rt) {
        int rl = wave * 32 + rt * 16 + lr;   // local row 0..127
        afrag[rt] = *(const h8v*)&lt[rl][ks2 * 32 + lk * 8];
      }
      #pragma unroll
      for (int c = 0; c < 8; ++c) {
        h8v bfrag = *(const h8v*)&W[(long)(c * 16 + lr) * 256 + ks * 32 + lk * 8];
        acc[0][c] = __builtin_amdgcn_mfma_f32_16x16x32_f16(afrag[0], bfrag, acc[0][c], 0, 0, 0);
        acc[1][c] = __builtin_amdgcn_mfma_f32_16x16x32_f16(afrag[1], bfrag, acc[1][c], 0, 0, 0);
      }
    }
    __syncthreads();
  }
  // A2 = x1a rows (perm-mapped)
  int prow[2];
  #pragma unroll
  for (int rt = 0; rt < 2; ++rt) {
    int row = mrow0 + rt * 16 + lr;
    prow[rt] = (row < NN) ? perm[row] : -1;
  }
  #pragma unroll
  for (int ks = 4; ks < 8; ++ks) {
    int kk = (ks & 3) * 32 + lk * 8;
    h8v afrag[2];
    #pragma unroll
    for (int rt = 0; rt < 2; ++rt) {
      h8v z = {};
      afrag[rt] = (prow[rt] >= 0) ? *(const h8v*)&x1a[(long)prow[rt] * 128 + kk] : z;
    }
    #pragma unroll
    for (int c = 0; c < 8; ++c) {
      h8v bfrag = *(const h8v*)&W[(long)(c * 16 + lr) * 256 + ks * 32 + lk * 8];
      acc[0][c] = __builtin_amdgcn_mfma_f32_16x16x32_f16(afrag[0], bfrag, acc[0][c], 0, 0, 0);
      acc[1][c] = __builtin_amdgcn_mfma_f32_16x16x32_f16(afrag[1], bfrag, acc[1][c], 0, 0, 0);
    }
  }
  float wl[8], wr[8], bi[8];
  #pragma unroll
  for (int c = 0; c < 8; ++c) {
    wl[c] = w3l[c * 16 + lr];
    wr[c] = w3r[c * 16 + lr];
    bi[c] = bias[c * 16 + lr];
  }
  #pragma unroll
  for (int rt = 0; rt < 2; ++rt) {
    #pragma unroll
    for (int reg = 0; reg < 4; ++reg) {
      float s1 = 0.0f, s2 = 0.0f;
      #pragma unroll
      for (int c = 0; c < 8; ++c) {
        float v = acc[rt][c][reg] + bi[c];
        float sg = sigm(v);
        s1 += sg * wl[c];
        s2 += sg * wr[c];
      }
      #pragma unroll
      for (int d = 1; d < 16; d <<= 1) {
        s1 += __shfl_xor(s1, d, 64);
        s2 += __shfl_xor(s2, d, 64);
      }
      int row = mrow0 + rt * 16 + lk * 4 + reg;
      if (lr == 0 && row < NN) {
        int node = perm[row];
        pp[node] = s1; qq[node] = s2;
      }
    }
  }
}

// ================= fused dispatches =================
__global__ __launch_bounds__(256) void k_fuseA(
    const __half* x12h, const int* perm, const int* off, const int* srcarr, __half* A32,
    const float* x, const float* t1aw, const float* t1bw, const float* dis, __half* PTop) {
  if (blockIdx.x < GA) gmean12h_body(blockIdx.x, x12h, perm, off, srcarr, A32);
  else tagp8_top_body(blockIdx.x - GA, x, t1aw, t1bw, dis, PTop);
}

__global__ __launch_bounds__(256) void k_fuseB(
    const __half* A32, const __half* W32, const float* s1b, __half* x1a,
    const __half* PTop, const float* Pa2, const float* Pb5, __half* zbuf0,
    const int* perm, const int* off, const int* srcarr, const float* dis) {
  __shared__ __half lt[4][32][136];
  if (blockIdx.x < GM) mm1_body(blockIdx.x, A32, W32, s1b, x1a, lt);
  else d8_dual_body(blockIdx.x - GM, PTop, Pa2, Pb5, zbuf0, perm, off, srcarr, dis);
}

__global__ __launch_bounds__(256) void k_fuseC(
    const __half* x1a, const __half* w2h, const float* s2b,
    const float* w3l, const float* w3r, float* pp, float* qq,
    const __half* zbuf0, const float* Pa1, const float* Pb4, __half* zbuf1,
    const int* perm, const int* off, const int* srcarr, const float* dis) {
  __shared__ __half lt[128][72];
  if (blockIdx.x < GM)
    gmm2_body(blockIdx.x, x1a, w2h, s2b, w3l, w3r, pp, qq, perm, off, srcarr, lt);
  else
    d8_dual_body(blockIdx.x - GM, zbuf0, Pa1, Pb4, zbuf1, perm, off, srcarr, dis);
}

__global__ __launch_bounds__(256) void k_fuseD(
    const __half* zbuf1, const float* Pa0, const float* t1ab, const float* t2aw,
    const float* Pb3, __half* zbuf0, float* P2,
    const float* pp, const float* qq, const float* s3b, float* x1s,
    const int* perm, const int* off, const int* srcarr, const float* dis) {
  if (blockIdx.x < GM)
    d8_l3_body(blockIdx.x, zbuf1, Pa0, t1ab, t2aw, Pb3, zbuf0, P2, perm, off, srcarr, dis);
  else
    x1s_body(blockIdx.x - GM, pp, qq, s3b, perm, off, srcarr, x1s);
}

__global__ __launch_bounds__(256) void k_fuseE(
    const __half* zbuf0, const float* Pb2, __half* zbuf1,
    const float* P2, float* uA1,
    const int* perm, const int* off, const int* srcarr, const float* dis) {
  if (blockIdx.x < GM)
    d8_single_body(blockIdx.x, zbuf0, Pb2, zbuf1, perm, off, srcarr, dis);
  else
    d1_body(blockIdx.x - GM, P2 + 3 * (size_t)NN, P2 + 2 * (size_t)NN,
            nullptr, 3, uA1, perm, off, srcarr, dis);
}

__global__ __launch_bounds__(256) void k_fuseF(
    const __half* zbuf1, const float* Pb1, __half* zbuf0,
    const float* uA1, const float* P2, float* uA2,
    const int* perm, const int* off, const int* srcarr, const float* dis) {
  if (blockIdx.x < GM)
    d8_single_body(blockIdx.x, zbuf1, Pb1, zbuf0, perm, off, srcarr, dis);
  else
    d1_body(blockIdx.x - GM, uA1, P2 + 1 * (size_t)NN, nullptr, 3, uA2,
            perm, off, srcarr, dis);
}

__global__ __launch_bounds__(256) void k_fuseG(
    const __half* zbuf0, const float* Pb0, const float* t1bb, const float* t2bw,
    float* P2b, const float* uA2, const float* P2, const float* t2ab, float* x2s,
    const int* perm, const int* off, const int* srcarr, const float* dis) {
  if (blockIdx.x < GM)
    d8_l6_body(blockIdx.x, zbuf0, Pb0, t1bb, t2bw, P2b, perm, off, srcarr, dis);
  else
    d1_body(blockIdx.x - GM, uA2, P2, t2ab, 2, x2s, perm, off, srcarr, dis);
}

__global__ __launch_bounds__(256) void k_d1b(
    const float* ua, const float* adda, float* outa,
    const int* perm, const int* off, const int* srcarr, const float* dis) {
  d1_body(blockIdx.x, ua, adda, nullptr, 3, outa, perm, off, srcarr, dis);
}

__global__ __launch_bounds__(256) void k_g1_final(
    const float* ua, const float* adda, const float* biasa,
    const float* x1s, const float* x2s,
    const float* lw, const float* lb,
    const int* perm, const int* off, const int* srcarr, const float* dis,
    float* out) {
  int g = blockIdx.x * 64 + (threadIdx.x >> 2);
  int t = threadIdx.x & 3;
  if (g >= NN) return;
  int node = perm[g];
  int s = off[node], e = off[node + 1];
  float accA = 0.0f;
  for (int p = s + t; p < e; p += 4) accA += ua[srcarr[p]];
  accA += __shfl_xor(accA, 1, 64); accA += __shfl_xor(accA, 2, 64);
  if (t == 0) {
    float x3v = fmaxf(accA * dis[node] + adda[node] + biasa[0], 0.0f);
    float v = x1s[node] * lw[0] + x2s[node] * lw[1] + x3v * lw[2] + lb[0];
    out[node] = fmaxf(v, 0.0f);
  }
}

extern "C" void kernel_launch(void* const* d_in, const int* in_sizes, int n_in,
                              void* d_out, int out_size, void* d_ws, size_t ws_size,
                              hipStream_t stream) {
  const float* x    = (const float*)d_in[0];
  const int*   ei   = (const int*)d_in[1];
  const float* s1wl = (const float*)d_in[2];
  const float* s1wr = (const float*)d_in[3];
  const float* s1b  = (const float*)d_in[4];
  const float* s2wl = (const float*)d_in[5];
  const float* s2wr = (const float*)d_in[6];
  const float* s2b  = (const float*)d_in[7];
  const float* s3wl = (const float*)d_in[8];
  const float* s3wr = (const float*)d_in[9];
  const float* s3b  = (const float*)d_in[10];
  const float* t1aw = (const float*)d_in[11];
  const float* t1ab = (const float*)d_in[12];
  const float* t2aw = (const float*)d_in[13];
  const float* t2ab = (const float*)d_in[14];
  const float* t1bw = (const float*)d_in[15];
  const float* t1bb = (const float*)d_in[16];
  const float* t2bw = (const float*)d_in[17];
  const float* t2bb = (const float*)d_in[18];
  const float* lw   = (const float*)d_in[19];
  const float* lb   = (const float*)d_in[20];
  float* out = (float*)d_out;

  char* basep = (char*)d_ws;
  size_t off = 0;
  auto alloc = [&](size_t bytes) -> void* {
    void* ptr = basep + off;
    off = (off + bytes + 255) & ~(size_t)255;
    return ptr;
  };
  int*      cnt     = (int*)alloc((size_t)NN * 4);
  int*      csr_off = (int*)alloc((size_t)(NN + 1) * 4);
  float*    dis     = (float*)alloc((size_t)NN * 4);
  int*      csr_src = (int*)alloc((size_t)EE * 4);
  unsigned* pairs   = (unsigned*)alloc((size_t)EE * 4);
  int*      perm    = (int*)alloc((size_t)NN * 4);
  int*      ghist   = (int*)alloc(256 * 4);
  int*      gcur    = (int*)alloc(256 * 4);
  int*      bexclB  = (int*)alloc(256 * 4);
  int*      hist    = (int*)alloc(NBIN * 4);
  int*      bincur  = (int*)alloc(NBIN * 4);
  float*    x1s     = (float*)alloc((size_t)NN * 4);
  float*    x2s     = (float*)alloc((size_t)NN * 4);
  float*    pp      = (float*)alloc((size_t)NN * 4);
  float*    qq      = (float*)alloc((size_t)NN * 4);
  float*    uA1     = (float*)alloc((size_t)NN * 4);
  float*    uA2     = (float*)alloc((size_t)NN * 4);
  float*    uB1     = (float*)alloc((size_t)NN * 4);
  float*    uB2     = (float*)alloc((size_t)NN * 4);
  __half*   x12h    = (__half*)alloc((size_t)NN * 12 * 2);
  __half*   A32     = (__half*)alloc((size_t)NN * 32 * 2);
  __half*   w1h     = (__half*)alloc((size_t)128 * 32 * 2);
  __half*   w2h     = (__half*)alloc((size_t)128 * 256 * 2);
  __half*   x1a_h   = (__half*)alloc((size_t)NN * 128 * 2);
  float*    Pa    = (float*)alloc((size_t)NN * 24 * 4);   // [3][N][8]
  float*    Pb    = (float*)alloc((size_t)NN * 48 * 4);   // [6][N][8]
  __half*   PTop  = (__half*)alloc((size_t)NN * 16 * 2);  // [N][16] interleaved
  __half*   zbuf0 = (__half*)alloc((size_t)NN * 16 * 2);
  __half*   zbuf1 = (__half*)alloc((size_t)NN * 16 * 2);
  float*    P2    = (float*)alloc((size_t)NN * 4 * 4);    // [4][N]
  float*    P2b   = (float*)alloc((size_t)NN * 7 * 4);    // [7][N]

  const size_t S8 = (size_t)NN * 8;
  const size_t S1 = (size_t)NN;

  // ---- CSR build + prep ----
  hipMemsetAsync(ghist, 0, 3840, stream);
  k_bhist_prep<<<BH_B + PREP_B0 + PREP_B1 + 16 + 128, 256, 0, stream>>>(
      ei, ghist, x, s1wl, s1wr, s2wl, s2wr, x12h, A32, w1h, w2h);
  k_b196scan<<<1, 256, 0, stream>>>(ghist, gcur, bexclB, csr_off);
  k_split_tag<<<SPB + TGA, 256, 0, stream>>>(ei, gcur, pairs, x, t1aw, t1bw, Pa, Pb);
  k_bbuild<<<NBK, 256, 0, stream>>>(pairs, bexclB, cnt, csr_off, dis, csr_src, hist);
  k_binscan<<<1, 64, 0, stream>>>(hist, bincur);
  k_scatter<<<(NN + 255) / 256, 256, 0, stream>>>(cnt, bincur, perm);

  // ---- co-scheduled SAGE + TAG ----
  k_fuseA<<<GA + GT, 256, 0, stream>>>(
      x12h, perm, csr_off, csr_src, A32, x, t1aw, t1bw, dis, PTop);
  k_fuseB<<<GM + GM, 256, 0, stream>>>(
      A32, w1h, s1b, x1a_h, PTop, Pa + 2 * S8, Pb + 5 * S8, zbuf0,
      perm, csr_off, csr_src, dis);
  k_fuseC<<<GM + GM, 256, 0, stream>>>(
      x1a_h, w2h, s2b, s3wl, s3wr, pp, qq,
      zbuf0, Pa + 1 * S8, Pb + 4 * S8, zbuf1,
      perm, csr_off, csr_src, dis);
  k_fuseD<<<GM + G1, 256, 0, stream>>>(
      zbuf1, Pa, t1ab, t2aw, Pb + 3 * S8, zbuf0, P2,
      pp, qq, s3b, x1s,
      perm, csr_off, csr_src, dis);
  k_fuseE<<<GM + G1, 256, 0, stream>>>(
      zbuf0, Pb + 2 * S8, zbuf1, P2, uA1,
      perm, csr_off, csr_src, dis);
  k_fuseF<<<GM + G1, 256, 0, stream>>>(
      zbuf1, Pb + 1 * S8, zbuf0, uA1, P2, uA2,
      perm, csr_off, csr_src, dis);
  k_fuseG<<<GM + G1, 256, 0, stream>>>(
      zbuf0, Pb, t1bb, t2bw, P2b, uA2, P2, t2ab, x2s,
      perm, csr_off, csr_src, dis);

  // ---- d1b tail chain ----
  k_d1b<<<G1, 256, 0, stream>>>(P2b + 6 * S1, P2b + 5 * S1, uB1, perm, csr_off, csr_src, dis);
  k_d1b<<<G1, 256, 0, stream>>>(uB1, P2b + 4 * S1, uB2, perm, csr_off, csr_src, dis);
  k_d1b<<<G1, 256, 0, stream>>>(uB2, P2b + 3 * S1, uB1, perm, csr_off, csr_src, dis);
  k_d1b<<<G1, 256, 0, stream>>>(uB1, P2b + 2 * S1, uB2, perm, csr_off, csr_src, dis);
  k_d1b<<<G1, 256, 0, stream>>>(uB2, P2b + 1 * S1, uB1, perm, csr_off, csr_src, dis);
  k_g1_final<<<G1, 256, 0, stream>>>(
      uB1, P2b, t2bb, x1s, x2s, lw, lb, perm, csr_off, csr_src, dis, out);
}

// Round 11
// 469.726 us; speedup vs baseline: 3.1132x; 1.0297x over previous
//
#include <hip/hip_runtime.h>
#include <hip/hip_bf16.h>
#include <hip/hip_fp16.h>

#define NN 100000
#define EE 1600000
#define NBIN 64
#define BSH 9
#define BSZ 512
#define NBK 196   // ceil(NN/512)

// grid segment sizes
#define GA 1563   // gmean12h blocks (64 nodes/block)
#define GT 391    // tagP8-top blocks (256 nodes/block)
#define GM 782    // mm / d8 blocks (128 nodes/block)
#define GG 6250   // gather128 blocks (16 nodes/block)
#define G1 1563   // d1 blocks (64 nodes/block)
#define SPB 391   // split blocks (4096 edges/block)
#define TGA 391   // tagP8-adds blocks (256 nodes/block)

typedef _Float16 h8v __attribute__((ext_vector_type(8)));
typedef float f4v __attribute__((ext_vector_type(4)));

__device__ __forceinline__ float sigm(float v) { return 1.0f / (1.0f + expf(-v)); }
__device__ __forceinline__ float4 f4add(float4 a, float4 b) {
  a.x += b.x; a.y += b.y; a.z += b.z; a.w += b.w; return a;
}
__device__ __forceinline__ float4 h4f(uint2 v) {
  __half2 a = *reinterpret_cast<__half2*>(&v.x);
  __half2 b = *reinterpret_cast<__half2*>(&v.y);
  float2 fa = __half22float2(a), fb = __half22float2(b);
  return make_float4(fa.x, fa.y, fb.x, fb.y);
}
__device__ __forceinline__ void h8acc(uint4 v, float* a) {
  float4 lo = h4f(make_uint2(v.x, v.y));
  float4 hi = h4f(make_uint2(v.z, v.w));
  a[0] += lo.x; a[1] += lo.y; a[2] += lo.z; a[3] += lo.w;
  a[4] += hi.x; a[5] += hi.y; a[6] += hi.z; a[7] += hi.w;
}
__device__ __forceinline__ uint2 pack4h(float4 r) {
  __half2 q0 = __floats2half2_rn(r.x, r.y), q1 = __floats2half2_rn(r.z, r.w);
  uint2 o; o.x = *(unsigned*)&q0; o.y = *(unsigned*)&q1; return o;
}

// ================= CSR build + fused prep =================
#define BH_B 512
#define PREP_B0 ((NN * 12 + 255) / 256)
#define PREP_B1 ((NN + 255) / 256)
__global__ __launch_bounds__(256) void k_bhist_prep(
    const int* __restrict__ ei, int* __restrict__ ghist,
    const float* __restrict__ x, const float* __restrict__ s1wl, const float* __restrict__ s1wr,
    const float* __restrict__ s2wl, const float* __restrict__ s2wr,
    __half* __restrict__ x12h, __half* __restrict__ A32,
    __half* __restrict__ w1h, __half* __restrict__ w2h) {
  __shared__ int lh[NBK];
  int bid = blockIdx.x;
  if (bid < BH_B) {
    for (int j = threadIdx.x; j < NBK; j += 256) lh[j] = 0;
    __syncthreads();
    for (int i = bid * 256 + threadIdx.x; i < EE; i += BH_B * 256)
      atomicAdd(&lh[ei[EE + i] >> BSH], 1);
    __syncthreads();
    for (int j = threadIdx.x; j < NBK; j += 256) {
      int v = lh[j];
      if (v) atomicAdd(&ghist[j], v);
    }
    return;
  }
  int pid = bid - BH_B;
  if (pid < PREP_B0) {
    int i = pid * 256 + threadIdx.x;
    if (i < NN * 12) {
      int n = i / 12, j = i - n * 12;
      x12h[i] = __float2half((j < 11) ? x[n * 11 + j] : 0.0f);
    }
  } else if (pid < PREP_B0 + PREP_B1) {
    int i = (pid - PREP_B0) * 256 + threadIdx.x;
    if (i < NN) {
      float a[11];
      #pragma unroll
      for (int j = 0; j < 11; ++j) a[j] = x[(long)i * 11 + j];
      uint2* row = (uint2*)(A32 + (long)i * 32);
      row[3] = make_uint2(0u, 0u);
      row[4] = pack4h(make_float4(a[0], a[1], a[2], a[3]));
      row[5] = pack4h(make_float4(a[4], a[5], a[6], a[7]));
      row[6] = pack4h(make_float4(a[8], a[9], a[10], 0.0f));
      row[7] = make_uint2(0u, 0u);
    }
  } else if (pid < PREP_B0 + PREP_B1 + 16) {
    int i = (pid - PREP_B0 - PREP_B1) * 256 + threadIdx.x;
    int o = i >> 5, k = i & 31;
    float v = 0.0f;
    if (k < 11) v = s1wl[o * 11 + k];
    else if (k >= 16 && k < 27) v = s1wr[o * 11 + (k - 16)];
    w1h[i] = __float2half(v);
  } else {
    int i = (pid - PREP_B0 - PREP_B1 - 16) * 256 + threadIdx.x;
    int o = i >> 8, k = i & 255;
    float v = (k < 128) ? s2wl[o * 128 + k] : s2wr[o * 128 + (k - 128)];
    w2h[i] = __float2half(v);
  }
}

__global__ void k_b196scan(const int* __restrict__ ghist, int* __restrict__ gcur,
                           int* __restrict__ bexclB, int* __restrict__ csr_off) {
  __shared__ int sh[256];
  int tid = threadIdx.x;
  int v = (tid < NBK) ? ghist[tid] : 0;
  sh[tid] = v;
  __syncthreads();
  for (int d = 1; d < 256; d <<= 1) {
    int t = (tid >= d) ? sh[tid - d] : 0;
    __syncthreads();
    sh[tid] += t;
    __syncthreads();
  }
  int excl = sh[tid] - v;
  if (tid < NBK) { gcur[tid] = excl; bexclB[tid] = excl; }
  if (tid == 0) { bexclB[NBK] = EE; csr_off[NN] = EE; }
}

// unscaled TAG first-linear slices (no dis dependency)
__device__ void tagp8_adds_body(int bid, const float* x, const float* t1aw,
                                const float* t1bw, float* Pa, float* Pb) {
  int i = bid * 256 + threadIdx.x;
  if (i >= NN) return;
  float a[11];
  #pragma unroll
  for (int j = 0; j < 11; ++j) a[j] = x[(long)i * 11 + j];
  #pragma unroll
  for (int k = 0; k < 3; ++k) {
    float s[8];
    #pragma unroll
    for (int o = 0; o < 8; ++o) {
      float acc = 0.0f;
      #pragma unroll
      for (int j = 0; j < 11; ++j) acc += a[j] * t1aw[o * 44 + k * 11 + j];
      s[o] = acc;
    }
    float4* dst = (float4*)&Pa[((size_t)k * NN + i) * 8];
    dst[0] = make_float4(s[0], s[1], s[2], s[3]);
    dst[1] = make_float4(s[4], s[5], s[6], s[7]);
  }
  #pragma unroll
  for (int k = 0; k < 6; ++k) {
    float s[8];
    #pragma unroll
    for (int o = 0; o < 8; ++o) {
      float acc = 0.0f;
      #pragma unroll
      for (int j = 0; j < 11; ++j) acc += a[j] * t1bw[o * 77 + k * 11 + j];
      s[o] = acc;
    }
    float4* dst = (float4*)&Pb[((size_t)k * NN + i) * 8];
    dst[0] = make_float4(s[0], s[1], s[2], s[3]);
    dst[1] = make_float4(s[4], s[5], s[6], s[7]);
  }
}

// split + co-scheduled tagP8-adds
__global__ __launch_bounds__(256) void k_split_tag(
    const int* __restrict__ ei, int* __restrict__ gcur, unsigned* __restrict__ pairs,
    const float* __restrict__ x, const float* __restrict__ t1aw,
    const float* __restrict__ t1bw, float* __restrict__ Pa, float* __restrict__ Pb) {
  if (blockIdx.x >= SPB) {
    tagp8_adds_body(blockIdx.x - SPB, x, t1aw, t1bw, Pa, Pb);
    return;
  }
  __shared__ int cntL[256];
  __shared__ int segO[256];
  __shared__ int curL[256];
  __shared__ int baseL[256];
  __shared__ unsigned stag[4096];
  __shared__ unsigned char bktL[4096];
  int tid = threadIdx.x;
  int tile0 = blockIdx.x * 4096;
  int tcnt = min(4096, EE - tile0);
  cntL[tid] = 0; curL[tid] = 0;
  __syncthreads();
  for (int i = tid; i < tcnt; i += 256)
    atomicAdd(&cntL[ei[EE + tile0 + i] >> BSH], 1);
  __syncthreads();
  int v = cntL[tid];
  segO[tid] = v;
  __syncthreads();
  for (int d = 1; d < 256; d <<= 1) {
    int t = (tid >= d) ? segO[tid - d] : 0;
    __syncthreads();
    segO[tid] += t;
    __syncthreads();
  }
  int excl = segO[tid] - v;
  __syncthreads();
  segO[tid] = excl;
  __syncthreads();
  for (int i = tid; i < tcnt; i += 256) {
    int s = ei[tile0 + i], dd = ei[EE + tile0 + i];
    int b = dd >> BSH;
    int slot = segO[b] + atomicAdd(&curL[b], 1);
    stag[slot] = (unsigned)s | ((unsigned)(dd & (BSZ - 1)) << 17);
    bktL[slot] = (unsigned char)b;
  }
  baseL[tid] = v ? atomicAdd(&gcur[tid], v) : 0;
  __syncthreads();
  for (int i = tid; i < tcnt; i += 256) {
    int b = bktL[i];
    pairs[baseL[b] + (i - segO[b])] = stag[i];
  }
}

// per-bucket count + scan + fill + degree-histogram (fused)
__global__ __launch_bounds__(256) void k_bbuild(const unsigned* __restrict__ pairs,
                                                const int* __restrict__ bexclB,
                                                int* __restrict__ cnt, int* __restrict__ csr_off,
                                                float* __restrict__ dis, int* __restrict__ csr_src,
                                                int* __restrict__ hist) {
  __shared__ int c[BSZ];
  __shared__ int ps[256];
  __shared__ int curB[BSZ];
  __shared__ int lhist[NBIN];
  int tid = threadIdx.x;
  int b = blockIdx.x;
  int lo = b << BSH;
  for (int j = tid; j < BSZ; j += 256) c[j] = 0;
  if (tid < NBIN) lhist[tid] = 0;
  __syncthreads();
  int s0e = bexclB[b], s1e = bexclB[b + 1];
  for (int i = s0e + tid; i < s1e; i += 256)
    atomicAdd(&c[pairs[i] >> 17], 1);
  __syncthreads();
  int a0 = c[2 * tid], a1 = c[2 * tid + 1];
  int pv = a0 + a1;
  ps[tid] = pv;
  __syncthreads();
  for (int d = 1; d < 256; d <<= 1) {
    int t = (tid >= d) ? ps[tid - d] : 0;
    __syncthreads();
    ps[tid] += t;
    __syncthreads();
  }
  int pex = ps[tid] - pv;
  int base = s0e + pex;
  int n0 = lo + 2 * tid, n1 = n0 + 1;
  if (n0 < NN) {
    csr_off[n0] = base; cnt[n0] = a0;
    dis[n0] = (a0 > 0) ? rsqrtf((float)a0) : 0.0f;
    atomicAdd(&lhist[min(a0, NBIN - 1)], 1);
  }
  if (n1 < NN) {
    csr_off[n1] = base + a0; cnt[n1] = a1;
    dis[n1] = (a1 > 0) ? rsqrtf((float)a1) : 0.0f;
    atomicAdd(&lhist[min(a1, NBIN - 1)], 1);
  }
  curB[2 * tid] = base;
  curB[2 * tid + 1] = base + a0;
  __syncthreads();
  for (int i = s0e + tid; i < s1e; i += 256) {
    unsigned pk = pairs[i];
    int p = atomicAdd(&curB[pk >> 17], 1);
    csr_src[p] = (int)(pk & 0x1FFFFu);
  }
  __syncthreads();
  if (tid < NBIN) {
    int v = lhist[tid];
    if (v) atomicAdd(&hist[tid], v);
  }
}

__global__ void k_binscan(const int* __restrict__ hist, int* __restrict__ bincur) {
  int tid = threadIdx.x;
  int v = hist[tid];
  int incl = v;
  for (int d = 1; d < 64; d <<= 1) {
    int t = __shfl_up(incl, d, 64);
    if (tid >= d) incl += t;
  }
  bincur[tid] = incl - v;
}
__global__ __launch_bounds__(256) void k_scatter(const int* __restrict__ cnt,
                                                 int* __restrict__ bincur,
                                                 int* __restrict__ perm) {
  __shared__ int lh[NBIN];
  __shared__ int lbase[NBIN];
  if (threadIdx.x < NBIN) lh[threadIdx.x] = 0;
  __syncthreads();
  int i = blockIdx.x * 256 + threadIdx.x;
  int b = 0, r = 0;
  bool valid = i < NN;
  if (valid) {
    b = min(cnt[i], NBIN - 1);
    r = atomicAdd(&lh[b], 1);
  }
  __syncthreads();
  if (threadIdx.x < NBIN) {
    int v = lh[threadIdx.x];
    lbase[threadIdx.x] = v ? atomicAdd(&bincur[threadIdx.x], v) : 0;
  }
  __syncthreads();
  if (valid) perm[lbase[b] + r] = i;
}

// ================= device bodies =================
__device__ void gmean12h_body(int bid, const __half* x12h, const int* perm,
                              const int* off, const int* srcarr, __half* A32) {
  int g = bid * 64 + (threadIdx.x >> 2);
  int t = threadIdx.x & 3;
  if (g >= NN || t >= 3) return;
  int node = perm[g];
  int s = off[node], e = off[node + 1];
  const uint2* h2 = (const uint2*)x12h;
  float4 acc = {0, 0, 0, 0};
  int p = s;
  for (; p + 4 <= e; p += 4) {
    int s0 = srcarr[p], s1 = srcarr[p + 1], s2 = srcarr[p + 2], s3 = srcarr[p + 3];
    acc = f4add(acc, f4add(f4add(h4f(h2[(long)s0 * 3 + t]), h4f(h2[(long)s1 * 3 + t])),
                           f4add(h4f(h2[(long)s2 * 3 + t]), h4f(h2[(long)s3 * 3 + t]))));
  }
  for (; p < e; ++p) acc = f4add(acc, h4f(h2[(long)srcarr[p] * 3 + t]));
  int c = e - s;
  float inv = 1.0f / (float)(c > 0 ? c : 1);
  acc.x *= inv; acc.y *= inv; acc.z *= inv; acc.w *= inv;
  ((uint2*)A32)[(long)node * 8 + t] = pack4h(acc);
}

__device__ void tagp8_top_body(int bid, const float* x, const float* t1aw, const float* t1bw,
                               const float* dis, __half* PTop) {
  int i = bid * 256 + threadIdx.x;
  if (i >= NN) return;
  float a[11];
  #pragma unroll
  for (int j = 0; j < 11; ++j) a[j] = x[(long)i * 11 + j];
  float dn = dis[i];
  {
    float s[8];
    #pragma unroll
    for (int o = 0; o < 8; ++o) {
      float acc = 0.0f;
      #pragma unroll
      for (int j = 0; j < 11; ++j) acc += a[j] * t1aw[o * 44 + 3 * 11 + j];
      s[o] = acc;
    }
    uint2 lo = pack4h(make_float4(s[0] * dn, s[1] * dn, s[2] * dn, s[3] * dn));
    uint2 hi = pack4h(make_float4(s[4] * dn, s[5] * dn, s[6] * dn, s[7] * dn));
    uint4 o4; o4.x = lo.x; o4.y = lo.y; o4.z = hi.x; o4.w = hi.y;
    ((uint4*)PTop)[(long)i * 2] = o4;
  }
  {
    float s[8];
    #pragma unroll
    for (int o = 0; o < 8; ++o) {
      float acc = 0.0f;
      #pragma unroll
      for (int j = 0; j < 11; ++j) acc += a[j] * t1bw[o * 77 + 6 * 11 + j];
      s[o] = acc;
    }
    uint2 lo = pack4h(make_float4(s[0] * dn, s[1] * dn, s[2] * dn, s[3] * dn));
    uint2 hi = pack4h(make_float4(s[4] * dn, s[5] * dn, s[6] * dn, s[7] * dn));
    uint4 o4; o4.x = lo.x; o4.y = lo.y; o4.z = hi.x; o4.w = hi.y;
    ((uint4*)PTop)[(long)i * 2 + 1] = o4;
  }
}

__device__ void d8_dual_body(int bid, const __half* src, const float* addA,
                             const float* addB, __half* dst,
                             const int* perm, const int* off,
                             const int* srcarr, const float* dis) {
  const uint4* src4 = (const uint4*)src;
  int t = threadIdx.x & 1;
  const float4* addp = (const float4*)(t == 0 ? addA : addB);
  int g = bid * 128 + (threadIdx.x >> 1);
  if (g >= NN) return;
  int node = perm[g];
  int s = off[node], e = off[node + 1];
  float acc[8] = {};
  int p = s;
  for (; p + 4 <= e; p += 4) {
    int s0 = srcarr[p], s1 = srcarr[p + 1], s2 = srcarr[p + 2], s3 = srcarr[p + 3];
    h8acc(src4[(long)s0 * 2 + t], acc); h8acc(src4[(long)s1 * 2 + t], acc);
    h8acc(src4[(long)s2 * 2 + t], acc); h8acc(src4[(long)s3 * 2 + t], acc);
  }
  for (; p < e; ++p) h8acc(src4[(long)srcarr[p] * 2 + t], acc);
  float dn = dis[node];
  float4 a0 = addp[(long)node * 2], a1 = addp[(long)node * 2 + 1];
  float4 r0 = make_float4((acc[0] * dn + a0.x) * dn, (acc[1] * dn + a0.y) * dn,
                          (acc[2] * dn + a0.z) * dn, (acc[3] * dn + a0.w) * dn);
  float4 r1 = make_float4((acc[4] * dn + a1.x) * dn, (acc[5] * dn + a1.y) * dn,
                          (acc[6] * dn + a1.z) * dn, (acc[7] * dn + a1.w) * dn);
  uint2 lo = pack4h(r0), hi = pack4h(r1);
  uint4 o; o.x = lo.x; o.y = lo.y; o.z = hi.x; o.w = hi.y;
  ((uint4*)dst)[(long)node * 2 + t] = o;
}

__device__ void d8_l3_body(int bid, const __half* src, const float* Pa0,
                           const float* t1ab, const float* t2aw,
                           const float* Pb3, __half* dstB, float* P2,
                           const int* perm, const int* off,
                           const int* srcarr, const float* dis) {
  const uint4* src4 = (const uint4*)src;
  int t = threadIdx.x & 1;
  int g = bid * 128 + (threadIdx.x >> 1);
  if (g >= NN) return;
  int node = perm[g];
  int s = off[node], e = off[node + 1];
  float acc[8] = {};
  int p = s;
  for (; p + 4 <= e; p += 4) {
    int s0 = srcarr[p], s1 = srcarr[p + 1], s2 = srcarr[p + 2], s3 = srcarr[p + 3];
    h8acc(src4[(long)s0 * 2 + t], acc); h8acc(src4[(long)s1 * 2 + t], acc);
    h8acc(src4[(long)s2 * 2 + t], acc); h8acc(src4[(long)s3 * 2 + t], acc);
  }
  for (; p < e; ++p) h8acc(src4[(long)srcarr[p] * 2 + t], acc);
  float dn = dis[node];
  if (t == 0) {
    const float4* addp = (const float4*)Pa0;
    float4 a0 = addp[(long)node * 2], a1 = addp[(long)node * 2 + 1];
    float4 b0 = ((const float4*)t1ab)[0], b1 = ((const float4*)t1ab)[1];
    float a[8];
    a[0] = sigm(acc[0] * dn + a0.x + b0.x); a[1] = sigm(acc[1] * dn + a0.y + b0.y);
    a[2] = sigm(acc[2] * dn + a0.z + b0.z); a[3] = sigm(acc[3] * dn + a0.w + b0.w);
    a[4] = sigm(acc[4] * dn + a1.x + b1.x); a[5] = sigm(acc[5] * dn + a1.y + b1.y);
    a[6] = sigm(acc[6] * dn + a1.z + b1.z); a[7] = sigm(acc[7] * dn + a1.w + b1.w);
    #pragma unroll
    for (int k = 0; k < 4; ++k) {
      float sv = 0.0f;
      #pragma unroll
      for (int j = 0; j < 8; ++j) sv += a[j] * t2aw[k * 8 + j];
      if (k == 3) sv *= dn;
      P2[(size_t)k * NN + node] = sv;
    }
  } else {
    const float4* addp = (const float4*)Pb3;
    float4 a0 = addp[(long)node * 2], a1 = addp[(long)node * 2 + 1];
    float4 r0 = make_float4((acc[0] * dn + a0.x) * dn, (acc[1] * dn + a0.y) * dn,
                            (acc[2] * dn + a0.z) * dn, (acc[3] * dn + a0.w) * dn);
    float4 r1 = make_float4((acc[4] * dn + a1.x) * dn, (acc[5] * dn + a1.y) * dn,
                            (acc[6] * dn + a1.z) * dn, (acc[7] * dn + a1.w) * dn);
    uint2 lo = pack4h(r0), hi = pack4h(r1);
    uint4 o; o.x = lo.x; o.y = lo.y; o.z = hi.x; o.w = hi.y;
    ((uint4*)dstB)[(long)node * 2 + 1] = o;
  }
}

__device__ void d8_single_body(int bid, const __half* src, const float* addB, __half* dst,
                               const int* perm, const int* off,
                               const int* srcarr, const float* dis) {
  const uint2* src2 = (const uint2*)src;
  int t = threadIdx.x & 1;
  int g = bid * 128 + (threadIdx.x >> 1);
  if (g >= NN) return;
  int node = perm[g];
  int s = off[node], e = off[node + 1];
  float4 acc = {0, 0, 0, 0};
  int p = s;
  for (; p + 4 <= e; p += 4) {
    int s0 = srcarr[p], s1 = srcarr[p + 1], s2 = srcarr[p + 2], s3 = srcarr[p + 3];
    acc = f4add(acc, f4add(f4add(h4f(src2[(long)s0 * 4 + 2 + t]), h4f(src2[(long)s1 * 4 + 2 + t])),
                           f4add(h4f(src2[(long)s2 * 4 + 2 + t]), h4f(src2[(long)s3 * 4 + 2 + t]))));
  }
  for (; p < e; ++p) acc = f4add(acc, h4f(src2[(long)srcarr[p] * 4 + 2 + t]));
  float dn = dis[node];
  float4 av = ((const float4*)addB)[(long)node * 2 + t];
  float4 r = make_float4((acc.x * dn + av.x) * dn, (acc.y * dn + av.y) * dn,
                         (acc.z * dn + av.z) * dn, (acc.w * dn + av.w) * dn);
  ((uint2*)dst)[(long)node * 4 + 2 + t] = pack4h(r);
}

__device__ void d8_l6_body(int bid, const __half* src, const float* Pb0,
                           const float* t1bb, const float* t2bw, float* P2b,
                           const int* perm, const int* off,
                           const int* srcarr, const float* dis) {
  const uint2* src2 = (const uint2*)src;
  int t = threadIdx.x & 1;
  int g = bid * 128 + (threadIdx.x >> 1);
  if (g >= NN) return;
  int node = perm[g];
  int s = off[node], e = off[node + 1];
  float4 acc = {0, 0, 0, 0};
  int p = s;
  for (; p + 4 <= e; p += 4) {
    int s0 = srcarr[p], s1 = srcarr[p + 1], s2 = srcarr[p + 2], s3 = srcarr[p + 3];
    acc = f4add(acc, f4add(f4add(h4f(src2[(long)s0 * 4 + 2 + t]), h4f(src2[(long)s1 * 4 + 2 + t])),
                           f4add(h4f(src2[(long)s2 * 4 + 2 + t]), h4f(src2[(long)s3 * 4 + 2 + t]))));
  }
  for (; p < e; ++p) acc = f4add(acc, h4f(src2[(long)srcarr[p] * 4 + 2 + t]));
  float dn = dis[node];
  float4 av = ((const float4*)Pb0)[(long)node * 2 + t];
  float4 bv = ((const float4*)t1bb)[t];
  float4 r = make_float4(sigm(acc.x * dn + av.x + bv.x), sigm(acc.y * dn + av.y + bv.y),
                         sigm(acc.z * dn + av.z + bv.z), sigm(acc.w * dn + av.w + bv.w));
  float o0 = __shfl_xor(r.x, 1, 64), o1 = __shfl_xor(r.y, 1, 64);
  float o2 = __shfl_xor(r.z, 1, 64), o3 = __shfl_xor(r.w, 1, 64);
  if (t == 0) {
    float a[8] = {r.x, r.y, r.z, r.w, o0, o1, o2, o3};
    #pragma unroll
    for (int k = 0; k < 7; ++k) {
      float sv = 0.0f;
      #pragma unroll
      for (int j = 0; j < 8; ++j) sv += a[j] * t2bw[k * 8 + j];
      if (k == 6) sv *= dn;
      P2b[(size_t)k * NN + node] = sv;
    }
  }
}

__device__ void d1_body(int bid, const float* ua, const float* adda, const float* bias,
                        int act, float* outa, const int* perm, const int* off,
                        const int* srcarr, const float* dis) {
  int g = bid * 64 + (threadIdx.x >> 2);
  int t = threadIdx.x & 3;
  if (g >= NN) return;
  int node = perm[g];
  int s = off[node], e = off[node + 1];
  float accA = 0.0f;
  for (int p = s + t; p < e; p += 4) accA += ua[srcarr[p]];
  accA += __shfl_xor(accA, 1, 64); accA += __shfl_xor(accA, 2, 64);
  if (t == 0) {
    float sc = dis[node];
    float rA = accA * sc + adda[node];
    if (bias) rA += bias[0];
    if (act == 3) rA *= sc; else if (act == 2) rA = fmaxf(rA, 0.0f);
    outa[node] = rA;
  }
}

__device__ void x1s_body(int bid, const float* pp, const float* qq, const float* s3b,
                         const int* perm, const int* off, const int* srcarr,
                         float* x1s) {
  int g = bid * 64 + (threadIdx.x >> 2);
  int t = threadIdx.x & 3;
  if (g >= NN) return;
  int node = perm[g];
  int s = off[node], e = off[node + 1];
  float acc = 0.0f;
  for (int p = s + t; p < e; p += 4) acc += pp[srcarr[p]];
  acc += __shfl_xor(acc, 1, 64); acc += __shfl_xor(acc, 2, 64);
  if (t == 0) {
    int c = e - s;
    float sc = 1.0f / (float)(c > 0 ? c : 1);
    x1s[node] = fmaxf(acc * sc + qq[node] + s3b[0], 0.0f);
  }
}

__device__ void gather128_body(int bid, const __half* h, const int* perm,
                               const int* off, const int* srcarr, __half* outh) {
  int g = bid * 16 + (threadIdx.x >> 4);
  int t = threadIdx.x & 15;
  if (g >= NN) return;
  int node = perm[g];
  int s = off[node], e = off[node + 1];
  const uint4* h4 = (const uint4*)h;
  float acc[8] = {};
  int p = s;
  for (; p + 4 <= e; p += 4) {
    int s0 = srcarr[p], s1 = srcarr[p + 1], s2 = srcarr[p + 2], s3 = srcarr[p + 3];
    uint4 r0 = h4[(long)s0 * 16 + t], r1 = h4[(long)s1 * 16 + t];
    uint4 r2 = h4[(long)s2 * 16 + t], r3 = h4[(long)s3 * 16 + t];
    h8acc(r0, acc); h8acc(r1, acc); h8acc(r2, acc); h8acc(r3, acc);
  }
  for (; p < e; ++p) h8acc(h4[(long)srcarr[p] * 16 + t], acc);
  int c = e - s;
  float inv = 1.0f / (float)(c > 0 ? c : 1);
  uint2 lo = pack4h(make_float4(acc[0] * inv, acc[1] * inv, acc[2] * inv, acc[3] * inv));
  uint2 hi = pack4h(make_float4(acc[4] * inv, acc[5] * inv, acc[6] * inv, acc[7] * inv));
  uint4 o; o.x = lo.x; o.y = lo.y; o.z = hi.x; o.w = hi.y;
  ((uint4*)outh)[(long)node * 16 + t] = o;
}

__device__ void mm1_body(int bid, const __half* A32, const __half* W32,
                         const float* bias, __half* out, __half (*lt)[32][136]) {
  int tid = threadIdx.x;
  int wave = tid >> 6, l = tid & 63;
  int lr = l & 15, lk = l >> 4;
  int m0 = bid * 128 + wave * 32;
  f4v acc[2][8] = {};
  h8v afrag[2];
  #pragma unroll
  for (int rt = 0; rt < 2; ++rt) {
    int row = m0 + rt * 16 + lr;
    h8v z = {};
    afrag[rt] = (row < NN) ? *(const h8v*)&A32[(long)row * 32 + lk * 8] : z;
  }
  #pragma unroll
  for (int c = 0; c < 8; ++c) {
    h8v bfrag = *(const h8v*)&W32[(c * 16 + lr) * 32 + lk * 8];
    acc[0][c] = __builtin_amdgcn_mfma_f32_16x16x32_f16(afrag[0], bfrag, acc[0][c], 0, 0, 0);
    acc[1][c] = __builtin_amdgcn_mfma_f32_16x16x32_f16(afrag[1], bfrag, acc[1][c], 0, 0, 0);
  }
  float bi[8];
  #pragma unroll
  for (int c = 0; c < 8; ++c) bi[c] = bias[c * 16 + lr];
  #pragma unroll
  for (int rt = 0; rt < 2; ++rt)
    #pragma unroll
    for (int c = 0; c < 8; ++c)
      #pragma unroll
      for (int reg = 0; reg < 4; ++reg) {
        float v = acc[rt][c][reg] + bi[c];
        lt[wave][rt * 16 + lk * 4 + reg][c * 16 + lr] = __float2half(sigm(v));
      }
  __syncthreads();
  #pragma unroll
  for (int it = 0; it < 8; ++it) {
    int idx = it * 64 + l;
    int row = idx >> 4, c16 = idx & 15;
    int grow = m0 + row;
    if (grow < NN) {
      uint4 v = *(const uint4*)&lt[wave][row][c16 * 8];
      ((uint4*)out)[(long)grow * 16 + c16] = v;
    }
  }
}

__device__ void mm2_body(int bid, const __half* A1, const __half* A2,
                         const __half* W, const float* bias,
                         const float* w3l, const float* w3r,
                         float* pp, float* qq) {
  int tid = threadIdx.x;
  int wave = tid >> 6;
  int l = tid & 63;
  int lr = l & 15;
  int lk = l >> 4;
  int m0 = bid * 128 + wave * 32;
  f4v acc[2][8] = {};
  #pragma unroll
  for (int ks = 0; ks < 8; ++ks) {
    const __half* Asrc = (ks < 4) ? A1 : A2;
    int kk = (ks & 3) * 32 + lk * 8;
    h8v afrag[2];
    #pragma unroll
    for (int rt = 0; rt < 2; ++rt) {
      int row = m0 + rt * 16 + lr;
      h8v z = {};
      afrag[rt] = (row < NN) ? *(const h8v*)&Asrc[(long)row * 128 + kk] : z;
    }
    #pragma unroll
    for (int c = 0; c < 8; ++c) {
      h8v bfrag = *(const h8v*)&W[(long)(c * 16 + lr) * 256 + ks * 32 + lk * 8];
      acc[0][c] = __builtin_amdgcn_mfma_f32_16x16x32_f16(afrag[0], bfrag, acc[0][c], 0, 0, 0);
      acc[1][c] = __builtin_amdgcn_mfma_f32_16x16x32_f16(afrag[1], bfrag, acc[1][c], 0, 0, 0);
    }
  }
  float wl[8], wr[8], bi[8];
  #pragma unroll
  for (int c = 0; c < 8; ++c) {
    wl[c] = w3l[c * 16 + lr];
    wr[c] = w3r[c * 16 + lr];
    bi[c] = bias[c * 16 + lr];
  }
  #pragma unroll
  for (int rt = 0; rt < 2; ++rt) {
    #pragma unroll
    for (int reg = 0; reg < 4; ++reg) {
      float s1 = 0.0f, s2 = 0.0f;
      #pragma unroll
      for (int c = 0; c < 8; ++c) {
        float v = acc[rt][c][reg] + bi[c];
        float sg = sigm(v);
        s1 += sg * wl[c];
        s2 += sg * wr[c];
      }
      #pragma unroll
      for (int d = 1; d < 16; d <<= 1) {
        s1 += __shfl_xor(s1, d, 64);
        s2 += __shfl_xor(s2, d, 64);
      }
      int row = m0 + rt * 16 + lk * 4 + reg;
      if (lr == 0 && row < NN) { pp[row] = s1; qq[row] = s2; }
    }
  }
}

// ================= fused dispatches =================
__global__ __launch_bounds__(256) void k_fuseA(
    const __half* x12h, const int* perm, const int* off, const int* srcarr, __half* A32,
    const float* x, const float* t1aw, const float* t1bw, const float* dis, __half* PTop) {
  if (blockIdx.x < GA) gmean12h_body(blockIdx.x, x12h, perm, off, srcarr, A32);
  else tagp8_top_body(blockIdx.x - GA, x, t1aw, t1bw, dis, PTop);
}

__global__ __launch_bounds__(256) void k_fuseB(
    const __half* A32, const __half* W32, const float* s1b, __half* x1a,
    const __half* PTop, const float* Pa2, const float* Pb5, __half* zbuf0,
    const int* perm, const int* off, const int* srcarr, const float* dis) {
  __shared__ __half lt[4][32][136];
  if (blockIdx.x < GM) mm1_body(blockIdx.x, A32, W32, s1b, x1a, lt);
  else d8_dual_body(blockIdx.x - GM, PTop, Pa2, Pb5, zbuf0, perm, off, srcarr, dis);
}

__global__ __launch_bounds__(256) void k_fuseC(
    const __half* x1a, __half* mean128,
    const __half* zbuf0, const float* Pa1, const float* Pb4, __half* zbuf1,
    const int* perm, const int* off, const int* srcarr, const float* dis) {
  if (blockIdx.x < GG) gather128_body(blockIdx.x, x1a, perm, off, srcarr, mean128);
  else d8_dual_body(blockIdx.x - GG, zbuf0, Pa1, Pb4, zbuf1, perm, off, srcarr, dis);
}

__global__ __launch_bounds__(256) void k_fuseD(
    const __half* mean128, const __half* x1a, const __half* w2h, const float* s2b,
    const float* w3l, const float* w3r, float* pp, float* qq,
    const __half* zbuf1, const float* Pa0, const float* t1ab, const float* t2aw,
    const float* Pb3, __half* zbuf0, float* P2,
    const int* perm, const int* off, const int* srcarr, const float* dis) {
  if (blockIdx.x < GM) mm2_body(blockIdx.x, mean128, x1a, w2h, s2b, w3l, w3r, pp, qq);
  else d8_l3_body(blockIdx.x - GM, zbuf1, Pa0, t1ab, t2aw, Pb3, zbuf0, P2,
                  perm, off, srcarr, dis);
}

__global__ __launch_bounds__(256) void k_fuseE(
    const __half* zbuf0, const float* Pb2, __half* zbuf1,
    const float* pp, const float* qq, const float* s3b, float* x1s,
    const float* P2, float* uA1,
    const int* perm, const int* off, const int* srcarr, const float* dis) {
  if (blockIdx.x < GM)
    d8_single_body(blockIdx.x, zbuf0, Pb2, zbuf1, perm, off, srcarr, dis);
  else if (blockIdx.x < GM + G1)
    x1s_body(blockIdx.x - GM, pp, qq, s3b, perm, off, srcarr, x1s);
  else
    d1_body(blockIdx.x - GM - G1, P2 + 3 * (size_t)NN, P2 + 2 * (size_t)NN,
            nullptr, 3, uA1, perm, off, srcarr, dis);
}

__global__ __launch_bounds__(256) void k_fuseF(
    const __half* zbuf1, const float* Pb1, __half* zbuf0,
    const float* uA1, const float* P2, float* uA2,
    const int* perm, const int* off, const int* srcarr, const float* dis) {
  if (blockIdx.x < GM)
    d8_single_body(blockIdx.x, zbuf1, Pb1, zbuf0, perm, off, srcarr, dis);
  else
    d1_body(blockIdx.x - GM, uA1, P2 + 1 * (size_t)NN, nullptr, 3, uA2,
            perm, off, srcarr, dis);
}

__global__ __launch_bounds__(256) void k_fuseG(
    const __half* zbuf0, const float* Pb0, const float* t1bb, const float* t2bw,
    float* P2b, const float* uA2, const float* P2, const float* t2ab, float* x2s,
    const int* perm, const int* off, const int* srcarr, const float* dis) {
  if (blockIdx.x < GM)
    d8_l6_body(blockIdx.x, zbuf0, Pb0, t1bb, t2bw, P2b, perm, off, srcarr, dis);
  else
    d1_body(blockIdx.x - GM, uA2, P2, t2ab, 2, x2s, perm, off, srcarr, dis);
}

__global__ __launch_bounds__(256) void k_d1b(
    const float* ua, const float* adda, float* outa,
    const int* perm, const int* off, const int* srcarr, const float* dis) {
  d1_body(blockIdx.x, ua, adda, nullptr, 3, outa, perm, off, srcarr, dis);
}

__global__ __launch_bounds__(256) void k_g1_final(
    const float* ua, const float* adda, const float* biasa,
    const float* x1s, const float* x2s,
    const float* lw, const float* lb,
    const int* perm, const int* off, const int* srcarr, const float* dis,
    float* out) {
  int g = blockIdx.x * 64 + (threadIdx.x >> 2);
  int t = threadIdx.x & 3;
  if (g >= NN) return;
  int node = perm[g];
  int s = off[node], e = off[node + 1];
  float accA = 0.0f;
  for (int p = s + t; p < e; p += 4) accA += ua[srcarr[p]];
  accA += __shfl_xor(accA, 1, 64); accA += __shfl_xor(accA, 2, 64);
  if (t == 0) {
    float x3v = fmaxf(accA * dis[node] + adda[node] + biasa[0], 0.0f);
    float v = x1s[node] * lw[0] + x2s[node] * lw[1] + x3v * lw[2] + lb[0];
    out[node] = fmaxf(v, 0.0f);
  }
}

extern "C" void kernel_launch(void* const* d_in, const int* in_sizes, int n_in,
                              void* d_out, int out_size, void* d_ws, size_t ws_size,
                              hipStream_t stream) {
  const float* x    = (const float*)d_in[0];
  const int*   ei   = (const int*)d_in[1];
  const float* s1wl = (const float*)d_in[2];
  const float* s1wr = (const float*)d_in[3];
  const float* s1b  = (const float*)d_in[4];
  const float* s2wl = (const float*)d_in[5];
  const float* s2wr = (const float*)d_in[6];
  const float* s2b  = (const float*)d_in[7];
  const float* s3wl = (const float*)d_in[8];
  const float* s3wr = (const float*)d_in[9];
  const float* s3b  = (const float*)d_in[10];
  const float* t1aw = (const float*)d_in[11];
  const float* t1ab = (const float*)d_in[12];
  const float* t2aw = (const float*)d_in[13];
  const float* t2ab = (const float*)d_in[14];
  const float* t1bw = (const float*)d_in[15];
  const float* t1bb = (const float*)d_in[16];
  const float* t2bw = (const float*)d_in[17];
  const float* t2bb = (const float*)d_in[18];
  const float* lw   = (const float*)d_in[19];
  const float* lb   = (const float*)d_in[20];
  float* out = (float*)d_out;

  char* basep = (char*)d_ws;
  size_t off = 0;
  auto alloc = [&](size_t bytes) -> void* {
    void* ptr = basep + off;
    off = (off + bytes + 255) & ~(size_t)255;
    return ptr;
  };
  int*      cnt     = (int*)alloc((size_t)NN * 4);
  int*      csr_off = (int*)alloc((size_t)(NN + 1) * 4);
  float*    dis     = (float*)alloc((size_t)NN * 4);
  int*      csr_src = (int*)alloc((size_t)EE * 4);
  unsigned* pairs   = (unsigned*)alloc((size_t)EE * 4);
  int*      perm    = (int*)alloc((size_t)NN * 4);
  int*      ghist   = (int*)alloc(256 * 4);
  int*      gcur    = (int*)alloc(256 * 4);
  int*      bexclB  = (int*)alloc(256 * 4);
  int*      hist    = (int*)alloc(NBIN * 4);
  int*      bincur  = (int*)alloc(NBIN * 4);
  float*    x1s     = (float*)alloc((size_t)NN * 4);
  float*    x2s     = (float*)alloc((size_t)NN * 4);
  float*    pp      = (float*)alloc((size_t)NN * 4);
  float*    qq      = (float*)alloc((size_t)NN * 4);
  float*    uA1     = (float*)alloc((size_t)NN * 4);
  float*    uA2     = (float*)alloc((size_t)NN * 4);
  float*    uB1     = (float*)alloc((size_t)NN * 4);
  float*    uB2     = (float*)alloc((size_t)NN * 4);
  __half*   x12h    = (__half*)alloc((size_t)NN * 12 * 2);
  __half*   A32     = (__half*)alloc((size_t)NN * 32 * 2);
  __half*   w1h     = (__half*)alloc((size_t)128 * 32 * 2);
  __half*   w2h     = (__half*)alloc((size_t)128 * 256 * 2);
  __half*   x1a_h   = (__half*)alloc((size_t)NN * 128 * 2);
  __half*   mean128_h = (__half*)alloc((size_t)NN * 128 * 2);
  float*    Pa    = (float*)alloc((size_t)NN * 24 * 4);   // [3][N][8]
  float*    Pb    = (float*)alloc((size_t)NN * 48 * 4);   // [6][N][8]
  __half*   PTop  = (__half*)alloc((size_t)NN * 16 * 2);  // [N][16] interleaved
  __half*   zbuf0 = (__half*)alloc((size_t)NN * 16 * 2);
  __half*   zbuf1 = (__half*)alloc((size_t)NN * 16 * 2);
  float*    P2    = (float*)alloc((size_t)NN * 4 * 4);    // [4][N]
  float*    P2b   = (float*)alloc((size_t)NN * 7 * 4);    // [7][N]

  const size_t S8 = (size_t)NN * 8;
  const size_t S1 = (size_t)NN;

  // ---- CSR build + prep ----
  hipMemsetAsync(ghist, 0, 3840, stream);
  k_bhist_prep<<<BH_B + PREP_B0 + PREP_B1 + 16 + 128, 256, 0, stream>>>(
      ei, ghist, x, s1wl, s1wr, s2wl, s2wr, x12h, A32, w1h, w2h);
  k_b196scan<<<1, 256, 0, stream>>>(ghist, gcur, bexclB, csr_off);
  k_split_tag<<<SPB + TGA, 256, 0, stream>>>(ei, gcur, pairs, x, t1aw, t1bw, Pa, Pb);
  k_bbuild<<<NBK, 256, 0, stream>>>(pairs, bexclB, cnt, csr_off, dis, csr_src, hist);
  k_binscan<<<1, 64, 0, stream>>>(hist, bincur);
  k_scatter<<<(NN + 255) / 256, 256, 0, stream>>>(cnt, bincur, perm);

  // ---- co-scheduled SAGE + TAG ----
  k_fuseA<<<GA + GT, 256, 0, stream>>>(
      x12h, perm, csr_off, csr_src, A32, x, t1aw, t1bw, dis, PTop);
  k_fuseB<<<GM + GM, 256, 0, stream>>>(
      A32, w1h, s1b, x1a_h, PTop, Pa + 2 * S8, Pb + 5 * S8, zbuf0,
      perm, csr_off, csr_src, dis);
  k_fuseC<<<GG + GM, 256, 0, stream>>>(
      x1a_h, mean128_h, zbuf0, Pa + 1 * S8, Pb + 4 * S8, zbuf1,
      perm, csr_off, csr_src, dis);
  k_fuseD<<<GM + GM, 256, 0, stream>>>(
      mean128_h, x1a_h, w2h, s2b, s3wl, s3wr, pp, qq,
      zbuf1, Pa, t1ab, t2aw, Pb + 3 * S8, zbuf0, P2,
      perm, csr_off, csr_src, dis);
  k_fuseE<<<GM + G1 + G1, 256, 0, stream>>>(
      zbuf0, Pb + 2 * S8, zbuf1, pp, qq, s3b, x1s, P2, uA1,
      perm, csr_off, csr_src, dis);
  k_fuseF<<<GM + G1, 256, 0, stream>>>(
      zbuf1, Pb + 1 * S8, zbuf0, uA1, P2, uA2,
      perm, csr_off, csr_src, dis);
  k_fuseG<<<GM + G1, 256, 0, stream>>>(
      zbuf0, Pb, t1bb, t2bw, P2b, uA2, P2, t2ab, x2s,
      perm, csr_off, csr_src, dis);

  // ---- d1b tail chain ----
  k_d1b<<<G1, 256, 0, stream>>>(P2b + 6 * S1, P2b + 5 * S1, uB1, perm, csr_off, csr_src, dis);
  k_d1b<<<G1, 256, 0, stream>>>(uB1, P2b + 4 * S1, uB2, perm, csr_off, csr_src, dis);
  k_d1b<<<G1, 256, 0, stream>>>(uB2, P2b + 3 * S1, uB1, perm, csr_off, csr_src, dis);
  k_d1b<<<G1, 256, 0, stream>>>(uB1, P2b + 2 * S1, uB2, perm, csr_off, csr_src, dis);
  k_d1b<<<G1, 256, 0, stream>>>(uB2, P2b + 1 * S1, uB1, perm, csr_off, csr_src, dis);
  k_g1_final<<<G1, 256, 0, stream>>>(
      uB1, P2b, t2bb, x1s, x2s, lw, lb, perm, csr_off, csr_src, dis, out);
}

// Round 12
// 464.325 us; speedup vs baseline: 3.1494x; 1.0116x over previous
//
#include <hip/hip_runtime.h>
#include <hip/hip_bf16.h>
#include <hip/hip_fp16.h>

#define NN 100000
#define EE 1600000
#define NBIN 64
#define BSH 9
#define BSZ 512
#define NBK 196   // ceil(NN/512)

// grid segment sizes
#define GA 1563   // gmean12h blocks (64 nodes/block)
#define GT 391    // tagP8-top blocks (256 nodes/block)
#define GM 782    // mm / d8 blocks (128 nodes/block)
#define GG 6250   // gather128 blocks (16 nodes/block)
#define G1 1563   // d1 blocks (64 nodes/block)
#define SPB 391   // split blocks (4096 edges/block)
#define TGA 391   // tagP8-adds blocks (256 nodes/block)

typedef _Float16 h8v __attribute__((ext_vector_type(8)));
typedef float f4v __attribute__((ext_vector_type(4)));

__device__ __forceinline__ float sigm(float v) { return 1.0f / (1.0f + expf(-v)); }
__device__ __forceinline__ float4 f4add(float4 a, float4 b) {
  a.x += b.x; a.y += b.y; a.z += b.z; a.w += b.w; return a;
}
__device__ __forceinline__ float4 h4f(uint2 v) {
  __half2 a = *reinterpret_cast<__half2*>(&v.x);
  __half2 b = *reinterpret_cast<__half2*>(&v.y);
  float2 fa = __half22float2(a), fb = __half22float2(b);
  return make_float4(fa.x, fa.y, fb.x, fb.y);
}
__device__ __forceinline__ void h8acc(uint4 v, float* a) {
  float4 lo = h4f(make_uint2(v.x, v.y));
  float4 hi = h4f(make_uint2(v.z, v.w));
  a[0] += lo.x; a[1] += lo.y; a[2] += lo.z; a[3] += lo.w;
  a[4] += hi.x; a[5] += hi.y; a[6] += hi.z; a[7] += hi.w;
}
__device__ __forceinline__ uint2 pack4h(float4 r) {
  __half2 q0 = __floats2half2_rn(r.x, r.y), q1 = __floats2half2_rn(r.z, r.w);
  uint2 o; o.x = *(unsigned*)&q0; o.y = *(unsigned*)&q1; return o;
}

// ================= CSR build + fused prep =================
#define BH_B 512
#define PREP_B0 ((NN * 12 + 255) / 256)
#define PREP_B1 ((NN + 255) / 256)
__global__ __launch_bounds__(256) void k_bhist_prep(
    const int* __restrict__ ei, int* __restrict__ ghist,
    const float* __restrict__ x, const float* __restrict__ s1wl, const float* __restrict__ s1wr,
    const float* __restrict__ s2wl, const float* __restrict__ s2wr,
    __half* __restrict__ x12h, __half* __restrict__ A32,
    __half* __restrict__ w1h, __half* __restrict__ w2h) {
  __shared__ int lh[NBK];
  int bid = blockIdx.x;
  if (bid < BH_B) {
    for (int j = threadIdx.x; j < NBK; j += 256) lh[j] = 0;
    __syncthreads();
    for (int i = bid * 256 + threadIdx.x; i < EE; i += BH_B * 256)
      atomicAdd(&lh[ei[EE + i] >> BSH], 1);
    __syncthreads();
    for (int j = threadIdx.x; j < NBK; j += 256) {
      int v = lh[j];
      if (v) atomicAdd(&ghist[j], v);
    }
    return;
  }
  int pid = bid - BH_B;
  if (pid < PREP_B0) {
    int i = pid * 256 + threadIdx.x;
    if (i < NN * 12) {
      int n = i / 12, j = i - n * 12;
      x12h[i] = __float2half((j < 11) ? x[n * 11 + j] : 0.0f);
    }
  } else if (pid < PREP_B0 + PREP_B1) {
    int i = (pid - PREP_B0) * 256 + threadIdx.x;
    if (i < NN) {
      float a[11];
      #pragma unroll
      for (int j = 0; j < 11; ++j) a[j] = x[(long)i * 11 + j];
      uint2* row = (uint2*)(A32 + (long)i * 32);
      row[3] = make_uint2(0u, 0u);
      row[4] = pack4h(make_float4(a[0], a[1], a[2], a[3]));
      row[5] = pack4h(make_float4(a[4], a[5], a[6], a[7]));
      row[6] = pack4h(make_float4(a[8], a[9], a[10], 0.0f));
      row[7] = make_uint2(0u, 0u);
    }
  } else if (pid < PREP_B0 + PREP_B1 + 16) {
    int i = (pid - PREP_B0 - PREP_B1) * 256 + threadIdx.x;
    int o = i >> 5, k = i & 31;
    float v = 0.0f;
    if (k < 11) v = s1wl[o * 11 + k];
    else if (k >= 16 && k < 27) v = s1wr[o * 11 + (k - 16)];
    w1h[i] = __float2half(v);
  } else {
    int i = (pid - PREP_B0 - PREP_B1 - 16) * 256 + threadIdx.x;
    int o = i >> 8, k = i & 255;
    float v = (k < 128) ? s2wl[o * 128 + k] : s2wr[o * 128 + (k - 128)];
    w2h[i] = __float2half(v);
  }
}

__global__ void k_b196scan(const int* __restrict__ ghist, int* __restrict__ gcur,
                           int* __restrict__ bexclB, int* __restrict__ csr_off) {
  __shared__ int sh[256];
  int tid = threadIdx.x;
  int v = (tid < NBK) ? ghist[tid] : 0;
  sh[tid] = v;
  __syncthreads();
  for (int d = 1; d < 256; d <<= 1) {
    int t = (tid >= d) ? sh[tid - d] : 0;
    __syncthreads();
    sh[tid] += t;
    __syncthreads();
  }
  int excl = sh[tid] - v;
  if (tid < NBK) { gcur[tid] = excl; bexclB[tid] = excl; }
  if (tid == 0) { bexclB[NBK] = EE; csr_off[NN] = EE; }
}

// unscaled TAG first-linear slices (fp16, one uint4 per node per slice)
__device__ void tagp8_adds_body(int bid, const float* x, const float* t1aw,
                                const float* t1bw, __half* PaH, __half* PbH) {
  int i = bid * 256 + threadIdx.x;
  if (i >= NN) return;
  float a[11];
  #pragma unroll
  for (int j = 0; j < 11; ++j) a[j] = x[(long)i * 11 + j];
  #pragma unroll
  for (int k = 0; k < 3; ++k) {
    float s[8];
    #pragma unroll
    for (int o = 0; o < 8; ++o) {
      float acc = 0.0f;
      #pragma unroll
      for (int j = 0; j < 11; ++j) acc += a[j] * t1aw[o * 44 + k * 11 + j];
      s[o] = acc;
    }
    uint2 lo = pack4h(make_float4(s[0], s[1], s[2], s[3]));
    uint2 hi = pack4h(make_float4(s[4], s[5], s[6], s[7]));
    uint4 o4; o4.x = lo.x; o4.y = lo.y; o4.z = hi.x; o4.w = hi.y;
    ((uint4*)PaH)[(size_t)k * NN + i] = o4;
  }
  #pragma unroll
  for (int k = 0; k < 6; ++k) {
    float s[8];
    #pragma unroll
    for (int o = 0; o < 8; ++o) {
      float acc = 0.0f;
      #pragma unroll
      for (int j = 0; j < 11; ++j) acc += a[j] * t1bw[o * 77 + k * 11 + j];
      s[o] = acc;
    }
    uint2 lo = pack4h(make_float4(s[0], s[1], s[2], s[3]));
    uint2 hi = pack4h(make_float4(s[4], s[5], s[6], s[7]));
    uint4 o4; o4.x = lo.x; o4.y = lo.y; o4.z = hi.x; o4.w = hi.y;
    ((uint4*)PbH)[(size_t)k * NN + i] = o4;
  }
}

// split + co-scheduled tagP8-adds
__global__ __launch_bounds__(256) void k_split_tag(
    const int* __restrict__ ei, int* __restrict__ gcur, unsigned* __restrict__ pairs,
    const float* __restrict__ x, const float* __restrict__ t1aw,
    const float* __restrict__ t1bw, __half* __restrict__ PaH, __half* __restrict__ PbH) {
  if (blockIdx.x >= SPB) {
    tagp8_adds_body(blockIdx.x - SPB, x, t1aw, t1bw, PaH, PbH);
    return;
  }
  __shared__ int cntL[256];
  __shared__ int segO[256];
  __shared__ int curL[256];
  __shared__ int baseL[256];
  __shared__ unsigned stag[4096];
  __shared__ unsigned char bktL[4096];
  int tid = threadIdx.x;
  int tile0 = blockIdx.x * 4096;
  int tcnt = min(4096, EE - tile0);
  cntL[tid] = 0; curL[tid] = 0;
  __syncthreads();
  for (int i = tid; i < tcnt; i += 256)
    atomicAdd(&cntL[ei[EE + tile0 + i] >> BSH], 1);
  __syncthreads();
  int v = cntL[tid];
  segO[tid] = v;
  __syncthreads();
  for (int d = 1; d < 256; d <<= 1) {
    int t = (tid >= d) ? segO[tid - d] : 0;
    __syncthreads();
    segO[tid] += t;
    __syncthreads();
  }
  int excl = segO[tid] - v;
  __syncthreads();
  segO[tid] = excl;
  __syncthreads();
  for (int i = tid; i < tcnt; i += 256) {
    int s = ei[tile0 + i], dd = ei[EE + tile0 + i];
    int b = dd >> BSH;
    int slot = segO[b] + atomicAdd(&curL[b], 1);
    stag[slot] = (unsigned)s | ((unsigned)(dd & (BSZ - 1)) << 17);
    bktL[slot] = (unsigned char)b;
  }
  baseL[tid] = v ? atomicAdd(&gcur[tid], v) : 0;
  __syncthreads();
  for (int i = tid; i < tcnt; i += 256) {
    int b = bktL[i];
    pairs[baseL[b] + (i - segO[b])] = stag[i];
  }
}

// per-bucket count + scan + fill + degree-histogram (fused)
__global__ __launch_bounds__(256) void k_bbuild(const unsigned* __restrict__ pairs,
                                                const int* __restrict__ bexclB,
                                                int* __restrict__ cnt, int* __restrict__ csr_off,
                                                float* __restrict__ dis, int* __restrict__ csr_src,
                                                int* __restrict__ hist) {
  __shared__ int c[BSZ];
  __shared__ int ps[256];
  __shared__ int curB[BSZ];
  __shared__ int lhist[NBIN];
  int tid = threadIdx.x;
  int b = blockIdx.x;
  int lo = b << BSH;
  for (int j = tid; j < BSZ; j += 256) c[j] = 0;
  if (tid < NBIN) lhist[tid] = 0;
  __syncthreads();
  int s0e = bexclB[b], s1e = bexclB[b + 1];
  for (int i = s0e + tid; i < s1e; i += 256)
    atomicAdd(&c[pairs[i] >> 17], 1);
  __syncthreads();
  int a0 = c[2 * tid], a1 = c[2 * tid + 1];
  int pv = a0 + a1;
  ps[tid] = pv;
  __syncthreads();
  for (int d = 1; d < 256; d <<= 1) {
    int t = (tid >= d) ? ps[tid - d] : 0;
    __syncthreads();
    ps[tid] += t;
    __syncthreads();
  }
  int pex = ps[tid] - pv;
  int base = s0e + pex;
  int n0 = lo + 2 * tid, n1 = n0 + 1;
  if (n0 < NN) {
    csr_off[n0] = base; cnt[n0] = a0;
    dis[n0] = (a0 > 0) ? rsqrtf((float)a0) : 0.0f;
    atomicAdd(&lhist[min(a0, NBIN - 1)], 1);
  }
  if (n1 < NN) {
    csr_off[n1] = base + a0; cnt[n1] = a1;
    dis[n1] = (a1 > 0) ? rsqrtf((float)a1) : 0.0f;
    atomicAdd(&lhist[min(a1, NBIN - 1)], 1);
  }
  curB[2 * tid] = base;
  curB[2 * tid + 1] = base + a0;
  __syncthreads();
  for (int i = s0e + tid; i < s1e; i += 256) {
    unsigned pk = pairs[i];
    int p = atomicAdd(&curB[pk >> 17], 1);
    csr_src[p] = (int)(pk & 0x1FFFFu);
  }
  __syncthreads();
  if (tid < NBIN) {
    int v = lhist[tid];
    if (v) atomicAdd(&hist[tid], v);
  }
}

__global__ void k_binscan(const int* __restrict__ hist, int* __restrict__ bincur) {
  int tid = threadIdx.x;
  int v = hist[tid];
  int incl = v;
  for (int d = 1; d < 64; d <<= 1) {
    int t = __shfl_up(incl, d, 64);
    if (tid >= d) incl += t;
  }
  bincur[tid] = incl - v;
}
__global__ __launch_bounds__(256) void k_scatter(const int* __restrict__ cnt,
                                                 int* __restrict__ bincur,
                                                 int* __restrict__ perm) {
  __shared__ int lh[NBIN];
  __shared__ int lbase[NBIN];
  if (threadIdx.x < NBIN) lh[threadIdx.x] = 0;
  __syncthreads();
  int i = blockIdx.x * 256 + threadIdx.x;
  int b = 0, r = 0;
  bool valid = i < NN;
  if (valid) {
    b = min(cnt[i], NBIN - 1);
    r = atomicAdd(&lh[b], 1);
  }
  __syncthreads();
  if (threadIdx.x < NBIN) {
    int v = lh[threadIdx.x];
    lbase[threadIdx.x] = v ? atomicAdd(&bincur[threadIdx.x], v) : 0;
  }
  __syncthreads();
  if (valid) perm[lbase[b] + r] = i;
}

// ================= device bodies =================
__device__ void gmean12h_body(int bid, const __half* x12h, const int* perm,
                              const int* off, const int* srcarr, __half* A32) {
  int g = bid * 64 + (threadIdx.x >> 2);
  int t = threadIdx.x & 3;
  if (g >= NN || t >= 3) return;
  int node = perm[g];
  int s = off[node], e = off[node + 1];
  const uint2* h2 = (const uint2*)x12h;
  float4 acc = {0, 0, 0, 0};
  int p = s;
  for (; p + 4 <= e; p += 4) {
    int s0 = srcarr[p], s1 = srcarr[p + 1], s2 = srcarr[p + 2], s3 = srcarr[p + 3];
    acc = f4add(acc, f4add(f4add(h4f(h2[(long)s0 * 3 + t]), h4f(h2[(long)s1 * 3 + t])),
                           f4add(h4f(h2[(long)s2 * 3 + t]), h4f(h2[(long)s3 * 3 + t]))));
  }
  for (; p < e; ++p) acc = f4add(acc, h4f(h2[(long)srcarr[p] * 3 + t]));
  int c = e - s;
  float inv = 1.0f / (float)(c > 0 ? c : 1);
  acc.x *= inv; acc.y *= inv; acc.z *= inv; acc.w *= inv;
  ((uint2*)A32)[(long)node * 8 + t] = pack4h(acc);
}

__device__ void tagp8_top_body(int bid, const float* x, const float* t1aw, const float* t1bw,
                               const float* dis, __half* PTop) {
  int i = bid * 256 + threadIdx.x;
  if (i >= NN) return;
  float a[11];
  #pragma unroll
  for (int j = 0; j < 11; ++j) a[j] = x[(long)i * 11 + j];
  float dn = dis[i];
  {
    float s[8];
    #pragma unroll
    for (int o = 0; o < 8; ++o) {
      float acc = 0.0f;
      #pragma unroll
      for (int j = 0; j < 11; ++j) acc += a[j] * t1aw[o * 44 + 3 * 11 + j];
      s[o] = acc;
    }
    uint2 lo = pack4h(make_float4(s[0] * dn, s[1] * dn, s[2] * dn, s[3] * dn));
    uint2 hi = pack4h(make_float4(s[4] * dn, s[5] * dn, s[6] * dn, s[7] * dn));
    uint4 o4; o4.x = lo.x; o4.y = lo.y; o4.z = hi.x; o4.w = hi.y;
    ((uint4*)PTop)[(long)i * 2] = o4;
  }
  {
    float s[8];
    #pragma unroll
    for (int o = 0; o < 8; ++o) {
      float acc = 0.0f;
      #pragma unroll
      for (int j = 0; j < 11; ++j) acc += a[j] * t1bw[o * 77 + 6 * 11 + j];
      s[o] = acc;
    }
    uint2 lo = pack4h(make_float4(s[0] * dn, s[1] * dn, s[2] * dn, s[3] * dn));
    uint2 hi = pack4h(make_float4(s[4] * dn, s[5] * dn, s[6] * dn, s[7] * dn));
    uint4 o4; o4.x = lo.x; o4.y = lo.y; o4.z = hi.x; o4.w = hi.y;
    ((uint4*)PTop)[(long)i * 2 + 1] = o4;
  }
}

// dual D8 hop; adds are fp16 [k][N][8] (one uint4 per node)
__device__ void d8_dual_body(int bid, const __half* src, const __half* addAH,
                             const __half* addBH, __half* dst,
                             const int* perm, const int* off,
                             const int* srcarr, const float* dis) {
  const uint4* src4 = (const uint4*)src;
  int t = threadIdx.x & 1;
  const uint4* addh = (const uint4*)(t == 0 ? addAH : addBH);
  int g = bid * 128 + (threadIdx.x >> 1);
  if (g >= NN) return;
  int node = perm[g];
  int s = off[node], e = off[node + 1];
  float acc[8] = {};
  int p = s;
  for (; p + 4 <= e; p += 4) {
    int s0 = srcarr[p], s1 = srcarr[p + 1], s2 = srcarr[p + 2], s3 = srcarr[p + 3];
    h8acc(src4[(long)s0 * 2 + t], acc); h8acc(src4[(long)s1 * 2 + t], acc);
    h8acc(src4[(long)s2 * 2 + t], acc); h8acc(src4[(long)s3 * 2 + t], acc);
  }
  for (; p < e; ++p) h8acc(src4[(long)srcarr[p] * 2 + t], acc);
  float dn = dis[node];
  uint4 av4 = addh[node];
  float4 a0 = h4f(make_uint2(av4.x, av4.y)), a1 = h4f(make_uint2(av4.z, av4.w));
  float4 r0 = make_float4((acc[0] * dn + a0.x) * dn, (acc[1] * dn + a0.y) * dn,
                          (acc[2] * dn + a0.z) * dn, (acc[3] * dn + a0.w) * dn);
  float4 r1 = make_float4((acc[4] * dn + a1.x) * dn, (acc[5] * dn + a1.y) * dn,
                          (acc[6] * dn + a1.z) * dn, (acc[7] * dn + a1.w) * dn);
  uint2 lo = pack4h(r0), hi = pack4h(r1);
  uint4 o; o.x = lo.x; o.y = lo.y; o.z = hi.x; o.w = hi.y;
  ((uint4*)dst)[(long)node * 2 + t] = o;
}

__device__ void d8_l3_body(int bid, const __half* src, const __half* Pa0H,
                           const float* t1ab, const float* t2aw,
                           const __half* Pb3H, __half* dstB, float* P2,
                           const int* perm, const int* off,
                           const int* srcarr, const float* dis) {
  const uint4* src4 = (const uint4*)src;
  int t = threadIdx.x & 1;
  int g = bid * 128 + (threadIdx.x >> 1);
  if (g >= NN) return;
  int node = perm[g];
  int s = off[node], e = off[node + 1];
  float acc[8] = {};
  int p = s;
  for (; p + 4 <= e; p += 4) {
    int s0 = srcarr[p], s1 = srcarr[p + 1], s2 = srcarr[p + 2], s3 = srcarr[p + 3];
    h8acc(src4[(long)s0 * 2 + t], acc); h8acc(src4[(long)s1 * 2 + t], acc);
    h8acc(src4[(long)s2 * 2 + t], acc); h8acc(src4[(long)s3 * 2 + t], acc);
  }
  for (; p < e; ++p) h8acc(src4[(long)srcarr[p] * 2 + t], acc);
  float dn = dis[node];
  if (t == 0) {
    uint4 av4 = ((const uint4*)Pa0H)[node];
    float4 a0 = h4f(make_uint2(av4.x, av4.y)), a1 = h4f(make_uint2(av4.z, av4.w));
    float4 b0 = ((const float4*)t1ab)[0], b1 = ((const float4*)t1ab)[1];
    float a[8];
    a[0] = sigm(acc[0] * dn + a0.x + b0.x); a[1] = sigm(acc[1] * dn + a0.y + b0.y);
    a[2] = sigm(acc[2] * dn + a0.z + b0.z); a[3] = sigm(acc[3] * dn + a0.w + b0.w);
    a[4] = sigm(acc[4] * dn + a1.x + b1.x); a[5] = sigm(acc[5] * dn + a1.y + b1.y);
    a[6] = sigm(acc[6] * dn + a1.z + b1.z); a[7] = sigm(acc[7] * dn + a1.w + b1.w);
    #pragma unroll
    for (int k = 0; k < 4; ++k) {
      float sv = 0.0f;
      #pragma unroll
      for (int j = 0; j < 8; ++j) sv += a[j] * t2aw[k * 8 + j];
      if (k == 3) sv *= dn;
      P2[(size_t)k * NN + node] = sv;
    }
  } else {
    uint4 av4 = ((const uint4*)Pb3H)[node];
    float4 a0 = h4f(make_uint2(av4.x, av4.y)), a1 = h4f(make_uint2(av4.z, av4.w));
    float4 r0 = make_float4((acc[0] * dn + a0.x) * dn, (acc[1] * dn + a0.y) * dn,
                            (acc[2] * dn + a0.z) * dn, (acc[3] * dn + a0.w) * dn);
    float4 r1 = make_float4((acc[4] * dn + a1.x) * dn, (acc[5] * dn + a1.y) * dn,
                            (acc[6] * dn + a1.z) * dn, (acc[7] * dn + a1.w) * dn);
    uint2 lo = pack4h(r0), hi = pack4h(r1);
    uint4 o; o.x = lo.x; o.y = lo.y; o.z = hi.x; o.w = hi.y;
    ((uint4*)dstB)[(long)node * 2 + 1] = o;
  }
}

// single-B D8 hop; addB fp16 slice (lane t reads halves 4t..4t+3)
__device__ void d8_single_body(int bid, const __half* src, const __half* addBH, __half* dst,
                               const int* perm, const int* off,
                               const int* srcarr, const float* dis) {
  const uint2* src2 = (const uint2*)src;
  int t = threadIdx.x & 1;
  int g = bid * 128 + (threadIdx.x >> 1);
  if (g >= NN) return;
  int node = perm[g];
  int s = off[node], e = off[node + 1];
  float4 acc = {0, 0, 0, 0};
  int p = s;
  for (; p + 4 <= e; p += 4) {
    int s0 = srcarr[p], s1 = srcarr[p + 1], s2 = srcarr[p + 2], s3 = srcarr[p + 3];
    acc = f4add(acc, f4add(f4add(h4f(src2[(long)s0 * 4 + 2 + t]), h4f(src2[(long)s1 * 4 + 2 + t])),
                           f4add(h4f(src2[(long)s2 * 4 + 2 + t]), h4f(src2[(long)s3 * 4 + 2 + t]))));
  }
  for (; p < e; ++p) acc = f4add(acc, h4f(src2[(long)srcarr[p] * 4 + 2 + t]));
  float dn = dis[node];
  float4 av = h4f(((const uint2*)addBH)[(long)node * 2 + t]);
  float4 r = make_float4((acc.x * dn + av.x) * dn, (acc.y * dn + av.y) * dn,
                         (acc.z * dn + av.z) * dn, (acc.w * dn + av.w) * dn);
  ((uint2*)dst)[(long)node * 4 + 2 + t] = pack4h(r);
}

__device__ void d8_l6_body(int bid, const __half* src, const __half* Pb0H,
                           const float* t1bb, const float* t2bw, float* P2b,
                           const int* perm, const int* off,
                           const int* srcarr, const float* dis) {
  const uint2* src2 = (const uint2*)src;
  int t = threadIdx.x & 1;
  int g = bid * 128 + (threadIdx.x >> 1);
  if (g >= NN) return;
  int node = perm[g];
  int s = off[node], e = off[node + 1];
  float4 acc = {0, 0, 0, 0};
  int p = s;
  for (; p + 4 <= e; p += 4) {
    int s0 = srcarr[p], s1 = srcarr[p + 1], s2 = srcarr[p + 2], s3 = srcarr[p + 3];
    acc = f4add(acc, f4add(f4add(h4f(src2[(long)s0 * 4 + 2 + t]), h4f(src2[(long)s1 * 4 + 2 + t])),
                           f4add(h4f(src2[(long)s2 * 4 + 2 + t]), h4f(src2[(long)s3 * 4 + 2 + t]))));
  }
  for (; p < e; ++p) acc = f4add(acc, h4f(src2[(long)srcarr[p] * 4 + 2 + t]));
  float dn = dis[node];
  float4 av = h4f(((const uint2*)Pb0H)[(long)node * 2 + t]);
  float4 bv = ((const float4*)t1bb)[t];
  float4 r = make_float4(sigm(acc.x * dn + av.x + bv.x), sigm(acc.y * dn + av.y + bv.y),
                         sigm(acc.z * dn + av.z + bv.z), sigm(acc.w * dn + av.w + bv.w));
  float o0 = __shfl_xor(r.x, 1, 64), o1 = __shfl_xor(r.y, 1, 64);
  float o2 = __shfl_xor(r.z, 1, 64), o3 = __shfl_xor(r.w, 1, 64);
  if (t == 0) {
    float a[8] = {r.x, r.y, r.z, r.w, o0, o1, o2, o3};
    #pragma unroll
    for (int k = 0; k < 7; ++k) {
      float sv = 0.0f;
      #pragma unroll
      for (int j = 0; j < 8; ++j) sv += a[j] * t2bw[k * 8 + j];
      if (k == 6) sv *= dn;
      P2b[(size_t)k * NN + node] = sv;
    }
  }
}

__device__ void d1_body(int bid, const float* ua, const float* adda, const float* bias,
                        int act, float* outa, const int* perm, const int* off,
                        const int* srcarr, const float* dis) {
  int g = bid * 64 + (threadIdx.x >> 2);
  int t = threadIdx.x & 3;
  if (g >= NN) return;
  int node = perm[g];
  int s = off[node], e = off[node + 1];
  float accA = 0.0f;
  for (int p = s + t; p < e; p += 4) accA += ua[srcarr[p]];
  accA += __shfl_xor(accA, 1, 64); accA += __shfl_xor(accA, 2, 64);
  if (t == 0) {
    float sc = dis[node];
    float rA = accA * sc + adda[node];
    if (bias) rA += bias[0];
    if (act == 3) rA *= sc; else if (act == 2) rA = fmaxf(rA, 0.0f);
    outa[node] = rA;
  }
}

__device__ void x1s_body(int bid, const float* pp, const float* qq, const float* s3b,
                         const int* perm, const int* off, const int* srcarr,
                         float* x1s) {
  int g = bid * 64 + (threadIdx.x >> 2);
  int t = threadIdx.x & 3;
  if (g >= NN) return;
  int node = perm[g];
  int s = off[node], e = off[node + 1];
  float acc = 0.0f;
  for (int p = s + t; p < e; p += 4) acc += pp[srcarr[p]];
  acc += __shfl_xor(acc, 1, 64); acc += __shfl_xor(acc, 2, 64);
  if (t == 0) {
    int c = e - s;
    float sc = 1.0f / (float)(c > 0 ? c : 1);
    x1s[node] = fmaxf(acc * sc + qq[node] + s3b[0], 0.0f);
  }
}

__device__ void gather128_body(int bid, const __half* h, const int* perm,
                               const int* off, const int* srcarr, __half* outh) {
  int g = bid * 16 + (threadIdx.x >> 4);
  int t = threadIdx.x & 15;
  if (g >= NN) return;
  int node = perm[g];
  int s = off[node], e = off[node + 1];
  const uint4* h4 = (const uint4*)h;
  float acc[8] = {};
  int p = s;
  for (; p + 4 <= e; p += 4) {
    int s0 = srcarr[p], s1 = srcarr[p + 1], s2 = srcarr[p + 2], s3 = srcarr[p + 3];
    uint4 r0 = h4[(long)s0 * 16 + t], r1 = h4[(long)s1 * 16 + t];
    uint4 r2 = h4[(long)s2 * 16 + t], r3 = h4[(long)s3 * 16 + t];
    h8acc(r0, acc); h8acc(r1, acc); h8acc(r2, acc); h8acc(r3, acc);
  }
  for (; p < e; ++p) h8acc(h4[(long)srcarr[p] * 16 + t], acc);
  int c = e - s;
  float inv = 1.0f / (float)(c > 0 ? c : 1);
  uint2 lo = pack4h(make_float4(acc[0] * inv, acc[1] * inv, acc[2] * inv, acc[3] * inv));
  uint2 hi = pack4h(make_float4(acc[4] * inv, acc[5] * inv, acc[6] * inv, acc[7] * inv));
  uint4 o; o.x = lo.x; o.y = lo.y; o.z = hi.x; o.w = hi.y;
  ((uint4*)outh)[(long)node * 16 + t] = o;
}

__device__ void mm1_body(int bid, const __half* A32, const __half* W32,
                         const float* bias, __half* out, __half (*lt)[32][136]) {
  int tid = threadIdx.x;
  int wave = tid >> 6, l = tid & 63;
  int lr = l & 15, lk = l >> 4;
  int m0 = bid * 128 + wave * 32;
  f4v acc[2][8] = {};
  h8v afrag[2];
  #pragma unroll
  for (int rt = 0; rt < 2; ++rt) {
    int row = m0 + rt * 16 + lr;
    h8v z = {};
    afrag[rt] = (row < NN) ? *(const h8v*)&A32[(long)row * 32 + lk * 8] : z;
  }
  #pragma unroll
  for (int c = 0; c < 8; ++c) {
    h8v bfrag = *(const h8v*)&W32[(c * 16 + lr) * 32 + lk * 8];
    acc[0][c] = __builtin_amdgcn_mfma_f32_16x16x32_f16(afrag[0], bfrag, acc[0][c], 0, 0, 0);
    acc[1][c] = __builtin_amdgcn_mfma_f32_16x16x32_f16(afrag[1], bfrag, acc[1][c], 0, 0, 0);
  }
  float bi[8];
  #pragma unroll
  for (int c = 0; c < 8; ++c) bi[c] = bias[c * 16 + lr];
  #pragma unroll
  for (int rt = 0; rt < 2; ++rt)
    #pragma unroll
    for (int c = 0; c < 8; ++c)
      #pragma unroll
      for (int reg = 0; reg < 4; ++reg) {
        float v = acc[rt][c][reg] + bi[c];
        lt[wave][rt * 16 + lk * 4 + reg][c * 16 + lr] = __float2half(sigm(v));
      }
  __syncthreads();
  #pragma unroll
  for (int it = 0; it < 8; ++it) {
    int idx = it * 64 + l;
    int row = idx >> 4, c16 = idx & 15;
    int grow = m0 + row;
    if (grow < NN) {
      uint4 v = *(const uint4*)&lt[wave][row][c16 * 8];
      ((uint4*)out)[(long)grow * 16 + c16] = v;
    }
  }
}

__device__ void mm2_body(int bid, const __half* A1, const __half* A2,
                         const __half* W, const float* bias,
                         const float* w3l, const float* w3r,
                         float* pp, float* qq) {
  int tid = threadIdx.x;
  int wave = tid >> 6;
  int l = tid & 63;
  int lr = l & 15;
  int lk = l >> 4;
  int m0 = bid * 128 + wave * 32;
  f4v acc[2][8] = {};
  #pragma unroll
  for (int ks = 0; ks < 8; ++ks) {
    const __half* Asrc = (ks < 4) ? A1 : A2;
    int kk = (ks & 3) * 32 + lk * 8;
    h8v afrag[2];
    #pragma unroll
    for (int rt = 0; rt < 2; ++rt) {
      int row = m0 + rt * 16 + lr;
      h8v z = {};
      afrag[rt] = (row < NN) ? *(const h8v*)&Asrc[(long)row * 128 + kk] : z;
    }
    #pragma unroll
    for (int c = 0; c < 8; ++c) {
      h8v bfrag = *(const h8v*)&W[(long)(c * 16 + lr) * 256 + ks * 32 + lk * 8];
      acc[0][c] = __builtin_amdgcn_mfma_f32_16x16x32_f16(afrag[0], bfrag, acc[0][c], 0, 0, 0);
      acc[1][c] = __builtin_amdgcn_mfma_f32_16x16x32_f16(afrag[1], bfrag, acc[1][c], 0, 0, 0);
    }
  }
  float wl[8], wr[8], bi[8];
  #pragma unroll
  for (int c = 0; c < 8; ++c) {
    wl[c] = w3l[c * 16 + lr];
    wr[c] = w3r[c * 16 + lr];
    bi[c] = bias[c * 16 + lr];
  }
  #pragma unroll
  for (int rt = 0; rt < 2; ++rt) {
    #pragma unroll
    for (int reg = 0; reg < 4; ++reg) {
      float s1 = 0.0f, s2 = 0.0f;
      #pragma unroll
      for (int c = 0; c < 8; ++c) {
        float v = acc[rt][c][reg] + bi[c];
        float sg = sigm(v);
        s1 += sg * wl[c];
        s2 += sg * wr[c];
      }
      #pragma unroll
      for (int d = 1; d < 16; d <<= 1) {
        s1 += __shfl_xor(s1, d, 64);
        s2 += __shfl_xor(s2, d, 64);
      }
      int row = m0 + rt * 16 + lk * 4 + reg;
      if (lr == 0 && row < NN) { pp[row] = s1; qq[row] = s2; }
    }
  }
}

// ================= fused dispatches =================
__global__ __launch_bounds__(256) void k_fuseA(
    const __half* x12h, const int* perm, const int* off, const int* srcarr, __half* A32,
    const float* x, const float* t1aw, const float* t1bw, const float* dis, __half* PTop) {
  if (blockIdx.x < GA) gmean12h_body(blockIdx.x, x12h, perm, off, srcarr, A32);
  else tagp8_top_body(blockIdx.x - GA, x, t1aw, t1bw, dis, PTop);
}

__global__ __launch_bounds__(256) void k_fuseB(
    const __half* A32, const __half* W32, const float* s1b, __half* x1a,
    const __half* PTop, const __half* Pa2H, const __half* Pb5H, __half* zbuf0,
    const int* perm, const int* off, const int* srcarr, const float* dis) {
  __shared__ __half lt[4][32][136];
  if (blockIdx.x < GM) mm1_body(blockIdx.x, A32, W32, s1b, x1a, lt);
  else d8_dual_body(blockIdx.x - GM, PTop, Pa2H, Pb5H, zbuf0, perm, off, srcarr, dis);
}

__global__ __launch_bounds__(256) void k_fuseC(
    const __half* x1a, __half* mean128,
    const __half* zbuf0, const __half* Pa1H, const __half* Pb4H, __half* zbuf1,
    const int* perm, const int* off, const int* srcarr, const float* dis) {
  if (blockIdx.x < GG) gather128_body(blockIdx.x, x1a, perm, off, srcarr, mean128);
  else d8_dual_body(blockIdx.x - GG, zbuf0, Pa1H, Pb4H, zbuf1, perm, off, srcarr, dis);
}

__global__ __launch_bounds__(256) void k_fuseD(
    const __half* mean128, const __half* x1a, const __half* w2h, const float* s2b,
    const float* w3l, const float* w3r, float* pp, float* qq,
    const __half* zbuf1, const __half* Pa0H, const float* t1ab, const float* t2aw,
    const __half* Pb3H, __half* zbuf0, float* P2,
    const int* perm, const int* off, const int* srcarr, const float* dis) {
  if (blockIdx.x < GM) mm2_body(blockIdx.x, mean128, x1a, w2h, s2b, w3l, w3r, pp, qq);
  else d8_l3_body(blockIdx.x - GM, zbuf1, Pa0H, t1ab, t2aw, Pb3H, zbuf0, P2,
                  perm, off, srcarr, dis);
}

__global__ __launch_bounds__(256) void k_fuseE(
    const __half* zbuf0, const __half* Pb2H, __half* zbuf1,
    const float* pp, const float* qq, const float* s3b, float* x1s,
    const float* P2, float* uA1,
    const int* perm, const int* off, const int* srcarr, const float* dis) {
  if (blockIdx.x < GM)
    d8_single_body(blockIdx.x, zbuf0, Pb2H, zbuf1, perm, off, srcarr, dis);
  else if (blockIdx.x < GM + G1)
    x1s_body(blockIdx.x - GM, pp, qq, s3b, perm, off, srcarr, x1s);
  else
    d1_body(blockIdx.x - GM - G1, P2 + 3 * (size_t)NN, P2 + 2 * (size_t)NN,
            nullptr, 3, uA1, perm, off, srcarr, dis);
}

__global__ __launch_bounds__(256) void k_fuseF(
    const __half* zbuf1, const __half* Pb1H, __half* zbuf0,
    const float* uA1, const float* P2, float* uA2,
    const int* perm, const int* off, const int* srcarr, const float* dis) {
  if (blockIdx.x < GM)
    d8_single_body(blockIdx.x, zbuf1, Pb1H, zbuf0, perm, off, srcarr, dis);
  else
    d1_body(blockIdx.x - GM, uA1, P2 + 1 * (size_t)NN, nullptr, 3, uA2,
            perm, off, srcarr, dis);
}

__global__ __launch_bounds__(256) void k_fuseG(
    const __half* zbuf0, const __half* Pb0H, const float* t1bb, const float* t2bw,
    float* P2b, const float* uA2, const float* P2, const float* t2ab, float* x2s,
    const int* perm, const int* off, const int* srcarr, const float* dis) {
  if (blockIdx.x < GM)
    d8_l6_body(blockIdx.x, zbuf0, Pb0H, t1bb, t2bw, P2b, perm, off, srcarr, dis);
  else
    d1_body(blockIdx.x - GM, uA2, P2, t2ab, 2, x2s, perm, off, srcarr, dis);
}

__global__ __launch_bounds__(256) void k_d1b(
    const float* ua, const float* adda, float* outa,
    const int* perm, const int* off, const int* srcarr, const float* dis) {
  d1_body(blockIdx.x, ua, adda, nullptr, 3, outa, perm, off, srcarr, dis);
}

__global__ __launch_bounds__(256) void k_g1_final(
    const float* ua, const float* adda, const float* biasa,
    const float* x1s, const float* x2s,
    const float* lw, const float* lb,
    const int* perm, const int* off, const int* srcarr, const float* dis,
    float* out) {
  int g = blockIdx.x * 64 + (threadIdx.x >> 2);
  int t = threadIdx.x & 3;
  if (g >= NN) return;
  int node = perm[g];
  int s = off[node], e = off[node + 1];
  float accA = 0.0f;
  for (int p = s + t; p < e; p += 4) accA += ua[srcarr[p]];
  accA += __shfl_xor(accA, 1, 64); accA += __shfl_xor(accA, 2, 64);
  if (t == 0) {
    float x3v = fmaxf(accA * dis[node] + adda[node] + biasa[0], 0.0f);
    float v = x1s[node] * lw[0] + x2s[node] * lw[1] + x3v * lw[2] + lb[0];
    out[node] = fmaxf(v, 0.0f);
  }
}

extern "C" void kernel_launch(void* const* d_in, const int* in_sizes, int n_in,
                              void* d_out, int out_size, void* d_ws, size_t ws_size,
                              hipStream_t stream) {
  const float* x    = (const float*)d_in[0];
  const int*   ei   = (const int*)d_in[1];
  const float* s1wl = (const float*)d_in[2];
  const float* s1wr = (const float*)d_in[3];
  const float* s1b  = (const float*)d_in[4];
  const float* s2wl = (const float*)d_in[5];
  const float* s2wr = (const float*)d_in[6];
  const float* s2b  = (const float*)d_in[7];
  const float* s3wl = (const float*)d_in[8];
  const float* s3wr = (const float*)d_in[9];
  const float* s3b  = (const float*)d_in[10];
  const float* t1aw = (const float*)d_in[11];
  const float* t1ab = (const float*)d_in[12];
  const float* t2aw = (const float*)d_in[13];
  const float* t2ab = (const float*)d_in[14];
  const float* t1bw = (const float*)d_in[15];
  const float* t1bb = (const float*)d_in[16];
  const float* t2bw = (const float*)d_in[17];
  const float* t2bb = (const float*)d_in[18];
  const float* lw   = (const float*)d_in[19];
  const float* lb   = (const float*)d_in[20];
  float* out = (float*)d_out;

  char* basep = (char*)d_ws;
  size_t off = 0;
  auto alloc = [&](size_t bytes) -> void* {
    void* ptr = basep + off;
    off = (off + bytes + 255) & ~(size_t)255;
    return ptr;
  };
  int*      cnt     = (int*)alloc((size_t)NN * 4);
  int*      csr_off = (int*)alloc((size_t)(NN + 1) * 4);
  float*    dis     = (float*)alloc((size_t)NN * 4);
  int*      csr_src = (int*)alloc((size_t)EE * 4);
  unsigned* pairs   = (unsigned*)alloc((size_t)EE * 4);
  int*      perm    = (int*)alloc((size_t)NN * 4);
  int*      ghist   = (int*)alloc(256 * 4);
  int*      gcur    = (int*)alloc(256 * 4);
  int*      bexclB  = (int*)alloc(256 * 4);
  int*      hist    = (int*)alloc(NBIN * 4);
  int*      bincur  = (int*)alloc(NBIN * 4);
  float*    x1s     = (float*)alloc((size_t)NN * 4);
  float*    x2s     = (float*)alloc((size_t)NN * 4);
  float*    pp      = (float*)alloc((size_t)NN * 4);
  float*    qq      = (float*)alloc((size_t)NN * 4);
  float*    uA1     = (float*)alloc((size_t)NN * 4);
  float*    uA2     = (float*)alloc((size_t)NN * 4);
  float*    uB1     = (float*)alloc((size_t)NN * 4);
  float*    uB2     = (float*)alloc((size_t)NN * 4);
  __half*   x12h    = (__half*)alloc((size_t)NN * 12 * 2);
  __half*   A32     = (__half*)alloc((size_t)NN * 32 * 2);
  __half*   w1h     = (__half*)alloc((size_t)128 * 32 * 2);
  __half*   w2h     = (__half*)alloc((size_t)128 * 256 * 2);
  __half*   x1a_h   = (__half*)alloc((size_t)NN * 128 * 2);
  __half*   mean128_h = (__half*)alloc((size_t)NN * 128 * 2);
  __half*   PaH   = (__half*)alloc((size_t)NN * 24 * 2);  // [3][N][8] fp16
  __half*   PbH   = (__half*)alloc((size_t)NN * 48 * 2);  // [6][N][8] fp16
  __half*   PTop  = (__half*)alloc((size_t)NN * 16 * 2);  // [N][16] interleaved
  __half*   zbuf0 = (__half*)alloc((size_t)NN * 16 * 2);
  __half*   zbuf1 = (__half*)alloc((size_t)NN * 16 * 2);
  float*    P2    = (float*)alloc((size_t)NN * 4 * 4);    // [4][N]
  float*    P2b   = (float*)alloc((size_t)NN * 7 * 4);    // [7][N]

  const size_t H8 = (size_t)NN * 8;   // halves per slice
  const size_t S1 = (size_t)NN;

  // ---- CSR build + prep ----
  hipMemsetAsync(ghist, 0, 3840, stream);
  k_bhist_prep<<<BH_B + PREP_B0 + PREP_B1 + 16 + 128, 256, 0, stream>>>(
      ei, ghist, x, s1wl, s1wr, s2wl, s2wr, x12h, A32, w1h, w2h);
  k_b196scan<<<1, 256, 0, stream>>>(ghist, gcur, bexclB, csr_off);
  k_split_tag<<<SPB + TGA, 256, 0, stream>>>(ei, gcur, pairs, x, t1aw, t1bw, PaH, PbH);
  k_bbuild<<<NBK, 256, 0, stream>>>(pairs, bexclB, cnt, csr_off, dis, csr_src, hist);
  k_binscan<<<1, 64, 0, stream>>>(hist, bincur);
  k_scatter<<<(NN + 255) / 256, 256, 0, stream>>>(cnt, bincur, perm);

  // ---- co-scheduled SAGE + TAG ----
  k_fuseA<<<GA + GT, 256, 0, stream>>>(
      x12h, perm, csr_off, csr_src, A32, x, t1aw, t1bw, dis, PTop);
  k_fuseB<<<GM + GM, 256, 0, stream>>>(
      A32, w1h, s1b, x1a_h, PTop, PaH + 2 * H8, PbH + 5 * H8, zbuf0,
      perm, csr_off, csr_src, dis);
  k_fuseC<<<GG + GM, 256, 0, stream>>>(
      x1a_h, mean128_h, zbuf0, PaH + 1 * H8, PbH + 4 * H8, zbuf1,
      perm, csr_off, csr_src, dis);
  k_fuseD<<<GM + GM, 256, 0, stream>>>(
      mean128_h, x1a_h, w2h, s2b, s3wl, s3wr, pp, qq,
      zbuf1, PaH, t1ab, t2aw, PbH + 3 * H8, zbuf0, P2,
      perm, csr_off, csr_src, dis);
  k_fuseE<<<GM + G1 + G1, 256, 0, stream>>>(
      zbuf0, PbH + 2 * H8, zbuf1, pp, qq, s3b, x1s, P2, uA1,
      perm, csr_off, csr_src, dis);
  k_fuseF<<<GM + G1, 256, 0, stream>>>(
      zbuf1, PbH + 1 * H8, zbuf0, uA1, P2, uA2,
      perm, csr_off, csr_src, dis);
  k_fuseG<<<GM + G1, 256, 0, stream>>>(
      zbuf0, PbH, t1bb, t2bw, P2b, uA2, P2, t2ab, x2s,
      perm, csr_off, csr_src, dis);

  // ---- d1b tail chain ----
  k_d1b<<<G1, 256, 0, stream>>>(P2b + 6 * S1, P2b + 5 * S1, uB1, perm, csr_off, csr_src, dis);
  k_d1b<<<G1, 256, 0, stream>>>(uB1, P2b + 4 * S1, uB2, perm, csr_off, csr_src, dis);
  k_d1b<<<G1, 256, 0, stream>>>(uB2, P2b + 3 * S1, uB1, perm, csr_off, csr_src, dis);
  k_d1b<<<G1, 256, 0, stream>>>(uB1, P2b + 2 * S1, uB2, perm, csr_off, csr_src, dis);
  k_d1b<<<G1, 256, 0, stream>>>(uB2, P2b + 1 * S1, uB1, perm, csr_off, csr_src, dis);
  k_g1_final<<<G1, 256, 0, stream>>>(
      uB1, P2b, t2bb, x1s, x2s, lw, lb, perm, csr_off, csr_src, dis, out);
}

// Round 13
// 461.618 us; speedup vs baseline: 3.1678x; 1.0059x over previous
//
#include <hip/hip_runtime.h>
#include <hip/hip_bf16.h>
#include <hip/hip_fp16.h>

#define NN 100000
#define EE 1600000
#define NBIN 64
#define BSH 9
#define BSZ 512
#define NBK 196   // ceil(NN/512)

// grid segment sizes
#define GA 1563   // gmean12h blocks (64 nodes/block)
#define GT 391    // tagP8-top blocks (256 nodes/block)
#define GM 782    // mm / d8 blocks (128 nodes/block)
#define GG 6250   // gather128 blocks (16 nodes/block)
#define G1 1563   // d1 blocks (64 nodes/block)
#define SPB 391   // split blocks (4096 edges/block)
#define TGA 391   // tagP8-adds blocks (256 nodes/block)

typedef _Float16 h8v __attribute__((ext_vector_type(8)));
typedef float f4v __attribute__((ext_vector_type(4)));

__device__ __forceinline__ float sigm(float v) { return 1.0f / (1.0f + expf(-v)); }
__device__ __forceinline__ float4 f4add(float4 a, float4 b) {
  a.x += b.x; a.y += b.y; a.z += b.z; a.w += b.w; return a;
}
__device__ __forceinline__ float4 h4f(uint2 v) {
  __half2 a = *reinterpret_cast<__half2*>(&v.x);
  __half2 b = *reinterpret_cast<__half2*>(&v.y);
  float2 fa = __half22float2(a), fb = __half22float2(b);
  return make_float4(fa.x, fa.y, fb.x, fb.y);
}
__device__ __forceinline__ void h8acc(uint4 v, float* a) {
  float4 lo = h4f(make_uint2(v.x, v.y));
  float4 hi = h4f(make_uint2(v.z, v.w));
  a[0] += lo.x; a[1] += lo.y; a[2] += lo.z; a[3] += lo.w;
  a[4] += hi.x; a[5] += hi.y; a[6] += hi.z; a[7] += hi.w;
}
__device__ __forceinline__ uint2 pack4h(float4 r) {
  __half2 q0 = __floats2half2_rn(r.x, r.y), q1 = __floats2half2_rn(r.z, r.w);
  uint2 o; o.x = *(unsigned*)&q0; o.y = *(unsigned*)&q1; return o;
}

// ================= CSR build + fused prep =================
#define BH_B 512
#define PREP_B0 ((NN * 12 + 255) / 256)
#define PREP_B1 ((NN + 255) / 256)
__global__ __launch_bounds__(256) void k_bhist_prep(
    const int* __restrict__ ei, int* __restrict__ ghist,
    const float* __restrict__ x, const float* __restrict__ s1wl, const float* __restrict__ s1wr,
    const float* __restrict__ s2wl, const float* __restrict__ s2wr,
    __half* __restrict__ x12h, __half* __restrict__ A32,
    __half* __restrict__ w1h, __half* __restrict__ w2h) {
  __shared__ int lh[NBK];
  int bid = blockIdx.x;
  if (bid < BH_B) {
    for (int j = threadIdx.x; j < NBK; j += 256) lh[j] = 0;
    __syncthreads();
    for (int i = bid * 256 + threadIdx.x; i < EE; i += BH_B * 256)
      atomicAdd(&lh[ei[EE + i] >> BSH], 1);
    __syncthreads();
    for (int j = threadIdx.x; j < NBK; j += 256) {
      int v = lh[j];
      if (v) atomicAdd(&ghist[j], v);
    }
    return;
  }
  int pid = bid - BH_B;
  if (pid < PREP_B0) {
    int i = pid * 256 + threadIdx.x;
    if (i < NN * 12) {
      int n = i / 12, j = i - n * 12;
      x12h[i] = __float2half((j < 11) ? x[n * 11 + j] : 0.0f);
    }
  } else if (pid < PREP_B0 + PREP_B1) {
    int i = (pid - PREP_B0) * 256 + threadIdx.x;
    if (i < NN) {
      float a[11];
      #pragma unroll
      for (int j = 0; j < 11; ++j) a[j] = x[(long)i * 11 + j];
      uint2* row = (uint2*)(A32 + (long)i * 32);
      row[3] = make_uint2(0u, 0u);
      row[4] = pack4h(make_float4(a[0], a[1], a[2], a[3]));
      row[5] = pack4h(make_float4(a[4], a[5], a[6], a[7]));
      row[6] = pack4h(make_float4(a[8], a[9], a[10], 0.0f));
      row[7] = make_uint2(0u, 0u);
    }
  } else if (pid < PREP_B0 + PREP_B1 + 16) {
    int i = (pid - PREP_B0 - PREP_B1) * 256 + threadIdx.x;
    int o = i >> 5, k = i & 31;
    float v = 0.0f;
    if (k < 11) v = s1wl[o * 11 + k];
    else if (k >= 16 && k < 27) v = s1wr[o * 11 + (k - 16)];
    w1h[i] = __float2half(v);
  } else {
    int i = (pid - PREP_B0 - PREP_B1 - 16) * 256 + threadIdx.x;
    int o = i >> 8, k = i & 255;
    float v = (k < 128) ? s2wl[o * 128 + k] : s2wr[o * 128 + (k - 128)];
    w2h[i] = __float2half(v);
  }
}

// unscaled TAG first-linear slices (fp16, one uint4 per node per slice)
__device__ void tagp8_adds_body(int bid, const float* x, const float* t1aw,
                                const float* t1bw, __half* PaH, __half* PbH) {
  int i = bid * 256 + threadIdx.x;
  if (i >= NN) return;
  float a[11];
  #pragma unroll
  for (int j = 0; j < 11; ++j) a[j] = x[(long)i * 11 + j];
  #pragma unroll
  for (int k = 0; k < 3; ++k) {
    float s[8];
    #pragma unroll
    for (int o = 0; o < 8; ++o) {
      float acc = 0.0f;
      #pragma unroll
      for (int j = 0; j < 11; ++j) acc += a[j] * t1aw[o * 44 + k * 11 + j];
      s[o] = acc;
    }
    uint2 lo = pack4h(make_float4(s[0], s[1], s[2], s[3]));
    uint2 hi = pack4h(make_float4(s[4], s[5], s[6], s[7]));
    uint4 o4; o4.x = lo.x; o4.y = lo.y; o4.z = hi.x; o4.w = hi.y;
    ((uint4*)PaH)[(size_t)k * NN + i] = o4;
  }
  #pragma unroll
  for (int k = 0; k < 6; ++k) {
    float s[8];
    #pragma unroll
    for (int o = 0; o < 8; ++o) {
      float acc = 0.0f;
      #pragma unroll
      for (int j = 0; j < 11; ++j) acc += a[j] * t1bw[o * 77 + k * 11 + j];
      s[o] = acc;
    }
    uint2 lo = pack4h(make_float4(s[0], s[1], s[2], s[3]));
    uint2 hi = pack4h(make_float4(s[4], s[5], s[6], s[7]));
    uint4 o4; o4.x = lo.x; o4.y = lo.y; o4.z = hi.x; o4.w = hi.y;
    ((uint4*)PbH)[(size_t)k * NN + i] = o4;
  }
}

// split + co-scheduled tagP8-adds; bucket offsets computed locally from ghist
__global__ __launch_bounds__(256) void k_split_tag(
    const int* __restrict__ ei, const int* __restrict__ ghist, int* __restrict__ gcur0,
    unsigned* __restrict__ pairs,
    const float* __restrict__ x, const float* __restrict__ t1aw,
    const float* __restrict__ t1bw, __half* __restrict__ PaH, __half* __restrict__ PbH) {
  if (blockIdx.x >= SPB) {
    tagp8_adds_body(blockIdx.x - SPB, x, t1aw, t1bw, PaH, PbH);
    return;
  }
  __shared__ int exclS[256];
  __shared__ int cntL[256];
  __shared__ int segO[256];
  __shared__ int curL[256];
  __shared__ int baseL[256];
  __shared__ unsigned stag[4096];
  __shared__ unsigned char bktL[4096];
  int tid = threadIdx.x;
  // local exclusive scan of ghist
  {
    int v = (tid < NBK) ? ghist[tid] : 0;
    segO[tid] = v;
    __syncthreads();
    for (int d = 1; d < 256; d <<= 1) {
      int t = (tid >= d) ? segO[tid - d] : 0;
      __syncthreads();
      segO[tid] += t;
      __syncthreads();
    }
    exclS[tid] = segO[tid] - v;
    __syncthreads();
  }
  int tile0 = blockIdx.x * 4096;
  int tcnt = min(4096, EE - tile0);
  cntL[tid] = 0; curL[tid] = 0;
  __syncthreads();
  for (int i = tid; i < tcnt; i += 256)
    atomicAdd(&cntL[ei[EE + tile0 + i] >> BSH], 1);
  __syncthreads();
  int v = cntL[tid];
  segO[tid] = v;
  __syncthreads();
  for (int d = 1; d < 256; d <<= 1) {
    int t = (tid >= d) ? segO[tid - d] : 0;
    __syncthreads();
    segO[tid] += t;
    __syncthreads();
  }
  int excl = segO[tid] - v;
  __syncthreads();
  segO[tid] = excl;
  __syncthreads();
  for (int i = tid; i < tcnt; i += 256) {
    int s = ei[tile0 + i], dd = ei[EE + tile0 + i];
    int b = dd >> BSH;
    int slot = segO[b] + atomicAdd(&curL[b], 1);
    stag[slot] = (unsigned)s | ((unsigned)(dd & (BSZ - 1)) << 17);
    bktL[slot] = (unsigned char)b;
  }
  baseL[tid] = v ? (exclS[tid] + atomicAdd(&gcur0[tid], v)) : 0;
  __syncthreads();
  for (int i = tid; i < tcnt; i += 256) {
    int b = bktL[i];
    pairs[baseL[b] + (i - segO[b])] = stag[i];
  }
}

// per-bucket count + scan + fill + degree-histogram; bounds computed locally
__global__ __launch_bounds__(256) void k_bbuild(const unsigned* __restrict__ pairs,
                                                const int* __restrict__ ghist,
                                                int* __restrict__ csr_off,
                                                float* __restrict__ dis, int* __restrict__ csr_src,
                                                int* __restrict__ hist) {
  __shared__ int c[BSZ];
  __shared__ int ps[256];
  __shared__ int curB[BSZ];
  __shared__ int lhist[NBIN];
  __shared__ int s0s, s1s;
  int tid = threadIdx.x;
  int b = blockIdx.x;
  int lo = b << BSH;
  // local scan of ghist for this bucket's bounds
  {
    int v = (tid < NBK) ? ghist[tid] : 0;
    ps[tid] = v;
    __syncthreads();
    for (int d = 1; d < 256; d <<= 1) {
      int t = (tid >= d) ? ps[tid - d] : 0;
      __syncthreads();
      ps[tid] += t;
      __syncthreads();
    }
    if (tid == b) { s0s = ps[tid] - v; s1s = ps[tid]; }
    __syncthreads();
  }
  int s0e = s0s, s1e = s1s;
  for (int j = tid; j < BSZ; j += 256) c[j] = 0;
  if (tid < NBIN) lhist[tid] = 0;
  __syncthreads();
  for (int i = s0e + tid; i < s1e; i += 256)
    atomicAdd(&c[pairs[i] >> 17], 1);
  __syncthreads();
  int a0 = c[2 * tid], a1 = c[2 * tid + 1];
  int pv = a0 + a1;
  ps[tid] = pv;
  __syncthreads();
  for (int d = 1; d < 256; d <<= 1) {
    int t = (tid >= d) ? ps[tid - d] : 0;
    __syncthreads();
    ps[tid] += t;
    __syncthreads();
  }
  int pex = ps[tid] - pv;
  int base = s0e + pex;
  int n0 = lo + 2 * tid, n1 = n0 + 1;
  if (n0 < NN) {
    csr_off[n0] = base;
    dis[n0] = (a0 > 0) ? rsqrtf((float)a0) : 0.0f;
    atomicAdd(&lhist[min(a0, NBIN - 1)], 1);
  }
  if (n1 < NN) {
    csr_off[n1] = base + a0;
    dis[n1] = (a1 > 0) ? rsqrtf((float)a1) : 0.0f;
    atomicAdd(&lhist[min(a1, NBIN - 1)], 1);
  }
  curB[2 * tid] = base;
  curB[2 * tid + 1] = base + a0;
  if (b == 0 && tid == 0) csr_off[NN] = EE;
  __syncthreads();
  for (int i = s0e + tid; i < s1e; i += 256) {
    unsigned pk = pairs[i];
    int p = atomicAdd(&curB[pk >> 17], 1);
    csr_src[p] = (int)(pk & 0x1FFFFu);
  }
  __syncthreads();
  if (tid < NBIN) {
    int v = lhist[tid];
    if (v) atomicAdd(&hist[tid], v);
  }
}

// degree scatter; bin offsets computed locally from hist, zero-based cursors
__global__ __launch_bounds__(256) void k_scatter(const int* __restrict__ csr_off,
                                                 const int* __restrict__ hist,
                                                 int* __restrict__ bincur0,
                                                 int* __restrict__ perm) {
  __shared__ int hx[NBIN];
  __shared__ int lh[NBIN];
  __shared__ int lbase[NBIN];
  int tid = threadIdx.x;
  if (tid < NBIN) {
    int v = hist[tid];
    int incl = v;
    for (int d = 1; d < 64; d <<= 1) {
      int t = __shfl_up(incl, d, 64);
      if ((tid & 63) >= d) incl += t;
    }
    hx[tid] = incl - v;
    lh[tid] = 0;
  }
  __syncthreads();
  int i = blockIdx.x * 256 + threadIdx.x;
  int b = 0, r = 0;
  bool valid = i < NN;
  if (valid) {
    int deg = csr_off[i + 1] - csr_off[i];
    b = min(deg, NBIN - 1);
    r = atomicAdd(&lh[b], 1);
  }
  __syncthreads();
  if (threadIdx.x < NBIN) {
    int v = lh[threadIdx.x];
    lbase[threadIdx.x] = v ? (hx[threadIdx.x] + atomicAdd(&bincur0[threadIdx.x], v)) : 0;
  }
  __syncthreads();
  if (valid) perm[lbase[b] + r] = i;
}

// ================= device bodies =================
__device__ void gmean12h_body(int bid, const __half* x12h, const int* perm,
                              const int* off, const int* srcarr, __half* A32) {
  int g = bid * 64 + (threadIdx.x >> 2);
  int t = threadIdx.x & 3;
  if (g >= NN || t >= 3) return;
  int node = perm[g];
  int s = off[node], e = off[node + 1];
  const uint2* h2 = (const uint2*)x12h;
  float4 acc = {0, 0, 0, 0};
  int p = s;
  for (; p + 4 <= e; p += 4) {
    int s0 = srcarr[p], s1 = srcarr[p + 1], s2 = srcarr[p + 2], s3 = srcarr[p + 3];
    acc = f4add(acc, f4add(f4add(h4f(h2[(long)s0 * 3 + t]), h4f(h2[(long)s1 * 3 + t])),
                           f4add(h4f(h2[(long)s2 * 3 + t]), h4f(h2[(long)s3 * 3 + t]))));
  }
  for (; p < e; ++p) acc = f4add(acc, h4f(h2[(long)srcarr[p] * 3 + t]));
  int c = e - s;
  float inv = 1.0f / (float)(c > 0 ? c : 1);
  acc.x *= inv; acc.y *= inv; acc.z *= inv; acc.w *= inv;
  ((uint2*)A32)[(long)node * 8 + t] = pack4h(acc);
}

__device__ void tagp8_top_body(int bid, const float* x, const float* t1aw, const float* t1bw,
                               const float* dis, __half* PTop) {
  int i = bid * 256 + threadIdx.x;
  if (i >= NN) return;
  float a[11];
  #pragma unroll
  for (int j = 0; j < 11; ++j) a[j] = x[(long)i * 11 + j];
  float dn = dis[i];
  {
    float s[8];
    #pragma unroll
    for (int o = 0; o < 8; ++o) {
      float acc = 0.0f;
      #pragma unroll
      for (int j = 0; j < 11; ++j) acc += a[j] * t1aw[o * 44 + 3 * 11 + j];
      s[o] = acc;
    }
    uint2 lo = pack4h(make_float4(s[0] * dn, s[1] * dn, s[2] * dn, s[3] * dn));
    uint2 hi = pack4h(make_float4(s[4] * dn, s[5] * dn, s[6] * dn, s[7] * dn));
    uint4 o4; o4.x = lo.x; o4.y = lo.y; o4.z = hi.x; o4.w = hi.y;
    ((uint4*)PTop)[(long)i * 2] = o4;
  }
  {
    float s[8];
    #pragma unroll
    for (int o = 0; o < 8; ++o) {
      float acc = 0.0f;
      #pragma unroll
      for (int j = 0; j < 11; ++j) acc += a[j] * t1bw[o * 77 + 6 * 11 + j];
      s[o] = acc;
    }
    uint2 lo = pack4h(make_float4(s[0] * dn, s[1] * dn, s[2] * dn, s[3] * dn));
    uint2 hi = pack4h(make_float4(s[4] * dn, s[5] * dn, s[6] * dn, s[7] * dn));
    uint4 o4; o4.x = lo.x; o4.y = lo.y; o4.z = hi.x; o4.w = hi.y;
    ((uint4*)PTop)[(long)i * 2 + 1] = o4;
  }
}

// dual D8 hop; adds are fp16 [k][N][8] (one uint4 per node)
__device__ void d8_dual_body(int bid, const __half* src, const __half* addAH,
                             const __half* addBH, __half* dst,
                             const int* perm, const int* off,
                             const int* srcarr, const float* dis) {
  const uint4* src4 = (const uint4*)src;
  int t = threadIdx.x & 1;
  const uint4* addh = (const uint4*)(t == 0 ? addAH : addBH);
  int g = bid * 128 + (threadIdx.x >> 1);
  if (g >= NN) return;
  int node = perm[g];
  int s = off[node], e = off[node + 1];
  float acc[8] = {};
  int p = s;
  for (; p + 4 <= e; p += 4) {
    int s0 = srcarr[p], s1 = srcarr[p + 1], s2 = srcarr[p + 2], s3 = srcarr[p + 3];
    h8acc(src4[(long)s0 * 2 + t], acc); h8acc(src4[(long)s1 * 2 + t], acc);
    h8acc(src4[(long)s2 * 2 + t], acc); h8acc(src4[(long)s3 * 2 + t], acc);
  }
  for (; p < e; ++p) h8acc(src4[(long)srcarr[p] * 2 + t], acc);
  float dn = dis[node];
  uint4 av4 = addh[node];
  float4 a0 = h4f(make_uint2(av4.x, av4.y)), a1 = h4f(make_uint2(av4.z, av4.w));
  float4 r0 = make_float4((acc[0] * dn + a0.x) * dn, (acc[1] * dn + a0.y) * dn,
                          (acc[2] * dn + a0.z) * dn, (acc[3] * dn + a0.w) * dn);
  float4 r1 = make_float4((acc[4] * dn + a1.x) * dn, (acc[5] * dn + a1.y) * dn,
                          (acc[6] * dn + a1.z) * dn, (acc[7] * dn + a1.w) * dn);
  uint2 lo = pack4h(r0), hi = pack4h(r1);
  uint4 o; o.x = lo.x; o.y = lo.y; o.z = hi.x; o.w = hi.y;
  ((uint4*)dst)[(long)node * 2 + t] = o;
}

__device__ void d8_l3_body(int bid, const __half* src, const __half* Pa0H,
                           const float* t1ab, const float* t2aw,
                           const __half* Pb3H, __half* dstB, float* P2,
                           const int* perm, const int* off,
                           const int* srcarr, const float* dis) {
  const uint4* src4 = (const uint4*)src;
  int t = threadIdx.x & 1;
  int g = bid * 128 + (threadIdx.x >> 1);
  if (g >= NN) return;
  int node = perm[g];
  int s = off[node], e = off[node + 1];
  float acc[8] = {};
  int p = s;
  for (; p + 4 <= e; p += 4) {
    int s0 = srcarr[p], s1 = srcarr[p + 1], s2 = srcarr[p + 2], s3 = srcarr[p + 3];
    h8acc(src4[(long)s0 * 2 + t], acc); h8acc(src4[(long)s1 * 2 + t], acc);
    h8acc(src4[(long)s2 * 2 + t], acc); h8acc(src4[(long)s3 * 2 + t], acc);
  }
  for (; p < e; ++p) h8acc(src4[(long)srcarr[p] * 2 + t], acc);
  float dn = dis[node];
  if (t == 0) {
    uint4 av4 = ((const uint4*)Pa0H)[node];
    float4 a0 = h4f(make_uint2(av4.x, av4.y)), a1 = h4f(make_uint2(av4.z, av4.w));
    float4 b0 = ((const float4*)t1ab)[0], b1 = ((const float4*)t1ab)[1];
    float a[8];
    a[0] = sigm(acc[0] * dn + a0.x + b0.x); a[1] = sigm(acc[1] * dn + a0.y + b0.y);
    a[2] = sigm(acc[2] * dn + a0.z + b0.z); a[3] = sigm(acc[3] * dn + a0.w + b0.w);
    a[4] = sigm(acc[4] * dn + a1.x + b1.x); a[5] = sigm(acc[5] * dn + a1.y + b1.y);
    a[6] = sigm(acc[6] * dn + a1.z + b1.z); a[7] = sigm(acc[7] * dn + a1.w + b1.w);
    #pragma unroll
    for (int k = 0; k < 4; ++k) {
      float sv = 0.0f;
      #pragma unroll
      for (int j = 0; j < 8; ++j) sv += a[j] * t2aw[k * 8 + j];
      if (k == 3) sv *= dn;
      P2[(size_t)k * NN + node] = sv;
    }
  } else {
    uint4 av4 = ((const uint4*)Pb3H)[node];
    float4 a0 = h4f(make_uint2(av4.x, av4.y)), a1 = h4f(make_uint2(av4.z, av4.w));
    float4 r0 = make_float4((acc[0] * dn + a0.x) * dn, (acc[1] * dn + a0.y) * dn,
                            (acc[2] * dn + a0.z) * dn, (acc[3] * dn + a0.w) * dn);
    float4 r1 = make_float4((acc[4] * dn + a1.x) * dn, (acc[5] * dn + a1.y) * dn,
                            (acc[6] * dn + a1.z) * dn, (acc[7] * dn + a1.w) * dn);
    uint2 lo = pack4h(r0), hi = pack4h(r1);
    uint4 o; o.x = lo.x; o.y = lo.y; o.z = hi.x; o.w = hi.y;
    ((uint4*)dstB)[(long)node * 2 + 1] = o;
  }
}

// single-B D8 hop; addB fp16 slice (lane t reads halves 4t..4t+3)
__device__ void d8_single_body(int bid, const __half* src, const __half* addBH, __half* dst,
                               const int* perm, const int* off,
                               const int* srcarr, const float* dis) {
  const uint2* src2 = (const uint2*)src;
  int t = threadIdx.x & 1;
  int g = bid * 128 + (threadIdx.x >> 1);
  if (g >= NN) return;
  int node = perm[g];
  int s = off[node], e = off[node + 1];
  float4 acc = {0, 0, 0, 0};
  int p = s;
  for (; p + 4 <= e; p += 4) {
    int s0 = srcarr[p], s1 = srcarr[p + 1], s2 = srcarr[p + 2], s3 = srcarr[p + 3];
    acc = f4add(acc, f4add(f4add(h4f(src2[(long)s0 * 4 + 2 + t]), h4f(src2[(long)s1 * 4 + 2 + t])),
                           f4add(h4f(src2[(long)s2 * 4 + 2 + t]), h4f(src2[(long)s3 * 4 + 2 + t]))));
  }
  for (; p < e; ++p) acc = f4add(acc, h4f(src2[(long)srcarr[p] * 4 + 2 + t]));
  float dn = dis[node];
  float4 av = h4f(((const uint2*)addBH)[(long)node * 2 + t]);
  float4 r = make_float4((acc.x * dn + av.x) * dn, (acc.y * dn + av.y) * dn,
                         (acc.z * dn + av.z) * dn, (acc.w * dn + av.w) * dn);
  ((uint2*)dst)[(long)node * 4 + 2 + t] = pack4h(r);
}

__device__ void d8_l6_body(int bid, const __half* src, const __half* Pb0H,
                           const float* t1bb, const float* t2bw, float* P2b,
                           const int* perm, const int* off,
                           const int* srcarr, const float* dis) {
  const uint2* src2 = (const uint2*)src;
  int t = threadIdx.x & 1;
  int g = bid * 128 + (threadIdx.x >> 1);
  if (g >= NN) return;
  int node = perm[g];
  int s = off[node], e = off[node + 1];
  float4 acc = {0, 0, 0, 0};
  int p = s;
  for (; p + 4 <= e; p += 4) {
    int s0 = srcarr[p], s1 = srcarr[p + 1], s2 = srcarr[p + 2], s3 = srcarr[p + 3];
    acc = f4add(acc, f4add(f4add(h4f(src2[(long)s0 * 4 + 2 + t]), h4f(src2[(long)s1 * 4 + 2 + t])),
                           f4add(h4f(src2[(long)s2 * 4 + 2 + t]), h4f(src2[(long)s3 * 4 + 2 + t]))));
  }
  for (; p < e; ++p) acc = f4add(acc, h4f(src2[(long)srcarr[p] * 4 + 2 + t]));
  float dn = dis[node];
  float4 av = h4f(((const uint2*)Pb0H)[(long)node * 2 + t]);
  float4 bv = ((const float4*)t1bb)[t];
  float4 r = make_float4(sigm(acc.x * dn + av.x + bv.x), sigm(acc.y * dn + av.y + bv.y),
                         sigm(acc.z * dn + av.z + bv.z), sigm(acc.w * dn + av.w + bv.w));
  float o0 = __shfl_xor(r.x, 1, 64), o1 = __shfl_xor(r.y, 1, 64);
  float o2 = __shfl_xor(r.z, 1, 64), o3 = __shfl_xor(r.w, 1, 64);
  if (t == 0) {
    float a[8] = {r.x, r.y, r.z, r.w, o0, o1, o2, o3};
    #pragma unroll
    for (int k = 0; k < 7; ++k) {
      float sv = 0.0f;
      #pragma unroll
      for (int j = 0; j < 8; ++j) sv += a[j] * t2bw[k * 8 + j];
      if (k == 6) sv *= dn;
      P2b[(size_t)k * NN + node] = sv;
    }
  }
}

__device__ void d1_body(int bid, const float* ua, const float* adda, const float* bias,
                        int act, float* outa, const int* perm, const int* off,
                        const int* srcarr, const float* dis) {
  int g = bid * 64 + (threadIdx.x >> 2);
  int t = threadIdx.x & 3;
  if (g >= NN) return;
  int node = perm[g];
  int s = off[node], e = off[node + 1];
  float accA = 0.0f;
  for (int p = s + t; p < e; p += 4) accA += ua[srcarr[p]];
  accA += __shfl_xor(accA, 1, 64); accA += __shfl_xor(accA, 2, 64);
  if (t == 0) {
    float sc = dis[node];
    float rA = accA * sc + adda[node];
    if (bias) rA += bias[0];
    if (act == 3) rA *= sc; else if (act == 2) rA = fmaxf(rA, 0.0f);
    outa[node] = rA;
  }
}

__device__ void x1s_body(int bid, const float* pp, const float* qq, const float* s3b,
                         const int* perm, const int* off, const int* srcarr,
                         float* x1s) {
  int g = bid * 64 + (threadIdx.x >> 2);
  int t = threadIdx.x & 3;
  if (g >= NN) return;
  int node = perm[g];
  int s = off[node], e = off[node + 1];
  float acc = 0.0f;
  for (int p = s + t; p < e; p += 4) acc += pp[srcarr[p]];
  acc += __shfl_xor(acc, 1, 64); acc += __shfl_xor(acc, 2, 64);
  if (t == 0) {
    int c = e - s;
    float sc = 1.0f / (float)(c > 0 ? c : 1);
    x1s[node] = fmaxf(acc * sc + qq[node] + s3b[0], 0.0f);
  }
}

__device__ void gather128_body(int bid, const __half* h, const int* perm,
                               const int* off, const int* srcarr, __half* outh) {
  int g = bid * 16 + (threadIdx.x >> 4);
  int t = threadIdx.x & 15;
  if (g >= NN) return;
  int node = perm[g];
  int s = off[node], e = off[node + 1];
  const uint4* h4 = (const uint4*)h;
  float acc[8] = {};
  int p = s;
  for (; p + 4 <= e; p += 4) {
    int s0 = srcarr[p], s1 = srcarr[p + 1], s2 = srcarr[p + 2], s3 = srcarr[p + 3];
    uint4 r0 = h4[(long)s0 * 16 + t], r1 = h4[(long)s1 * 16 + t];
    uint4 r2 = h4[(long)s2 * 16 + t], r3 = h4[(long)s3 * 16 + t];
    h8acc(r0, acc); h8acc(r1, acc); h8acc(r2, acc); h8acc(r3, acc);
  }
  for (; p < e; ++p) h8acc(h4[(long)srcarr[p] * 16 + t], acc);
  int c = e - s;
  float inv = 1.0f / (float)(c > 0 ? c : 1);
  uint2 lo = pack4h(make_float4(acc[0] * inv, acc[1] * inv, acc[2] * inv, acc[3] * inv));
  uint2 hi = pack4h(make_float4(acc[4] * inv, acc[5] * inv, acc[6] * inv, acc[7] * inv));
  uint4 o; o.x = lo.x; o.y = lo.y; o.z = hi.x; o.w = hi.y;
  ((uint4*)outh)[(long)node * 16 + t] = o;
}

__device__ void mm1_body(int bid, const __half* A32, const __half* W32,
                         const float* bias, __half* out, __half (*lt)[32][136]) {
  int tid = threadIdx.x;
  int wave = tid >> 6, l = tid & 63;
  int lr = l & 15, lk = l >> 4;
  int m0 = bid * 128 + wave * 32;
  f4v acc[2][8] = {};
  h8v afrag[2];
  #pragma unroll
  for (int rt = 0; rt < 2; ++rt) {
    int row = m0 + rt * 16 + lr;
    h8v z = {};
    afrag[rt] = (row < NN) ? *(const h8v*)&A32[(long)row * 32 + lk * 8] : z;
  }
  #pragma unroll
  for (int c = 0; c < 8; ++c) {
    h8v bfrag = *(const h8v*)&W32[(c * 16 + lr) * 32 + lk * 8];
    acc[0][c] = __builtin_amdgcn_mfma_f32_16x16x32_f16(afrag[0], bfrag, acc[0][c], 0, 0, 0);
    acc[1][c] = __builtin_amdgcn_mfma_f32_16x16x32_f16(afrag[1], bfrag, acc[1][c], 0, 0, 0);
  }
  float bi[8];
  #pragma unroll
  for (int c = 0; c < 8; ++c) bi[c] = bias[c * 16 + lr];
  #pragma unroll
  for (int rt = 0; rt < 2; ++rt)
    #pragma unroll
    for (int c = 0; c < 8; ++c)
      #pragma unroll
      for (int reg = 0; reg < 4; ++reg) {
        float v = acc[rt][c][reg] + bi[c];
        lt[wave][rt * 16 + lk * 4 + reg][c * 16 + lr] = __float2half(sigm(v));
      }
  __syncthreads();
  #pragma unroll
  for (int it = 0; it < 8; ++it) {
    int idx = it * 64 + l;
    int row = idx >> 4, c16 = idx & 15;
    int grow = m0 + row;
    if (grow < NN) {
      uint4 v = *(const uint4*)&lt[wave][row][c16 * 8];
      ((uint4*)out)[(long)grow * 16 + c16] = v;
    }
  }
}

__device__ void mm2_body(int bid, const __half* A1, const __half* A2,
                         const __half* W, const float* bias,
                         const float* w3l, const float* w3r,
                         float* pp, float* qq) {
  int tid = threadIdx.x;
  int wave = tid >> 6;
  int l = tid & 63;
  int lr = l & 15;
  int lk = l >> 4;
  int m0 = bid * 128 + wave * 32;
  f4v acc[2][8] = {};
  #pragma unroll
  for (int ks = 0; ks < 8; ++ks) {
    const __half* Asrc = (ks < 4) ? A1 : A2;
    int kk = (ks & 3) * 32 + lk * 8;
    h8v afrag[2];
    #pragma unroll
    for (int rt = 0; rt < 2; ++rt) {
      int row = m0 + rt * 16 + lr;
      h8v z = {};
      afrag[rt] = (row < NN) ? *(const h8v*)&Asrc[(long)row * 128 + kk] : z;
    }
    #pragma unroll
    for (int c = 0; c < 8; ++c) {
      h8v bfrag = *(const h8v*)&W[(long)(c * 16 + lr) * 256 + ks * 32 + lk * 8];
      acc[0][c] = __builtin_amdgcn_mfma_f32_16x16x32_f16(afrag[0], bfrag, acc[0][c], 0, 0, 0);
      acc[1][c] = __builtin_amdgcn_mfma_f32_16x16x32_f16(afrag[1], bfrag, acc[1][c], 0, 0, 0);
    }
  }
  float wl[8], wr[8], bi[8];
  #pragma unroll
  for (int c = 0; c < 8; ++c) {
    wl[c] = w3l[c * 16 + lr];
    wr[c] = w3r[c * 16 + lr];
    bi[c] = bias[c * 16 + lr];
  }
  #pragma unroll
  for (int rt = 0; rt < 2; ++rt) {
    #pragma unroll
    for (int reg = 0; reg < 4; ++reg) {
      float s1 = 0.0f, s2 = 0.0f;
      #pragma unroll
      for (int c = 0; c < 8; ++c) {
        float v = acc[rt][c][reg] + bi[c];
        float sg = sigm(v);
        s1 += sg * wl[c];
        s2 += sg * wr[c];
      }
      #pragma unroll
      for (int d = 1; d < 16; d <<= 1) {
        s1 += __shfl_xor(s1, d, 64);
        s2 += __shfl_xor(s2, d, 64);
      }
      int row = m0 + rt * 16 + lk * 4 + reg;
      if (lr == 0 && row < NN) { pp[row] = s1; qq[row] = s2; }
    }
  }
}

// ================= fused dispatches =================
__global__ __launch_bounds__(256) void k_fuseA(
    const __half* x12h, const int* perm, const int* off, const int* srcarr, __half* A32,
    const float* x, const float* t1aw, const float* t1bw, const float* dis, __half* PTop) {
  if (blockIdx.x < GA) gmean12h_body(blockIdx.x, x12h, perm, off, srcarr, A32);
  else tagp8_top_body(blockIdx.x - GA, x, t1aw, t1bw, dis, PTop);
}

__global__ __launch_bounds__(256) void k_fuseB(
    const __half* A32, const __half* W32, const float* s1b, __half* x1a,
    const __half* PTop, const __half* Pa2H, const __half* Pb5H, __half* zbuf0,
    const int* perm, const int* off, const int* srcarr, const float* dis) {
  __shared__ __half lt[4][32][136];
  if (blockIdx.x < GM) mm1_body(blockIdx.x, A32, W32, s1b, x1a, lt);
  else d8_dual_body(blockIdx.x - GM, PTop, Pa2H, Pb5H, zbuf0, perm, off, srcarr, dis);
}

__global__ __launch_bounds__(256) void k_fuseC(
    const __half* x1a, __half* mean128,
    const __half* zbuf0, const __half* Pa1H, const __half* Pb4H, __half* zbuf1,
    const int* perm, const int* off, const int* srcarr, const float* dis) {
  if (blockIdx.x < GG) gather128_body(blockIdx.x, x1a, perm, off, srcarr, mean128);
  else d8_dual_body(blockIdx.x - GG, zbuf0, Pa1H, Pb4H, zbuf1, perm, off, srcarr, dis);
}

__global__ __launch_bounds__(256) void k_fuseD(
    const __half* mean128, const __half* x1a, const __half* w2h, const float* s2b,
    const float* w3l, const float* w3r, float* pp, float* qq,
    const __half* zbuf1, const __half* Pa0H, const float* t1ab, const float* t2aw,
    const __half* Pb3H, __half* zbuf0, float* P2,
    const int* perm, const int* off, const int* srcarr, const float* dis) {
  if (blockIdx.x < GM) mm2_body(blockIdx.x, mean128, x1a, w2h, s2b, w3l, w3r, pp, qq);
  else d8_l3_body(blockIdx.x - GM, zbuf1, Pa0H, t1ab, t2aw, Pb3H, zbuf0, P2,
                  perm, off, srcarr, dis);
}

__global__ __launch_bounds__(256) void k_fuseE(
    const __half* zbuf0, const __half* Pb2H, __half* zbuf1,
    const float* pp, const float* qq, const float* s3b, float* x1s,
    const float* P2, float* uA1,
    const int* perm, const int* off, const int* srcarr, const float* dis) {
  if (blockIdx.x < GM)
    d8_single_body(blockIdx.x, zbuf0, Pb2H, zbuf1, perm, off, srcarr, dis);
  else if (blockIdx.x < GM + G1)
    x1s_body(blockIdx.x - GM, pp, qq, s3b, perm, off, srcarr, x1s);
  else
    d1_body(blockIdx.x - GM - G1, P2 + 3 * (size_t)NN, P2 + 2 * (size_t)NN,
            nullptr, 3, uA1, perm, off, srcarr, dis);
}

__global__ __launch_bounds__(256) void k_fuseF(
    const __half* zbuf1, const __half* Pb1H, __half* zbuf0,
    const float* uA1, const float* P2, float* uA2,
    const int* perm, const int* off, const int* srcarr, const float* dis) {
  if (blockIdx.x < GM)
    d8_single_body(blockIdx.x, zbuf1, Pb1H, zbuf0, perm, off, srcarr, dis);
  else
    d1_body(blockIdx.x - GM, uA1, P2 + 1 * (size_t)NN, nullptr, 3, uA2,
            perm, off, srcarr, dis);
}

__global__ __launch_bounds__(256) void k_fuseG(
    const __half* zbuf0, const __half* Pb0H, const float* t1bb, const float* t2bw,
    float* P2b, const float* uA2, const float* P2, const float* t2ab, float* x2s,
    const int* perm, const int* off, const int* srcarr, const float* dis) {
  if (blockIdx.x < GM)
    d8_l6_body(blockIdx.x, zbuf0, Pb0H, t1bb, t2bw, P2b, perm, off, srcarr, dis);
  else
    d1_body(blockIdx.x - GM, uA2, P2, t2ab, 2, x2s, perm, off, srcarr, dis);
}

__global__ __launch_bounds__(256) void k_d1b(
    const float* ua, const float* adda, float* outa,
    const int* perm, const int* off, const int* srcarr, const float* dis) {
  d1_body(blockIdx.x, ua, adda, nullptr, 3, outa, perm, off, srcarr, dis);
}

__global__ __launch_bounds__(256) void k_g1_final(
    const float* ua, const float* adda, const float* biasa,
    const float* x1s, const float* x2s,
    const float* lw, const float* lb,
    const int* perm, const int* off, const int* srcarr, const float* dis,
    float* out) {
  int g = blockIdx.x * 64 + (threadIdx.x >> 2);
  int t = threadIdx.x & 3;
  if (g >= NN) return;
  int node = perm[g];
  int s = off[node], e = off[node + 1];
  float accA = 0.0f;
  for (int p = s + t; p < e; p += 4) accA += ua[srcarr[p]];
  accA += __shfl_xor(accA, 1, 64); accA += __shfl_xor(accA, 2, 64);
  if (t == 0) {
    float x3v = fmaxf(accA * dis[node] + adda[node] + biasa[0], 0.0f);
    float v = x1s[node] * lw[0] + x2s[node] * lw[1] + x3v * lw[2] + lb[0];
    out[node] = fmaxf(v, 0.0f);
  }
}

extern "C" void kernel_launch(void* const* d_in, const int* in_sizes, int n_in,
                              void* d_out, int out_size, void* d_ws, size_t ws_size,
                              hipStream_t stream) {
  const float* x    = (const float*)d_in[0];
  const int*   ei   = (const int*)d_in[1];
  const float* s1wl = (const float*)d_in[2];
  const float* s1wr = (const float*)d_in[3];
  const float* s1b  = (const float*)d_in[4];
  const float* s2wl = (const float*)d_in[5];
  const float* s2wr = (const float*)d_in[6];
  const float* s2b  = (const float*)d_in[7];
  const float* s3wl = (const float*)d_in[8];
  const float* s3wr = (const float*)d_in[9];
  const float* s3b  = (const float*)d_in[10];
  const float* t1aw = (const float*)d_in[11];
  const float* t1ab = (const float*)d_in[12];
  const float* t2aw = (const float*)d_in[13];
  const float* t2ab = (const float*)d_in[14];
  const float* t1bw = (const float*)d_in[15];
  const float* t1bb = (const float*)d_in[16];
  const float* t2bw = (const float*)d_in[17];
  const float* t2bb = (const float*)d_in[18];
  const float* lw   = (const float*)d_in[19];
  const float* lb   = (const float*)d_in[20];
  float* out = (float*)d_out;

  char* basep = (char*)d_ws;
  size_t off = 0;
  auto alloc = [&](size_t bytes) -> void* {
    void* ptr = basep + off;
    off = (off + bytes + 255) & ~(size_t)255;
    return ptr;
  };
  int*      ghist   = (int*)alloc(256 * 4);   // zero block: ghist,gcur0,hist,bincur0
  int*      gcur0   = (int*)alloc(256 * 4);
  int*      hist    = (int*)alloc(NBIN * 4);
  int*      bincur0 = (int*)alloc(NBIN * 4);
  int*      csr_off = (int*)alloc((size_t)(NN + 1) * 4);
  float*    dis     = (float*)alloc((size_t)NN * 4);
  int*      csr_src = (int*)alloc((size_t)EE * 4);
  unsigned* pairs   = (unsigned*)alloc((size_t)EE * 4);
  int*      perm    = (int*)alloc((size_t)NN * 4);
  float*    x1s     = (float*)alloc((size_t)NN * 4);
  float*    x2s     = (float*)alloc((size_t)NN * 4);
  float*    pp      = (float*)alloc((size_t)NN * 4);
  float*    qq      = (float*)alloc((size_t)NN * 4);
  float*    uA1     = (float*)alloc((size_t)NN * 4);
  float*    uA2     = (float*)alloc((size_t)NN * 4);
  float*    uB1     = (float*)alloc((size_t)NN * 4);
  float*    uB2     = (float*)alloc((size_t)NN * 4);
  __half*   x12h    = (__half*)alloc((size_t)NN * 12 * 2);
  __half*   A32     = (__half*)alloc((size_t)NN * 32 * 2);
  __half*   w1h     = (__half*)alloc((size_t)128 * 32 * 2);
  __half*   w2h     = (__half*)alloc((size_t)128 * 256 * 2);
  __half*   x1a_h   = (__half*)alloc((size_t)NN * 128 * 2);
  __half*   mean128_h = (__half*)alloc((size_t)NN * 128 * 2);
  __half*   PaH   = (__half*)alloc((size_t)NN * 24 * 2);  // [3][N][8] fp16
  __half*   PbH   = (__half*)alloc((size_t)NN * 48 * 2);  // [6][N][8] fp16
  __half*   PTop  = (__half*)alloc((size_t)NN * 16 * 2);  // [N][16] interleaved
  __half*   zbuf0 = (__half*)alloc((size_t)NN * 16 * 2);
  __half*   zbuf1 = (__half*)alloc((size_t)NN * 16 * 2);
  float*    P2    = (float*)alloc((size_t)NN * 4 * 4);    // [4][N]
  float*    P2b   = (float*)alloc((size_t)NN * 7 * 4);    // [7][N]

  const size_t H8 = (size_t)NN * 8;   // halves per slice
  const size_t S1 = (size_t)NN;

  // ---- CSR build + prep ----
  hipMemsetAsync(ghist, 0, 2560, stream);   // ghist+gcur0+hist+bincur0 (contiguous)
  k_bhist_prep<<<BH_B + PREP_B0 + PREP_B1 + 16 + 128, 256, 0, stream>>>(
      ei, ghist, x, s1wl, s1wr, s2wl, s2wr, x12h, A32, w1h, w2h);
  k_split_tag<<<SPB + TGA, 256, 0, stream>>>(
      ei, ghist, gcur0, pairs, x, t1aw, t1bw, PaH, PbH);
  k_bbuild<<<NBK, 256, 0, stream>>>(pairs, ghist, csr_off, dis, csr_src, hist);
  k_scatter<<<(NN + 255) / 256, 256, 0, stream>>>(csr_off, hist, bincur0, perm);

  // ---- co-scheduled SAGE + TAG ----
  k_fuseA<<<GA + GT, 256, 0, stream>>>(
      x12h, perm, csr_off, csr_src, A32, x, t1aw, t1bw, dis, PTop);
  k_fuseB<<<GM + GM, 256, 0, stream>>>(
      A32, w1h, s1b, x1a_h, PTop, PaH + 2 * H8, PbH + 5 * H8, zbuf0,
      perm, csr_off, csr_src, dis);
  k_fuseC<<<GG + GM, 256, 0, stream>>>(
      x1a_h, mean128_h, zbuf0, PaH + 1 * H8, PbH + 4 * H8, zbuf1,
      perm, csr_off, csr_src, dis);
  k_fuseD<<<GM + GM, 256, 0, stream>>>(
      mean128_h, x1a_h, w2h, s2b, s3wl, s3wr, pp, qq,
      zbuf1, PaH, t1ab, t2aw, PbH + 3 * H8, zbuf0, P2,
      perm, csr_off, csr_src, dis);
  k_fuseE<<<GM + G1 + G1, 256, 0, stream>>>(
      zbuf0, PbH + 2 * H8, zbuf1, pp, qq, s3b, x1s, P2, uA1,
      perm, csr_off, csr_src, dis);
  k_fuseF<<<GM + G1, 256, 0, stream>>>(
      zbuf1, PbH + 1 * H8, zbuf0, uA1, P2, uA2,
      perm, csr_off, csr_src, dis);
  k_fuseG<<<GM + G1, 256, 0, stream>>>(
      zbuf0, PbH, t1bb, t2bw, P2b, uA2, P2, t2ab, x2s,
      perm, csr_off, csr_src, dis);

  // ---- d1b tail chain ----
  k_d1b<<<G1, 256, 0, stream>>>(P2b + 6 * S1, P2b + 5 * S1, uB1, perm, csr_off, csr_src, dis);
  k_d1b<<<G1, 256, 0, stream>>>(uB1, P2b + 4 * S1, uB2, perm, csr_off, csr_src, dis);
  k_d1b<<<G1, 256, 0, stream>>>(uB2, P2b + 3 * S1, uB1, perm, csr_off, csr_src, dis);
  k_d1b<<<G1, 256, 0, stream>>>(uB1, P2b + 2 * S1, uB2, perm, csr_off, csr_src, dis);
  k_d1b<<<G1, 256, 0, stream>>>(uB2, P2b + 1 * S1, uB1, perm, csr_off, csr_src, dis);
  k_g1_final<<<G1, 256, 0, stream>>>(
      uB1, P2b, t2bb, x1s, x2s, lw, lb, perm, csr_off, csr_src, dis, out);
}